// Round 8
// baseline (750.075 us; speedup 1.0000x reference)
//
#include <hip/hip_runtime.h>
#include <hip/hip_bf16.h>
#include <hip/hip_fp16.h>

#define HID 128
#define EDIM 16

typedef float v4f __attribute__((ext_vector_type(4)));
typedef float v2f __attribute__((ext_vector_type(2)));
typedef short s8v __attribute__((ext_vector_type(8)));   // 8 bf16 (4 VGPRs) MFMA frag
typedef float f4v __attribute__((ext_vector_type(4)));   // MFMA acc
typedef _Float16 h2v __attribute__((ext_vector_type(2)));      // f16 pair for fdot2

#define MFMA_BF16(a, b, c) __builtin_amdgcn_mfma_f32_16x16x32_bf16((a), (b), (c), 0, 0, 0)

__device__ __forceinline__ unsigned short bf16_rne(float v)
{
    unsigned u = __builtin_bit_cast(unsigned, v);
    return (unsigned short)((u + 0x7fffu + ((u >> 16) & 1u)) >> 16);
}

__device__ __forceinline__ unsigned pack2(float lo, float hi)
{
    return (unsigned)bf16_rne(lo) | ((unsigned)bf16_rne(hi) << 16);
}

__device__ __forceinline__ float bflo(unsigned u) { return __builtin_bit_cast(float, u << 16); }
__device__ __forceinline__ float bfhi(unsigned u) { return __builtin_bit_cast(float, u & 0xffff0000u); }

__device__ __forceinline__ v2f unpack2(unsigned u)
{
    v2f r; r.x = bflo(u); r.y = bfhi(u); return r;
}

__device__ __forceinline__ void split_bf16(float v, unsigned short& h, unsigned short& l)
{
    unsigned u = __builtin_bit_cast(unsigned, v);
    unsigned hu = (u + 0x7fffu + ((u >> 16) & 1u)) >> 16;
    h = (unsigned short)hu;
    float hf = __builtin_bit_cast(float, hu << 16);
    l = bf16_rne(v - hf);
}

__device__ __forceinline__ v2f vmax0(v2f a)
{
    v2f r; r.x = fmaxf(a.x, 0.f); r.y = fmaxf(a.y, 0.f); return r;
}

// pack two floats to f16x2 (RNE)
__device__ __forceinline__ unsigned pkh2(float lo, float hi)
{
    return (unsigned)__half_as_ushort(__float2half(lo)) |
           ((unsigned)__half_as_ushort(__float2half(hi)) << 16);
}

// d += ea.lo*w.lo + ea.hi*w.hi (fp32 accumulate). Builtin (NOT bare asm): bare
// VOP3P asm assembles op_sel_hi:[0,0] -> 2*a.lo*b.lo (round-6 absmax 0.54).
__device__ __forceinline__ void dot2(float& d, unsigned ea, unsigned w)
{
    d = __builtin_amdgcn_fdot2(__builtin_bit_cast(h2v, ea),
                               __builtin_bit_cast(h2v, w), d, false);
}

// ================= CSR build =================
__global__ void hist_kernel(const int* __restrict__ dst, int* __restrict__ deg, int E)
{
    int e = blockIdx.x * 256 + threadIdx.x;
    if (e < E) atomicAdd(&deg[dst[e]], 1);
}

__global__ void block_sum_kernel(const int* __restrict__ deg, int* __restrict__ bsum, int Nn)
{
    int i = blockIdx.x * 256 + threadIdx.x;
    int v = (i < Nn) ? deg[i] : 0;
#pragma unroll
    for (int off = 32; off > 0; off >>= 1) v += __shfl_down(v, off, 64);
    __shared__ int ws[4];
    if ((threadIdx.x & 63) == 0) ws[threadIdx.x >> 6] = v;
    __syncthreads();
    if (threadIdx.x == 0) bsum[blockIdx.x] = ws[0] + ws[1] + ws[2] + ws[3];
}

__global__ void bsum_scan_kernel(int* bsum, int nb, int* total_out)
{
    __shared__ int sh[256];
    int tid = threadIdx.x;
    int v = (tid < nb) ? bsum[tid] : 0;
    sh[tid] = v;
    __syncthreads();
    for (int off = 1; off < 256; off <<= 1) {
        int tv = (tid >= off) ? sh[tid - off] : 0;
        __syncthreads();
        sh[tid] += tv;
        __syncthreads();
    }
    if (tid < nb) bsum[tid] = sh[tid] - v;
    if (tid == 255) *total_out = sh[255];
}

__global__ void block_scan_kernel(const int* __restrict__ deg, const int* __restrict__ bsum,
                                  int* __restrict__ row_start, int* __restrict__ cursor, int Nn)
{
    __shared__ int sh[256];
    int tid = threadIdx.x;
    int i = blockIdx.x * 256 + tid;
    int v = (i < Nn) ? deg[i] : 0;
    sh[tid] = v;
    __syncthreads();
    for (int off = 1; off < 256; off <<= 1) {
        int tv = (tid >= off) ? sh[tid - off] : 0;
        __syncthreads();
        sh[tid] += tv;
        __syncthreads();
    }
    if (i < Nn) {
        int excl = sh[tid] - v + bsum[blockIdx.x];
        row_start[i] = excl;
        cursor[i] = excl;
    }
}

// phase 1: permutation only (12B/edge traffic; scattered 4B writes live in L2)
__global__ void scatter_kernel(const int* __restrict__ src, const int* __restrict__ dst,
                               int* cursor, int* __restrict__ perm,
                               int* __restrict__ src_perm, int E)
{
    int e = blockIdx.x * 256 + threadIdx.x;
    if (e >= E) return;
    int pos = atomicAdd(&cursor[dst[e]], 1);
    perm[pos] = e;
    src_perm[pos] = src[e];
}

// phase 2: ea permute-copy + f16 convert — scattered READS, coalesced 16B writes.
// 2 threads per edge row; row = 8 dwords (16 f16).
__global__ void gather_ea_f16(const float* __restrict__ ea, const int* __restrict__ perm,
                              unsigned* __restrict__ eaH, int E)
{
    int idx = blockIdx.x * 256 + threadIdx.x;
    int p = idx >> 1, hf = idx & 1;
    if (p >= E) return;
    int e = perm[p];
    const float* ap = &ea[(size_t)e * EDIM + hf * 8];
    float4 f0 = *(const float4*)ap;
    float4 f1 = *(const float4*)(ap + 4);
    uint4 o;
    o.x = pkh2(f0.x, f0.y);
    o.y = pkh2(f0.z, f0.w);
    o.z = pkh2(f1.x, f1.y);
    o.w = pkh2(f1.z, f1.w);
    *(uint4*)&eaH[(size_t)p * 8 + hf * 4] = o;
}

// ================= weight prep: fp32 [K,128] -> transposed split-bf16 [128,K] hi/lo =================
__global__ void prep_weights(const float* __restrict__ Wp, const float* __restrict__ W1,
                             const float* __restrict__ W2, unsigned short* __restrict__ out)
{
    int idx = blockIdx.x * 256 + threadIdx.x;
    if (idx < 8192) {
        int n = idx >> 6, k = idx & 63;
        unsigned short h, l;
        split_bf16(Wp[k * 128 + n], h, l);
        out[idx] = h;
        out[8192 + idx] = l;
    } else {
        int j = idx - 8192;
        if (j >= 6 * 16384) return;
        int m2 = j >> 14;
        int r = j & 16383;
        int n = r >> 7, k = r & 127;
        int l = m2 >> 1;
        const float* Wsrc = (m2 & 1) ? (W2 + l * 16384) : (W1 + l * 16384);
        unsigned short h, lo;
        split_bf16(Wsrc[k * 128 + n], h, lo);
        int base = 16384 + m2 * 32768;
        out[base + r] = h;
        out[base + 16384 + r] = lo;
    }
}

// ===== f16-pair We table for aggregation: out[l][ch][kp] = pkh2(We[2kp][ch], We[2kp+1][ch]) =====
__global__ void prep_wef16(const float* __restrict__ We, unsigned* __restrict__ out)
{
    int idx = blockIdx.x * 256 + threadIdx.x;
    if (idx >= 3 * 1024) return;
    int l = idx >> 10, r = idx & 1023, ch = r >> 3, kp = r & 7;
    const float* W = We + (size_t)l * EDIM * HID;
    out[idx] = pkh2(W[(2 * kp) * HID + ch], W[(2 * kp + 1) * HID + ch]);
}

// ====== Node-centric aggregation v6: all-VMEM pipeline ======
// 1 wave/node, 2 ch/lane. ea rows + src ids read via VMEM broadcast (opaque-zero
// VGPR base -> counted vmcnt, compiler-scheduled; no SMEM lgkmcnt drains).
// ea lands in VGPRs -> fdot2 consumes directly (no s->v movs). 2-edge groups,
// ea+h rotated 1 group ahead; src ids 1 further (full-iteration slack on the
// src->h chain). f16 weight pairs from precomputed table (prep_wef16).
__device__ __forceinline__ void edgeD(v2f& acc, v2f bj, unsigned hu,
                                      uint4 ea, uint4 eb,
                                      uint4 w0a, uint4 w0b, uint4 w1a, uint4 w1b)
{
    float m0 = bj.x + bflo(hu);
    float m1 = bj.y + bfhi(hu);
    dot2(m0, ea.x, w0a.x); dot2(m1, ea.x, w1a.x);
    dot2(m0, ea.y, w0a.y); dot2(m1, ea.y, w1a.y);
    dot2(m0, ea.z, w0a.z); dot2(m1, ea.z, w1a.z);
    dot2(m0, ea.w, w0a.w); dot2(m1, ea.w, w1a.w);
    dot2(m0, eb.x, w0b.x); dot2(m1, eb.x, w1b.x);
    dot2(m0, eb.y, w0b.y); dot2(m1, eb.y, w1b.y);
    dot2(m0, eb.z, w0b.z); dot2(m1, eb.z, w1b.z);
    dot2(m0, eb.w, w0b.w); dot2(m1, eb.w, w1b.w);
    acc.x += fmaxf(m0, 0.f);
    acc.y += fmaxf(m1, 0.f);
}

__global__ __launch_bounds__(256, 6) void aggregate_f16(
    const unsigned short* __restrict__ h16, const unsigned* __restrict__ eaH,
    const int* __restrict__ src_perm, const int* __restrict__ row_start,
    const unsigned* __restrict__ Wpk, const float* __restrict__ be,
    float* __restrict__ t, int Nn)
{
    int tid = threadIdx.x;
    int lane = tid & 63;
    int c = lane * 2;
    int node = blockIdx.x * 4 + (tid >> 6);
    if (node >= Nn) return;
    const uint4* wrow = (const uint4*)(Wpk + (size_t)c * 8);
    uint4 w0a = wrow[0], w0b = wrow[1];   // channel c
    uint4 w1a = wrow[2], w1b = wrow[3];   // channel c+1
    v2f bj = *(const v2f*)&be[c];
    // opaque zero in a VGPR: derived addresses treated as divergent -> VMEM
    // broadcast loads (vmcnt-counted) even though all lanes read the same row.
    unsigned zz;
    asm("v_mov_b32 %0, 0" : "=v"(zz));
    const unsigned* __restrict__ eaV = eaH + zz;
    const int* __restrict__ spV = src_perm + zz;
    const unsigned* __restrict__ hw = (const unsigned*)h16 + lane;  // bf16 ch-pair per lane
    v2f acc = unpack2(hw[(unsigned)node << 6]);
    int p0 = __builtin_amdgcn_readfirstlane(row_start[node]);
    int p1 = __builtin_amdgcn_readfirstlane(row_start[node + 1]);
    int p = p0;

    int s10 = 0, s11 = 0;                 // src ids of group g+1 (ready)
    unsigned hu0 = 0, hu1 = 0;            // h of group g (ready)
    uint4 e0 = {0, 0, 0, 0}, e1 = {0, 0, 0, 0};
    uint4 e2 = {0, 0, 0, 0}, e3 = {0, 0, 0, 0};   // ea of group g (ready)
    if (p < p1) {
        int q0 = p;
        int q1 = (p + 1 < p1) ? p + 1 : p;
        int q2 = (p + 2 < p1) ? p + 2 : q1;
        int q3 = (p + 3 < p1) ? p + 3 : q2;
        int sc0 = spV[q0], sc1 = spV[q1];
        s10 = spV[q2]; s11 = spV[q3];
        hu0 = hw[(unsigned)sc0 << 6];
        hu1 = hw[(unsigned)sc1 << 6];
        e0 = *(const uint4*)(eaV + (size_t)(unsigned)q0 * 8);
        e1 = *(const uint4*)(eaV + (size_t)(unsigned)q0 * 8 + 4);
        e2 = *(const uint4*)(eaV + (size_t)(unsigned)q1 * 8);
        e3 = *(const uint4*)(eaV + (size_t)(unsigned)q1 * 8 + 4);
    }
    while (p < p1) {
        int np = p + 2;
        int s20 = 0, s21 = 0;
        unsigned hn0 = 0, hn1 = 0;
        uint4 n0 = e0, n1 = e1, n2 = e2, n3 = e3;
        if (np < p1) {
            int qa = np;
            int qb = (np + 1 < p1) ? np + 1 : np;
            int qc = (np + 2 < p1) ? np + 2 : qb;
            int qd = (np + 3 < p1) ? np + 3 : qc;
            s20 = spV[qc]; s21 = spV[qd];           // ids for group g+2 (1-iter slack)
            hn0 = hw[(unsigned)s10 << 6];           // h for group g+1 (ids ready)
            hn1 = hw[(unsigned)s11 << 6];
            n0 = *(const uint4*)(eaV + (size_t)(unsigned)qa * 8);
            n1 = *(const uint4*)(eaV + (size_t)(unsigned)qa * 8 + 4);
            n2 = *(const uint4*)(eaV + (size_t)(unsigned)qb * 8);
            n3 = *(const uint4*)(eaV + (size_t)(unsigned)qb * 8 + 4);
        }
        edgeD(acc, bj, hu0, e0, e1, w0a, w0b, w1a, w1b);
        if (p + 1 < p1)
            edgeD(acc, bj, hu1, e2, e3, w0a, w0b, w1a, w1b);
        p = np;
        hu0 = hn0; hu1 = hn1;
        e0 = n0; e1 = n1; e2 = n2; e3 = n3;
        s10 = s20; s11 = s21;
    }
    *(v2f*)(t + ((unsigned)node << 7) + c) = acc;
}

// ====== fallback (no workspace for eaH): round-0 fp32 path via perm indirection ======
__device__ __forceinline__ void matvp(const v4f& a0, const v4f& a1,
                                      const v4f& a2, const v4f& a3,
                                      const v2f* __restrict__ w, v2f& m)
{
    m += w[0] * a0.x;  m += w[1] * a0.y;  m += w[2] * a0.z;  m += w[3] * a0.w;
    m += w[4] * a1.x;  m += w[5] * a1.y;  m += w[6] * a1.z;  m += w[7] * a1.w;
    m += w[8] * a2.x;  m += w[9] * a2.y;  m += w[10] * a2.z; m += w[11] * a2.w;
    m += w[12] * a3.x; m += w[13] * a3.y; m += w[14] * a3.z; m += w[15] * a3.w;
}

__global__ __launch_bounds__(256, 8) void aggregate_fp32(
    const unsigned short* __restrict__ h16, const float* __restrict__ eaG,
    const int* __restrict__ perm, const int* __restrict__ src_perm,
    const int* __restrict__ row_start,
    const float* __restrict__ We, const float* __restrict__ be,
    float* __restrict__ t, int Nn)
{
    int tid = threadIdx.x;
    int lane = tid & 63;
    int c = lane * 2;
    v2f w[16];
#pragma unroll
    for (int k = 0; k < 16; ++k) w[k] = *(const v2f*)&We[k * HID + c];
    v2f bj = *(const v2f*)&be[c];
    int node = blockIdx.x * 4 + (tid >> 6);
    if (node >= Nn) return;
    const unsigned* __restrict__ hw = (const unsigned*)h16 + lane;
    v2f acc = unpack2(hw[(unsigned)node << 6]);
    int p0 = __builtin_amdgcn_readfirstlane(row_start[node]);
    int p1 = __builtin_amdgcn_readfirstlane(row_start[node + 1]);
    int p = p0;
    int s0 = 0, s1 = 0, s2 = 0, s3 = 0;
    if (p + 4 <= p1) { s0 = src_perm[p]; s1 = src_perm[p + 1]; s2 = src_perm[p + 2]; s3 = src_perm[p + 3]; }
    while (p + 4 <= p1) {
        int np = p + 4;
        int t0 = 0, t1 = 0, t2 = 0, t3 = 0;
        if (np + 4 <= p1) { t0 = src_perm[np]; t1 = src_perm[np + 1]; t2 = src_perm[np + 2]; t3 = src_perm[np + 3]; }
        unsigned hu0 = hw[(unsigned)s0 << 6];
        unsigned hu1 = hw[(unsigned)s1 << 6];
        unsigned hu2 = hw[(unsigned)s2 << 6];
        unsigned hu3 = hw[(unsigned)s3 << 6];
        int q0 = perm[p], q1 = perm[p + 1], q2 = perm[p + 2], q3 = perm[p + 3];
        const v4f* e0 = (const v4f*)(eaG + (size_t)(unsigned)q0 * EDIM);
        const v4f* e1 = (const v4f*)(eaG + (size_t)(unsigned)q1 * EDIM);
        const v4f* e2 = (const v4f*)(eaG + (size_t)(unsigned)q2 * EDIM);
        const v4f* e3 = (const v4f*)(eaG + (size_t)(unsigned)q3 * EDIM);
        v4f a00 = e0[0], a01 = e0[1], a02 = e0[2], a03 = e0[3];
        v4f a10 = e1[0], a11 = e1[1], a12 = e1[2], a13 = e1[3];
        v4f a20 = e2[0], a21 = e2[1], a22 = e2[2], a23 = e2[3];
        v4f a30 = e3[0], a31 = e3[1], a32 = e3[2], a33 = e3[3];
        v2f m0 = bj + unpack2(hu0), m1 = bj + unpack2(hu1);
        v2f m2 = bj + unpack2(hu2), m3 = bj + unpack2(hu3);
        matvp(a00, a01, a02, a03, w, m0);
        matvp(a10, a11, a12, a13, w, m1);
        matvp(a20, a21, a22, a23, w, m2);
        matvp(a30, a31, a32, a33, w, m3);
        acc += (vmax0(m0) + vmax0(m1)) + (vmax0(m2) + vmax0(m3));
        p = np;
        s0 = t0; s1 = t1; s2 = t2; s3 = t3;
    }
    for (; p < p1; ++p) {
        int s = src_perm[p];
        int q = perm[p];
        const v4f* e0 = (const v4f*)(eaG + (size_t)(unsigned)q * EDIM);
        v4f a0 = e0[0], a1 = e0[1], a2 = e0[2], a3 = e0[3];
        v2f m0 = bj + unpack2(hw[(unsigned)s << 6]);
        matvp(a0, a1, a2, a3, w, m0);
        acc += vmax0(m0);
    }
    *(v2f*)(t + ((unsigned)node << 7) + c) = acc;
}

// ================= split-bf16 MFMA GEMM =================
#define LPAD 40

template<int K, bool PRE_BN, bool POST_STATS, bool OUT_BF16>
__global__ __launch_bounds__(256) void gemm_mfma(
    const float* __restrict__ A, const unsigned short* __restrict__ Wh,
    const unsigned short* __restrict__ Wl, const float* __restrict__ bias,
    const float* __restrict__ preStats, const float* __restrict__ preG, const float* __restrict__ preB,
    void* __restrict__ Cout, float* __restrict__ postStats, int Nrows, float invN)
{
    __shared__ __align__(16) unsigned short Ah[128 * LPAD], Al[128 * LPAD];
    __shared__ __align__(16) unsigned short Bh[128 * LPAD], Bl[128 * LPAD];
    __shared__ float sc[PRE_BN ? K : 1], sb[PRE_BN ? K : 1];
    int tid = threadIdx.x;
    int rbase = blockIdx.x * 128;
    if (PRE_BN) {
        if (tid < K) {
            float mean = preStats[tid] * invN;
            float var = preStats[K + tid] * invN - mean * mean;
            float rstd = rsqrtf(var + 1e-5f);
            float g = preG[tid];
            sc[tid] = rstd * g;
            sb[tid] = preB[tid] - mean * rstd * g;
        }
        __syncthreads();
    }
    int w = tid >> 6, nl = tid & 15, q = (tid >> 4) & 3;
    f4v acc[2][8];
#pragma unroll
    for (int mt = 0; mt < 2; ++mt)
#pragma unroll
        for (int nt = 0; nt < 8; ++nt)
#pragma unroll
            for (int r = 0; r < 4; ++r) acc[mt][nt][r] = 0.f;

    for (int ks = 0; ks < K / 32; ++ks) {
        int k0 = ks * 32;
        if (ks) __syncthreads();
#pragma unroll
        for (int i = 0; i < 4; ++i) {
            int cidx = tid + i * 256;
            int m = cidx >> 3, k4 = (cidx & 7) * 4;
            int gr = rbase + m;
            float4 v = make_float4(0.f, 0.f, 0.f, 0.f);
            if (gr < Nrows) v = *(const float4*)&A[(size_t)gr * K + k0 + k4];
            if (PRE_BN) {
                v.x = fmaxf(v.x * sc[k0 + k4]     + sb[k0 + k4],     0.f);
                v.y = fmaxf(v.y * sc[k0 + k4 + 1] + sb[k0 + k4 + 1], 0.f);
                v.z = fmaxf(v.z * sc[k0 + k4 + 2] + sb[k0 + k4 + 2], 0.f);
                v.w = fmaxf(v.w * sc[k0 + k4 + 3] + sb[k0 + k4 + 3], 0.f);
            }
            unsigned short h0, l0, h1, l1, h2, l2, h3, l3;
            split_bf16(v.x, h0, l0); split_bf16(v.y, h1, l1);
            split_bf16(v.z, h2, l2); split_bf16(v.w, h3, l3);
            uint2 hp, lp;
            hp.x = (unsigned)h0 | ((unsigned)h1 << 16); hp.y = (unsigned)h2 | ((unsigned)h3 << 16);
            lp.x = (unsigned)l0 | ((unsigned)l1 << 16); lp.y = (unsigned)l2 | ((unsigned)l3 << 16);
            *(uint2*)&Ah[m * LPAD + k4] = hp;
            *(uint2*)&Al[m * LPAD + k4] = lp;
        }
#pragma unroll
        for (int i = 0; i < 2; ++i) {
            int g = tid + i * 256;
            int n = g >> 2, kq = (g & 3) * 8;
            uint4 hv = *(const uint4*)&Wh[(size_t)n * K + k0 + kq];
            uint4 lv = *(const uint4*)&Wl[(size_t)n * K + k0 + kq];
            *(uint4*)&Bh[n * LPAD + kq] = hv;
            *(uint4*)&Bl[n * LPAD + kq] = lv;
        }
        __syncthreads();
        s8v ah0 = *(const s8v*)&Ah[(w * 32 + nl) * LPAD + q * 8];
        s8v ah1 = *(const s8v*)&Ah[(w * 32 + 16 + nl) * LPAD + q * 8];
        s8v al0 = *(const s8v*)&Al[(w * 32 + nl) * LPAD + q * 8];
        s8v al1 = *(const s8v*)&Al[(w * 32 + 16 + nl) * LPAD + q * 8];
#pragma unroll
        for (int nt = 0; nt < 8; ++nt) {
            s8v bh = *(const s8v*)&Bh[(nt * 16 + nl) * LPAD + q * 8];
            s8v bl = *(const s8v*)&Bl[(nt * 16 + nl) * LPAD + q * 8];
            acc[0][nt] = MFMA_BF16(ah0, bh, acc[0][nt]);
            acc[0][nt] = MFMA_BF16(ah0, bl, acc[0][nt]);
            acc[0][nt] = MFMA_BF16(al0, bh, acc[0][nt]);
            acc[1][nt] = MFMA_BF16(ah1, bh, acc[1][nt]);
            acc[1][nt] = MFMA_BF16(ah1, bl, acc[1][nt]);
            acc[1][nt] = MFMA_BF16(al1, bh, acc[1][nt]);
        }
    }
    __syncthreads();

    float* Cf = (float*)Cout;
    unsigned short* Ch = (unsigned short*)Cout;
    float* redS = (float*)Ah;
    float* redQ = (float*)Al;
#pragma unroll
    for (int nt = 0; nt < 8; ++nt) {
        int col = nt * 16 + nl;
        float bcol = bias[col];
        float sv = 0.f, qv = 0.f;
#pragma unroll
        for (int mt = 0; mt < 2; ++mt) {
#pragma unroll
            for (int r = 0; r < 4; ++r) {
                int grow = rbase + w * 32 + mt * 16 + q * 4 + r;
                if (grow < Nrows) {
                    float o = acc[mt][nt][r] + bcol;
                    if (OUT_BF16) Ch[(size_t)grow * HID + col] = bf16_rne(o);
                    else          Cf[(size_t)grow * HID + col] = o;
                    if (POST_STATS) { sv += o; qv += o * o; }
                }
            }
        }
        if (POST_STATS) {
            sv += __shfl_down(sv, 32, 64); sv += __shfl_down(sv, 16, 64);
            qv += __shfl_down(qv, 32, 64); qv += __shfl_down(qv, 16, 64);
            if ((tid & 63) < 16) { redS[w * 128 + col] = sv; redQ[w * 128 + col] = qv; }
        }
    }
    if (POST_STATS) {
        __syncthreads();
        if (tid < 128) {
            float S = redS[tid] + redS[128 + tid] + redS[256 + tid] + redS[384 + tid];
            float Q = redQ[tid] + redQ[128 + tid] + redQ[256 + tid] + redQ[384 + tid];
            atomicAdd(&postStats[tid], S);
            atomicAdd(&postStats[128 + tid], Q);
        }
    }
}

// ======== fused BN apply + ReLU + pool; h stored as packed bf16 (pool uses exact fp32) ========
__global__ void bn_apply_pool(const float* __restrict__ X, unsigned short* __restrict__ h16,
                              const float* __restrict__ stats, const float* __restrict__ g,
                              const float* __restrict__ b, const int* __restrict__ starts,
                              float* __restrict__ z, int l, float invN)
{
    int gph = blockIdx.x;
    int tid = threadIdx.x;
    int ch4 = (tid & 31) * 4, wk = tid >> 5;   // 16 walkers x 32 lanes(float4)
    float sc[4], sh[4];
#pragma unroll
    for (int u = 0; u < 4; ++u) {
        int j = ch4 + u;
        float mean = stats[j] * invN;
        float var = stats[128 + j] * invN - mean * mean;
        float rstd = rsqrtf(var + 1e-5f);
        float gg = g[j];
        sc[u] = rstd * gg;
        sh[u] = b[j] - mean * rstd * gg;
    }
    int s = starts[gph], e = starts[gph + 1];
    float4 sum = make_float4(0.f, 0.f, 0.f, 0.f);
    float4 mx = make_float4(0.f, 0.f, 0.f, 0.f);
    unsigned* hv32 = (unsigned*)h16;
    for (int n = s + wk; n < e; n += 16) {
        float4 v = *(const float4*)&X[(size_t)n * HID + ch4];
        v.x = fmaxf(v.x * sc[0] + sh[0], 0.f);
        v.y = fmaxf(v.y * sc[1] + sh[1], 0.f);
        v.z = fmaxf(v.z * sc[2] + sh[2], 0.f);
        v.w = fmaxf(v.w * sc[3] + sh[3], 0.f);
        uint2 pk;
        pk.x = pack2(v.x, v.y);
        pk.y = pack2(v.z, v.w);
        *(uint2*)&hv32[(size_t)n * 64 + (ch4 >> 1)] = pk;
        sum.x += v.x; sum.y += v.y; sum.z += v.z; sum.w += v.w;
        mx.x = fmaxf(mx.x, v.x); mx.y = fmaxf(mx.y, v.y);
        mx.z = fmaxf(mx.z, v.z); mx.w = fmaxf(mx.w, v.w);
    }
    __shared__ float ls[16 * 128], lm[16 * 128];
    *(float4*)&ls[wk * 128 + ch4] = sum;
    *(float4*)&lm[wk * 128 + ch4] = mx;
    __syncthreads();
    if (tid < 128) {
        float S = 0.f, M = 0.f;
#pragma unroll
        for (int k = 0; k < 16; ++k) {
            S += ls[k * 128 + tid];
            M = fmaxf(M, lm[k * 128 + tid]);
        }
        float cnt = (float)(e - s);
        z[(size_t)gph * 768 + l * 128 + tid] = S / fmaxf(cnt, 1.f);
        z[(size_t)gph * 768 + 384 + l * 128 + tid] = M;
    }
}

// ================= segment boundaries (batch sorted) =================
__global__ void starts_kernel(const int* __restrict__ batch, int* __restrict__ starts,
                              int Nn, int Gn)
{
    int g = blockIdx.x * blockDim.x + threadIdx.x;
    if (g > Gn) return;
    int lo = 0, hi = Nn;
    while (lo < hi) { int mid = (lo + hi) >> 1; if (batch[mid] < g) lo = mid + 1; else hi = mid; }
    starts[g] = lo;
}

// ================= head =================
__global__ void head_gemm1(const float* __restrict__ z, const float* __restrict__ W,
                           const float* __restrict__ bias, float* __restrict__ zr,
                           float* __restrict__ msums)
{
    __shared__ __align__(16) float zl[768];
    int g = blockIdx.x, j = threadIdx.x;
    for (int i = j; i < 768; i += 128) zl[i] = z[(size_t)g * 768 + i];
    __syncthreads();
    float acc = bias[j];
    for (int k = 0; k < 768; k += 4) {
        float4 a4 = *(const float4*)&zl[k];
        acc += a4.x * W[k * 128 + j] + a4.y * W[(k + 1) * 128 + j]
             + a4.z * W[(k + 2) * 128 + j] + a4.w * W[(k + 3) * 128 + j];
    }
    zr[(size_t)g * 128 + j] = acc;
    atomicAdd(&msums[j], acc);
    atomicAdd(&msums[128 + j], acc * acc);
}

__global__ void head_final(const float* __restrict__ zr, const float* __restrict__ msums,
                           const float* __restrict__ hg, const float* __restrict__ hb,
                           const float* __restrict__ W2, const float* __restrict__ b2,
                           float* __restrict__ out, float invG)
{
    int g = blockIdx.x, j = threadIdx.x;
    float mean = msums[j] * invG;
    float var = msums[128 + j] * invG - mean * mean;
    float rstd = rsqrtf(var + 1e-5f);
    float v = zr[(size_t)g * 128 + j];
    v = (v - mean) * rstd * hg[j] + hb[j];
    v = fmaxf(v, 0.f);
    float p = v * W2[j];
#pragma unroll
    for (int off = 32; off > 0; off >>= 1) p += __shfl_down(p, off, 64);
    __shared__ float partial[2];
    if ((j & 63) == 0) partial[j >> 6] = p;
    __syncthreads();
    if (j == 0) out[g] = partial[0] + partial[1] + b2[0];
}

extern "C" void kernel_launch(void* const* d_in, const int* in_sizes, int n_in,
                              void* d_out, int out_size, void* d_ws, size_t ws_size,
                              hipStream_t stream)
{
    const float* x         = (const float*)d_in[0];
    const float* edge_attr = (const float*)d_in[1];
    const int*   src       = (const int*)d_in[2];
    const int*   dst       = (const int*)d_in[3];
    const int*   batch     = (const int*)d_in[4];
    const float* Wp        = (const float*)d_in[5];
    const float* bp        = (const float*)d_in[6];
    const float* conv_We   = (const float*)d_in[7];
    const float* conv_be   = (const float*)d_in[8];
    const float* conv_W1   = (const float*)d_in[9];
    const float* conv_b1   = (const float*)d_in[10];
    const float* conv_g1   = (const float*)d_in[11];
    const float* conv_bt1  = (const float*)d_in[12];
    const float* conv_W2   = (const float*)d_in[13];
    const float* conv_b2   = (const float*)d_in[14];
    const float* bn_g      = (const float*)d_in[15];
    const float* bn_b      = (const float*)d_in[16];
    const float* head_W1   = (const float*)d_in[17];
    const float* head_b1   = (const float*)d_in[18];
    const float* head_g    = (const float*)d_in[19];
    const float* head_bt   = (const float*)d_in[20];
    const float* head_W2   = (const float*)d_in[21];
    const float* head_b2   = (const float*)d_in[22];

    const int N = in_sizes[4];            // 50000
    const int E = in_sizes[2];            // 800000
    const int G = out_size;               // 256
    const int L = 3;

    // ---- workspace layout ----
    float* t        = (float*)d_ws;                  // N*128 fp32
    unsigned short* h16 = (unsigned short*)(t + (size_t)N * HID);  // N*128 bf16
    float* z        = (float*)(h16 + (size_t)N * HID);             // G*768
    float* zr       = z + (size_t)G * 768;           // G*128
    float* statsAll = zr + (size_t)G * HID;          // 7*256
    int*   deg      = (int*)(statsAll + 7 * 256);    // N
    int*   starts   = deg + N;                       // G+1
    int*   row_start= starts + (G + 1);              // N+1
    int*   cursor   = row_start + (N + 1);           // N
    int*   bsum     = cursor + N;                    // 256
    int*   src_perm = bsum + 256;                    // E
    int*   perm     = src_perm + E;                  // E
    unsigned short* wt = (unsigned short*)(perm + E);  // 212992 ushorts gemm weights
    unsigned* wef   = (unsigned*)(wt + 212992);      // 3*1024 u32 f16-pair We table
    size_t base_end = (size_t)((char*)(wef + 3 * 1024) - (char*)d_ws);
    size_t ea_off = (base_end + 63) & ~(size_t)63;   // 64B-align ea rows
    bool gath = (ea_off + (size_t)E * 8 * sizeof(unsigned)) <= ws_size;  // f16 rows: 32B/edge
    unsigned* eaH = (unsigned*)((char*)d_ws + ea_off);
    float* msums = statsAll + 6 * 256;

    (void)n_in;

    const float invN = 1.0f / (float)N;
    const float invG = 1.0f / (float)G;
    const int nb = (N + 255) / 256;
    const int gemmBlocks = (N + 127) / 128;

    // ---- CSR build + weight prep ----
    (void)hipMemsetAsync(statsAll, 0, 7 * 256 * sizeof(float) + (size_t)N * sizeof(int), stream);
    hist_kernel<<<(E + 255) / 256, 256, 0, stream>>>(dst, deg, E);
    block_sum_kernel<<<nb, 256, 0, stream>>>(deg, bsum, N);
    bsum_scan_kernel<<<1, 256, 0, stream>>>(bsum, nb, &row_start[N]);
    block_scan_kernel<<<nb, 256, 0, stream>>>(deg, bsum, row_start, cursor, N);
    scatter_kernel<<<(E + 255) / 256, 256, 0, stream>>>(src, dst, cursor, perm, src_perm, E);
    if (gath)
        gather_ea_f16<<<(E * 2 + 255) / 256, 256, 0, stream>>>(edge_attr, perm, eaH, E);
    starts_kernel<<<1, 512, 0, stream>>>(batch, starts, N, G);
    prep_weights<<<(8192 + 6 * 16384 + 255) / 256, 256, 0, stream>>>(Wp, conv_W1, conv_W2, wt);
    prep_wef16<<<(3 * 1024 + 255) / 256, 256, 0, stream>>>(conv_We, wef);

    const unsigned short* Wp_hi = wt;
    const unsigned short* Wp_lo = wt + 8192;

    // h16 = bf16(x @ Wp + bp)
    gemm_mfma<64, false, false, true><<<gemmBlocks, 256, 0, stream>>>(
        x, Wp_hi, Wp_lo, bp, nullptr, nullptr, nullptr, h16, nullptr, N, invN);

    for (int l = 0; l < L; ++l) {
        float* sI = statsAll + l * 512;
        float* sO = sI + 256;
        const unsigned short* W1hi = wt + 16384 + (size_t)(2 * l) * 32768;
        const unsigned short* W1lo = W1hi + 16384;
        const unsigned short* W2hi = wt + 16384 + (size_t)(2 * l + 1) * 32768;
        const unsigned short* W2lo = W2hi + 16384;
        if (gath)
            aggregate_f16<<<(N + 3) / 4, 256, 0, stream>>>(
                h16, eaH, src_perm, row_start, wef + (size_t)l * 1024,
                conv_be + l * HID, t, N);
        else
            aggregate_fp32<<<(N + 3) / 4, 256, 0, stream>>>(
                h16, edge_attr, perm, src_perm, row_start,
                conv_We + (size_t)l * EDIM * HID, conv_be + l * HID, t, N);
        gemm_mfma<128, false, true, false><<<gemmBlocks, 256, 0, stream>>>(
            t, W1hi, W1lo, conv_b1 + l * HID,
            nullptr, nullptr, nullptr, t, sI, N, invN);
        gemm_mfma<128, true, true, false><<<gemmBlocks, 256, 0, stream>>>(
            t, W2hi, W2lo, conv_b2 + l * HID,
            sI, conv_g1 + l * HID, conv_bt1 + l * HID, t, sO, N, invN);
        bn_apply_pool<<<G, 512, 0, stream>>>(
            t, h16, sO, bn_g + l * HID, bn_b + l * HID, starts, z, l, invN);
    }

    head_gemm1<<<G, 128, 0, stream>>>(z, head_W1, head_b1, zr, msums);
    head_final<<<G, 128, 0, stream>>>(zr, msums, head_g, head_bt, head_W2, head_b2,
                                      (float*)d_out, invG);
}

// Round 9
// 679.603 us; speedup vs baseline: 1.1037x; 1.1037x over previous
//
#include <hip/hip_runtime.h>
#include <hip/hip_bf16.h>
#include <hip/hip_fp16.h>

#define HID 128
#define EDIM 16

typedef float v4f __attribute__((ext_vector_type(4)));
typedef float v2f __attribute__((ext_vector_type(2)));
typedef short s8v __attribute__((ext_vector_type(8)));   // 8 bf16 (4 VGPRs) MFMA frag
typedef float f4v __attribute__((ext_vector_type(4)));   // MFMA acc
typedef unsigned int u8x __attribute__((ext_vector_type(8)));  // 8 dwords = 16 f16
typedef _Float16 h2v __attribute__((ext_vector_type(2)));      // f16 pair for fdot2

#define MFMA_BF16(a, b, c) __builtin_amdgcn_mfma_f32_16x16x32_bf16((a), (b), (c), 0, 0, 0)

__device__ __forceinline__ unsigned short bf16_rne(float v)
{
    unsigned u = __builtin_bit_cast(unsigned, v);
    return (unsigned short)((u + 0x7fffu + ((u >> 16) & 1u)) >> 16);
}

__device__ __forceinline__ unsigned pack2(float lo, float hi)
{
    return (unsigned)bf16_rne(lo) | ((unsigned)bf16_rne(hi) << 16);
}

__device__ __forceinline__ float bflo(unsigned u) { return __builtin_bit_cast(float, u << 16); }
__device__ __forceinline__ float bfhi(unsigned u) { return __builtin_bit_cast(float, u & 0xffff0000u); }

__device__ __forceinline__ v2f unpack2(unsigned u)
{
    v2f r; r.x = bflo(u); r.y = bfhi(u); return r;
}

__device__ __forceinline__ void split_bf16(float v, unsigned short& h, unsigned short& l)
{
    unsigned u = __builtin_bit_cast(unsigned, v);
    unsigned hu = (u + 0x7fffu + ((u >> 16) & 1u)) >> 16;
    h = (unsigned short)hu;
    float hf = __builtin_bit_cast(float, hu << 16);
    l = bf16_rne(v - hf);
}

__device__ __forceinline__ v2f vmax0(v2f a)
{
    v2f r; r.x = fmaxf(a.x, 0.f); r.y = fmaxf(a.y, 0.f); return r;
}

// pack two floats to f16x2 (RNE)
__device__ __forceinline__ unsigned pkh2(float lo, float hi)
{
    return (unsigned)__half_as_ushort(__float2half(lo)) |
           ((unsigned)__half_as_ushort(__float2half(hi)) << 16);
}

// d += ea.lo*w.lo + ea.hi*w.hi (fp32 accumulate). Builtin (NOT bare asm): bare
// VOP3P asm assembles wrong default modifiers (round-6 absmax 0.54).
__device__ __forceinline__ void dot2(float& d, unsigned ea, unsigned w)
{
    d = __builtin_amdgcn_fdot2(__builtin_bit_cast(h2v, ea),
                               __builtin_bit_cast(h2v, w), d, false);
}

// ================= CSR build =================
__global__ void hist_kernel(const int* __restrict__ dst, int* __restrict__ deg, int E)
{
    int e = blockIdx.x * 256 + threadIdx.x;
    if (e < E) atomicAdd(&deg[dst[e]], 1);
}

__global__ void block_sum_kernel(const int* __restrict__ deg, int* __restrict__ bsum, int Nn)
{
    int i = blockIdx.x * 256 + threadIdx.x;
    int v = (i < Nn) ? deg[i] : 0;
#pragma unroll
    for (int off = 32; off > 0; off >>= 1) v += __shfl_down(v, off, 64);
    __shared__ int ws[4];
    if ((threadIdx.x & 63) == 0) ws[threadIdx.x >> 6] = v;
    __syncthreads();
    if (threadIdx.x == 0) bsum[blockIdx.x] = ws[0] + ws[1] + ws[2] + ws[3];
}

__global__ void bsum_scan_kernel(int* bsum, int nb, int* total_out)
{
    __shared__ int sh[256];
    int tid = threadIdx.x;
    int v = (tid < nb) ? bsum[tid] : 0;
    sh[tid] = v;
    __syncthreads();
    for (int off = 1; off < 256; off <<= 1) {
        int tv = (tid >= off) ? sh[tid - off] : 0;
        __syncthreads();
        sh[tid] += tv;
        __syncthreads();
    }
    if (tid < nb) bsum[tid] = sh[tid] - v;
    if (tid == 255) *total_out = sh[255];
}

__global__ void block_scan_kernel(const int* __restrict__ deg, const int* __restrict__ bsum,
                                  int* __restrict__ row_start, int* __restrict__ cursor, int Nn)
{
    __shared__ int sh[256];
    int tid = threadIdx.x;
    int i = blockIdx.x * 256 + tid;
    int v = (i < Nn) ? deg[i] : 0;
    sh[tid] = v;
    __syncthreads();
    for (int off = 1; off < 256; off <<= 1) {
        int tv = (tid >= off) ? sh[tid - off] : 0;
        __syncthreads();
        sh[tid] += tv;
        __syncthreads();
    }
    if (i < Nn) {
        int excl = sh[tid] - v + bsum[blockIdx.x];
        row_start[i] = excl;
        cursor[i] = excl;
    }
}

// phase 1: permutation only (12B/edge traffic; scattered 4B writes live in L2)
__global__ void scatter_kernel(const int* __restrict__ src, const int* __restrict__ dst,
                               int* cursor, int* __restrict__ perm,
                               int* __restrict__ src_perm, int E)
{
    int e = blockIdx.x * 256 + threadIdx.x;
    if (e >= E) return;
    int pos = atomicAdd(&cursor[dst[e]], 1);
    perm[pos] = e;
    src_perm[pos] = src[e];
}

// phase 2: ea permute-copy + f16 convert — scattered READS, coalesced 16B writes.
// 2 threads per edge row; row = 8 dwords (16 f16).
__global__ void gather_ea_f16(const float* __restrict__ ea, const int* __restrict__ perm,
                              unsigned* __restrict__ eaH, int E)
{
    int idx = blockIdx.x * 256 + threadIdx.x;
    int p = idx >> 1, hf = idx & 1;
    if (p >= E) return;
    int e = perm[p];
    const float* ap = &ea[(size_t)e * EDIM + hf * 8];
    float4 f0 = *(const float4*)ap;
    float4 f1 = *(const float4*)(ap + 4);
    uint4 o;
    o.x = pkh2(f0.x, f0.y);
    o.y = pkh2(f0.z, f0.w);
    o.z = pkh2(f1.x, f1.y);
    o.w = pkh2(f1.z, f1.w);
    *(uint4*)&eaH[(size_t)p * 8 + hf * 4] = o;
}

// ================= weight prep: fp32 [K,128] -> transposed split-bf16 [128,K] hi/lo =================
__global__ void prep_weights(const float* __restrict__ Wp, const float* __restrict__ W1,
                             const float* __restrict__ W2, unsigned short* __restrict__ out)
{
    int idx = blockIdx.x * 256 + threadIdx.x;
    if (idx < 8192) {
        int n = idx >> 6, k = idx & 63;
        unsigned short h, l;
        split_bf16(Wp[k * 128 + n], h, l);
        out[idx] = h;
        out[8192 + idx] = l;
    } else {
        int j = idx - 8192;
        if (j >= 6 * 16384) return;
        int m2 = j >> 14;
        int r = j & 16383;
        int n = r >> 7, k = r & 127;
        int l = m2 >> 1;
        const float* Wsrc = (m2 & 1) ? (W2 + l * 16384) : (W1 + l * 16384);
        unsigned short h, lo;
        split_bf16(Wsrc[k * 128 + n], h, lo);
        int base = 16384 + m2 * 32768;
        out[base + r] = h;
        out[base + 16384 + r] = lo;
    }
}

// ===== f16-pair We table for aggregation: out[l][ch][kp] = pkh2(We[2kp][ch], We[2kp+1][ch]) =====
__global__ void prep_wef16(const float* __restrict__ We, unsigned* __restrict__ out)
{
    int idx = blockIdx.x * 256 + threadIdx.x;
    if (idx >= 3 * 1024) return;
    int l = idx >> 10, r = idx & 1023, ch = r >> 3, kp = r & 7;
    const float* W = We + (size_t)l * EDIM * HID;
    out[idx] = pkh2(W[(2 * kp) * HID + ch], W[(2 * kp + 1) * HID + ch]);
}

// ====== Node-centric aggregation v7: r7 structure + clamped masked tail ======
// 1 wave/node, 2 ch/lane. ea rows wave-uniform -> SGPR (SMEM, scalar pipe);
// 16 fdot2/edge. EVERY group is a clamped 8-group (indices min(i, p1-1), SALU)
// with wave-uniform per-edge guards -> exactly ceil(deg/8) lgkmcnt drains per
// node (r7's scalar tail paid one drain PER tail edge). f16 weight pairs from
// the prep_wef16 table (saves 16 pkh2 + 32 loads per thread).
__device__ __forceinline__ void edge_f16(v2f& acc, v2f bj, unsigned hu, const u8x& e,
                                         uint4 w0a, uint4 w0b, uint4 w1a, uint4 w1b)
{
    float m0 = bj.x + bflo(hu);
    float m1 = bj.y + bfhi(hu);
    dot2(m0, e[0], w0a.x); dot2(m1, e[0], w1a.x);
    dot2(m0, e[1], w0a.y); dot2(m1, e[1], w1a.y);
    dot2(m0, e[2], w0a.z); dot2(m1, e[2], w1a.z);
    dot2(m0, e[3], w0a.w); dot2(m1, e[3], w1a.w);
    dot2(m0, e[4], w0b.x); dot2(m1, e[4], w1b.x);
    dot2(m0, e[5], w0b.y); dot2(m1, e[5], w1b.y);
    dot2(m0, e[6], w0b.z); dot2(m1, e[6], w1b.z);
    dot2(m0, e[7], w0b.w); dot2(m1, e[7], w1b.w);
    acc.x += fmaxf(m0, 0.f);
    acc.y += fmaxf(m1, 0.f);
}

__global__ __launch_bounds__(256, 8) void aggregate_f16(
    const unsigned short* __restrict__ h16, const unsigned* __restrict__ eaH,
    const int* __restrict__ src_perm, const int* __restrict__ row_start,
    const unsigned* __restrict__ Wpk, const float* __restrict__ be,
    float* __restrict__ t, int Nn)
{
    int tid = threadIdx.x;
    int lane = tid & 63;
    int c = lane * 2;
    int node = blockIdx.x * 4 + (tid >> 6);
    if (node >= Nn) return;
    const uint4* wrow = (const uint4*)(Wpk + (size_t)c * 8);
    uint4 w0a = wrow[0], w0b = wrow[1];   // channel c
    uint4 w1a = wrow[2], w1b = wrow[3];   // channel c+1
    v2f bj = *(const v2f*)&be[c];
    const unsigned* __restrict__ hw = (const unsigned*)h16 + lane;  // bf16 ch-pair per lane
    v2f acc = unpack2(hw[(unsigned)node << 6]);
    int p0 = __builtin_amdgcn_readfirstlane(row_start[node]);
    int p1 = __builtin_amdgcn_readfirstlane(row_start[node + 1]);
    if (p0 < p1) {
        int last = p1 - 1;
        int ng = (p1 - p0 + 7) >> 3;
#define CL(x) ((x) < last ? (x) : last)
        // prologue: src ids + h rows for group 0 (clamped; all index math SALU)
        int s0 = src_perm[p0];
        int s1 = src_perm[CL(p0 + 1)];
        int s2 = src_perm[CL(p0 + 2)];
        int s3 = src_perm[CL(p0 + 3)];
        int s4 = src_perm[CL(p0 + 4)];
        int s5 = src_perm[CL(p0 + 5)];
        int s6 = src_perm[CL(p0 + 6)];
        int s7 = src_perm[CL(p0 + 7)];
        unsigned hu0 = hw[(unsigned)s0 << 6];
        unsigned hu1 = hw[(unsigned)s1 << 6];
        unsigned hu2 = hw[(unsigned)s2 << 6];
        unsigned hu3 = hw[(unsigned)s3 << 6];
        unsigned hu4 = hw[(unsigned)s4 << 6];
        unsigned hu5 = hw[(unsigned)s5 << 6];
        unsigned hu6 = hw[(unsigned)s6 << 6];
        unsigned hu7 = hw[(unsigned)s7 << 6];
        for (int g = 0; g < ng; ++g) {
            int b = p0 + g * 8;
            // current group's ea rows (SMEM, clamped)
            u8x e0 = *(const u8x*)(eaH + (size_t)(unsigned)b * 8);
            u8x e1 = *(const u8x*)(eaH + (size_t)(unsigned)CL(b + 1) * 8);
            u8x e2 = *(const u8x*)(eaH + (size_t)(unsigned)CL(b + 2) * 8);
            u8x e3 = *(const u8x*)(eaH + (size_t)(unsigned)CL(b + 3) * 8);
            u8x e4 = *(const u8x*)(eaH + (size_t)(unsigned)CL(b + 4) * 8);
            u8x e5 = *(const u8x*)(eaH + (size_t)(unsigned)CL(b + 5) * 8);
            u8x e6 = *(const u8x*)(eaH + (size_t)(unsigned)CL(b + 6) * 8);
            u8x e7 = *(const u8x*)(eaH + (size_t)(unsigned)CL(b + 7) * 8);
            // next group's src ids (SMEM, clamped) + h rows (VMEM prefetch)
            int nb = b + 8;
            int t0 = src_perm[CL(nb)];
            int t1 = src_perm[CL(nb + 1)];
            int t2 = src_perm[CL(nb + 2)];
            int t3 = src_perm[CL(nb + 3)];
            int t4 = src_perm[CL(nb + 4)];
            int t5 = src_perm[CL(nb + 5)];
            int t6 = src_perm[CL(nb + 6)];
            int t7 = src_perm[CL(nb + 7)];
            unsigned hn0 = hw[(unsigned)t0 << 6];
            unsigned hn1 = hw[(unsigned)t1 << 6];
            unsigned hn2 = hw[(unsigned)t2 << 6];
            unsigned hn3 = hw[(unsigned)t3 << 6];
            unsigned hn4 = hw[(unsigned)t4 << 6];
            unsigned hn5 = hw[(unsigned)t5 << 6];
            unsigned hn6 = hw[(unsigned)t6 << 6];
            unsigned hn7 = hw[(unsigned)t7 << 6];
            // compute; per-edge guards are wave-uniform (scalar cmp + branch)
            edge_f16(acc, bj, hu0, e0, w0a, w0b, w1a, w1b);   // b < p1 always
            if (b + 1 <= last) edge_f16(acc, bj, hu1, e1, w0a, w0b, w1a, w1b);
            if (b + 2 <= last) edge_f16(acc, bj, hu2, e2, w0a, w0b, w1a, w1b);
            if (b + 3 <= last) edge_f16(acc, bj, hu3, e3, w0a, w0b, w1a, w1b);
            if (b + 4 <= last) edge_f16(acc, bj, hu4, e4, w0a, w0b, w1a, w1b);
            if (b + 5 <= last) edge_f16(acc, bj, hu5, e5, w0a, w0b, w1a, w1b);
            if (b + 6 <= last) edge_f16(acc, bj, hu6, e6, w0a, w0b, w1a, w1b);
            if (b + 7 <= last) edge_f16(acc, bj, hu7, e7, w0a, w0b, w1a, w1b);
            hu0 = hn0; hu1 = hn1; hu2 = hn2; hu3 = hn3;
            hu4 = hn4; hu5 = hn5; hu6 = hn6; hu7 = hn7;
        }
#undef CL
    }
    *(v2f*)(t + ((unsigned)node << 7) + c) = acc;
}

// ====== fallback (no workspace for eaH): round-0 fp32 path via perm indirection ======
__device__ __forceinline__ void matvp(const v4f& a0, const v4f& a1,
                                      const v4f& a2, const v4f& a3,
                                      const v2f* __restrict__ w, v2f& m)
{
    m += w[0] * a0.x;  m += w[1] * a0.y;  m += w[2] * a0.z;  m += w[3] * a0.w;
    m += w[4] * a1.x;  m += w[5] * a1.y;  m += w[6] * a1.z;  m += w[7] * a1.w;
    m += w[8] * a2.x;  m += w[9] * a2.y;  m += w[10] * a2.z; m += w[11] * a2.w;
    m += w[12] * a3.x; m += w[13] * a3.y; m += w[14] * a3.z; m += w[15] * a3.w;
}

__global__ __launch_bounds__(256, 8) void aggregate_fp32(
    const unsigned short* __restrict__ h16, const float* __restrict__ eaG,
    const int* __restrict__ perm, const int* __restrict__ src_perm,
    const int* __restrict__ row_start,
    const float* __restrict__ We, const float* __restrict__ be,
    float* __restrict__ t, int Nn)
{
    int tid = threadIdx.x;
    int lane = tid & 63;
    int c = lane * 2;
    v2f w[16];
#pragma unroll
    for (int k = 0; k < 16; ++k) w[k] = *(const v2f*)&We[k * HID + c];
    v2f bj = *(const v2f*)&be[c];
    int node = blockIdx.x * 4 + (tid >> 6);
    if (node >= Nn) return;
    const unsigned* __restrict__ hw = (const unsigned*)h16 + lane;
    v2f acc = unpack2(hw[(unsigned)node << 6]);
    int p0 = __builtin_amdgcn_readfirstlane(row_start[node]);
    int p1 = __builtin_amdgcn_readfirstlane(row_start[node + 1]);
    int p = p0;
    int s0 = 0, s1 = 0, s2 = 0, s3 = 0;
    if (p + 4 <= p1) { s0 = src_perm[p]; s1 = src_perm[p + 1]; s2 = src_perm[p + 2]; s3 = src_perm[p + 3]; }
    while (p + 4 <= p1) {
        int np = p + 4;
        int t0 = 0, t1 = 0, t2 = 0, t3 = 0;
        if (np + 4 <= p1) { t0 = src_perm[np]; t1 = src_perm[np + 1]; t2 = src_perm[np + 2]; t3 = src_perm[np + 3]; }
        unsigned hu0 = hw[(unsigned)s0 << 6];
        unsigned hu1 = hw[(unsigned)s1 << 6];
        unsigned hu2 = hw[(unsigned)s2 << 6];
        unsigned hu3 = hw[(unsigned)s3 << 6];
        int q0 = perm[p], q1 = perm[p + 1], q2 = perm[p + 2], q3 = perm[p + 3];
        const v4f* e0 = (const v4f*)(eaG + (size_t)(unsigned)q0 * EDIM);
        const v4f* e1 = (const v4f*)(eaG + (size_t)(unsigned)q1 * EDIM);
        const v4f* e2 = (const v4f*)(eaG + (size_t)(unsigned)q2 * EDIM);
        const v4f* e3 = (const v4f*)(eaG + (size_t)(unsigned)q3 * EDIM);
        v4f a00 = e0[0], a01 = e0[1], a02 = e0[2], a03 = e0[3];
        v4f a10 = e1[0], a11 = e1[1], a12 = e1[2], a13 = e1[3];
        v4f a20 = e2[0], a21 = e2[1], a22 = e2[2], a23 = e2[3];
        v4f a30 = e3[0], a31 = e3[1], a32 = e3[2], a33 = e3[3];
        v2f m0 = bj + unpack2(hu0), m1 = bj + unpack2(hu1);
        v2f m2 = bj + unpack2(hu2), m3 = bj + unpack2(hu3);
        matvp(a00, a01, a02, a03, w, m0);
        matvp(a10, a11, a12, a13, w, m1);
        matvp(a20, a21, a22, a23, w, m2);
        matvp(a30, a31, a32, a33, w, m3);
        acc += (vmax0(m0) + vmax0(m1)) + (vmax0(m2) + vmax0(m3));
        p = np;
        s0 = t0; s1 = t1; s2 = t2; s3 = t3;
    }
    for (; p < p1; ++p) {
        int s = src_perm[p];
        int q = perm[p];
        const v4f* e0 = (const v4f*)(eaG + (size_t)(unsigned)q * EDIM);
        v4f a0 = e0[0], a1 = e0[1], a2 = e0[2], a3 = e0[3];
        v2f m0 = bj + unpack2(hw[(unsigned)s << 6]);
        matvp(a0, a1, a2, a3, w, m0);
        acc += vmax0(m0);
    }
    *(v2f*)(t + ((unsigned)node << 7) + c) = acc;
}

// ================= split-bf16 MFMA GEMM =================
#define LPAD 40

template<int K, bool PRE_BN, bool POST_STATS, bool OUT_BF16>
__global__ __launch_bounds__(256) void gemm_mfma(
    const float* __restrict__ A, const unsigned short* __restrict__ Wh,
    const unsigned short* __restrict__ Wl, const float* __restrict__ bias,
    const float* __restrict__ preStats, const float* __restrict__ preG, const float* __restrict__ preB,
    void* __restrict__ Cout, float* __restrict__ postStats, int Nrows, float invN)
{
    __shared__ __align__(16) unsigned short Ah[128 * LPAD], Al[128 * LPAD];
    __shared__ __align__(16) unsigned short Bh[128 * LPAD], Bl[128 * LPAD];
    __shared__ float sc[PRE_BN ? K : 1], sb[PRE_BN ? K : 1];
    int tid = threadIdx.x;
    int rbase = blockIdx.x * 128;
    if (PRE_BN) {
        if (tid < K) {
            float mean = preStats[tid] * invN;
            float var = preStats[K + tid] * invN - mean * mean;
            float rstd = rsqrtf(var + 1e-5f);
            float g = preG[tid];
            sc[tid] = rstd * g;
            sb[tid] = preB[tid] - mean * rstd * g;
        }
        __syncthreads();
    }
    int w = tid >> 6, nl = tid & 15, q = (tid >> 4) & 3;
    f4v acc[2][8];
#pragma unroll
    for (int mt = 0; mt < 2; ++mt)
#pragma unroll
        for (int nt = 0; nt < 8; ++nt)
#pragma unroll
            for (int r = 0; r < 4; ++r) acc[mt][nt][r] = 0.f;

    for (int ks = 0; ks < K / 32; ++ks) {
        int k0 = ks * 32;
        if (ks) __syncthreads();
#pragma unroll
        for (int i = 0; i < 4; ++i) {
            int cidx = tid + i * 256;
            int m = cidx >> 3, k4 = (cidx & 7) * 4;
            int gr = rbase + m;
            float4 v = make_float4(0.f, 0.f, 0.f, 0.f);
            if (gr < Nrows) v = *(const float4*)&A[(size_t)gr * K + k0 + k4];
            if (PRE_BN) {
                v.x = fmaxf(v.x * sc[k0 + k4]     + sb[k0 + k4],     0.f);
                v.y = fmaxf(v.y * sc[k0 + k4 + 1] + sb[k0 + k4 + 1], 0.f);
                v.z = fmaxf(v.z * sc[k0 + k4 + 2] + sb[k0 + k4 + 2], 0.f);
                v.w = fmaxf(v.w * sc[k0 + k4 + 3] + sb[k0 + k4 + 3], 0.f);
            }
            unsigned short h0, l0, h1, l1, h2, l2, h3, l3;
            split_bf16(v.x, h0, l0); split_bf16(v.y, h1, l1);
            split_bf16(v.z, h2, l2); split_bf16(v.w, h3, l3);
            uint2 hp, lp;
            hp.x = (unsigned)h0 | ((unsigned)h1 << 16); hp.y = (unsigned)h2 | ((unsigned)h3 << 16);
            lp.x = (unsigned)l0 | ((unsigned)l1 << 16); lp.y = (unsigned)l2 | ((unsigned)l3 << 16);
            *(uint2*)&Ah[m * LPAD + k4] = hp;
            *(uint2*)&Al[m * LPAD + k4] = lp;
        }
#pragma unroll
        for (int i = 0; i < 2; ++i) {
            int g = tid + i * 256;
            int n = g >> 2, kq = (g & 3) * 8;
            uint4 hv = *(const uint4*)&Wh[(size_t)n * K + k0 + kq];
            uint4 lv = *(const uint4*)&Wl[(size_t)n * K + k0 + kq];
            *(uint4*)&Bh[n * LPAD + kq] = hv;
            *(uint4*)&Bl[n * LPAD + kq] = lv;
        }
        __syncthreads();
        s8v ah0 = *(const s8v*)&Ah[(w * 32 + nl) * LPAD + q * 8];
        s8v ah1 = *(const s8v*)&Ah[(w * 32 + 16 + nl) * LPAD + q * 8];
        s8v al0 = *(const s8v*)&Al[(w * 32 + nl) * LPAD + q * 8];
        s8v al1 = *(const s8v*)&Al[(w * 32 + 16 + nl) * LPAD + q * 8];
#pragma unroll
        for (int nt = 0; nt < 8; ++nt) {
            s8v bh = *(const s8v*)&Bh[(nt * 16 + nl) * LPAD + q * 8];
            s8v bl = *(const s8v*)&Bl[(nt * 16 + nl) * LPAD + q * 8];
            acc[0][nt] = MFMA_BF16(ah0, bh, acc[0][nt]);
            acc[0][nt] = MFMA_BF16(ah0, bl, acc[0][nt]);
            acc[0][nt] = MFMA_BF16(al0, bh, acc[0][nt]);
            acc[1][nt] = MFMA_BF16(ah1, bh, acc[1][nt]);
            acc[1][nt] = MFMA_BF16(ah1, bl, acc[1][nt]);
            acc[1][nt] = MFMA_BF16(al1, bh, acc[1][nt]);
        }
    }
    __syncthreads();

    float* Cf = (float*)Cout;
    unsigned short* Ch = (unsigned short*)Cout;
    float* redS = (float*)Ah;
    float* redQ = (float*)Al;
#pragma unroll
    for (int nt = 0; nt < 8; ++nt) {
        int col = nt * 16 + nl;
        float bcol = bias[col];
        float sv = 0.f, qv = 0.f;
#pragma unroll
        for (int mt = 0; mt < 2; ++mt) {
#pragma unroll
            for (int r = 0; r < 4; ++r) {
                int grow = rbase + w * 32 + mt * 16 + q * 4 + r;
                if (grow < Nrows) {
                    float o = acc[mt][nt][r] + bcol;
                    if (OUT_BF16) Ch[(size_t)grow * HID + col] = bf16_rne(o);
                    else          Cf[(size_t)grow * HID + col] = o;
                    if (POST_STATS) { sv += o; qv += o * o; }
                }
            }
        }
        if (POST_STATS) {
            sv += __shfl_down(sv, 32, 64); sv += __shfl_down(sv, 16, 64);
            qv += __shfl_down(qv, 32, 64); qv += __shfl_down(qv, 16, 64);
            if ((tid & 63) < 16) { redS[w * 128 + col] = sv; redQ[w * 128 + col] = qv; }
        }
    }
    if (POST_STATS) {
        __syncthreads();
        if (tid < 128) {
            float S = redS[tid] + redS[128 + tid] + redS[256 + tid] + redS[384 + tid];
            float Q = redQ[tid] + redQ[128 + tid] + redQ[256 + tid] + redQ[384 + tid];
            atomicAdd(&postStats[tid], S);
            atomicAdd(&postStats[128 + tid], Q);
        }
    }
}

// ======== fused BN apply + ReLU + pool; h stored as packed bf16 (pool uses exact fp32) ========
__global__ void bn_apply_pool(const float* __restrict__ X, unsigned short* __restrict__ h16,
                              const float* __restrict__ stats, const float* __restrict__ g,
                              const float* __restrict__ b, const int* __restrict__ starts,
                              float* __restrict__ z, int l, float invN)
{
    int gph = blockIdx.x;
    int tid = threadIdx.x;
    int ch4 = (tid & 31) * 4, wk = tid >> 5;   // 16 walkers x 32 lanes(float4)
    float sc[4], sh[4];
#pragma unroll
    for (int u = 0; u < 4; ++u) {
        int j = ch4 + u;
        float mean = stats[j] * invN;
        float var = stats[128 + j] * invN - mean * mean;
        float rstd = rsqrtf(var + 1e-5f);
        float gg = g[j];
        sc[u] = rstd * gg;
        sh[u] = b[j] - mean * rstd * gg;
    }
    int s = starts[gph], e = starts[gph + 1];
    float4 sum = make_float4(0.f, 0.f, 0.f, 0.f);
    float4 mx = make_float4(0.f, 0.f, 0.f, 0.f);
    unsigned* hv32 = (unsigned*)h16;
    for (int n = s + wk; n < e; n += 16) {
        float4 v = *(const float4*)&X[(size_t)n * HID + ch4];
        v.x = fmaxf(v.x * sc[0] + sh[0], 0.f);
        v.y = fmaxf(v.y * sc[1] + sh[1], 0.f);
        v.z = fmaxf(v.z * sc[2] + sh[2], 0.f);
        v.w = fmaxf(v.w * sc[3] + sh[3], 0.f);
        uint2 pk;
        pk.x = pack2(v.x, v.y);
        pk.y = pack2(v.z, v.w);
        *(uint2*)&hv32[(size_t)n * 64 + (ch4 >> 1)] = pk;
        sum.x += v.x; sum.y += v.y; sum.z += v.z; sum.w += v.w;
        mx.x = fmaxf(mx.x, v.x); mx.y = fmaxf(mx.y, v.y);
        mx.z = fmaxf(mx.z, v.z); mx.w = fmaxf(mx.w, v.w);
    }
    __shared__ float ls[16 * 128], lm[16 * 128];
    *(float4*)&ls[wk * 128 + ch4] = sum;
    *(float4*)&lm[wk * 128 + ch4] = mx;
    __syncthreads();
    if (tid < 128) {
        float S = 0.f, M = 0.f;
#pragma unroll
        for (int k = 0; k < 16; ++k) {
            S += ls[k * 128 + tid];
            M = fmaxf(M, lm[k * 128 + tid]);
        }
        float cnt = (float)(e - s);
        z[(size_t)gph * 768 + l * 128 + tid] = S / fmaxf(cnt, 1.f);
        z[(size_t)gph * 768 + 384 + l * 128 + tid] = M;
    }
}

// ================= segment boundaries (batch sorted) =================
__global__ void starts_kernel(const int* __restrict__ batch, int* __restrict__ starts,
                              int Nn, int Gn)
{
    int g = blockIdx.x * blockDim.x + threadIdx.x;
    if (g > Gn) return;
    int lo = 0, hi = Nn;
    while (lo < hi) { int mid = (lo + hi) >> 1; if (batch[mid] < g) lo = mid + 1; else hi = mid; }
    starts[g] = lo;
}

// ================= head =================
__global__ void head_gemm1(const float* __restrict__ z, const float* __restrict__ W,
                           const float* __restrict__ bias, float* __restrict__ zr,
                           float* __restrict__ msums)
{
    __shared__ __align__(16) float zl[768];
    int g = blockIdx.x, j = threadIdx.x;
    for (int i = j; i < 768; i += 128) zl[i] = z[(size_t)g * 768 + i];
    __syncthreads();
    float acc = bias[j];
    for (int k = 0; k < 768; k += 4) {
        float4 a4 = *(const float4*)&zl[k];
        acc += a4.x * W[k * 128 + j] + a4.y * W[(k + 1) * 128 + j]
             + a4.z * W[(k + 2) * 128 + j] + a4.w * W[(k + 3) * 128 + j];
    }
    zr[(size_t)g * 128 + j] = acc;
    atomicAdd(&msums[j], acc);
    atomicAdd(&msums[128 + j], acc * acc);
}

__global__ void head_final(const float* __restrict__ zr, const float* __restrict__ msums,
                           const float* __restrict__ hg, const float* __restrict__ hb,
                           const float* __restrict__ W2, const float* __restrict__ b2,
                           float* __restrict__ out, float invG)
{
    int g = blockIdx.x, j = threadIdx.x;
    float mean = msums[j] * invG;
    float var = msums[128 + j] * invG - mean * mean;
    float rstd = rsqrtf(var + 1e-5f);
    float v = zr[(size_t)g * 128 + j];
    v = (v - mean) * rstd * hg[j] + hb[j];
    v = fmaxf(v, 0.f);
    float p = v * W2[j];
#pragma unroll
    for (int off = 32; off > 0; off >>= 1) p += __shfl_down(p, off, 64);
    __shared__ float partial[2];
    if ((j & 63) == 0) partial[j >> 6] = p;
    __syncthreads();
    if (j == 0) out[g] = partial[0] + partial[1] + b2[0];
}

extern "C" void kernel_launch(void* const* d_in, const int* in_sizes, int n_in,
                              void* d_out, int out_size, void* d_ws, size_t ws_size,
                              hipStream_t stream)
{
    const float* x         = (const float*)d_in[0];
    const float* edge_attr = (const float*)d_in[1];
    const int*   src       = (const int*)d_in[2];
    const int*   dst       = (const int*)d_in[3];
    const int*   batch     = (const int*)d_in[4];
    const float* Wp        = (const float*)d_in[5];
    const float* bp        = (const float*)d_in[6];
    const float* conv_We   = (const float*)d_in[7];
    const float* conv_be   = (const float*)d_in[8];
    const float* conv_W1   = (const float*)d_in[9];
    const float* conv_b1   = (const float*)d_in[10];
    const float* conv_g1   = (const float*)d_in[11];
    const float* conv_bt1  = (const float*)d_in[12];
    const float* conv_W2   = (const float*)d_in[13];
    const float* conv_b2   = (const float*)d_in[14];
    const float* bn_g      = (const float*)d_in[15];
    const float* bn_b      = (const float*)d_in[16];
    const float* head_W1   = (const float*)d_in[17];
    const float* head_b1   = (const float*)d_in[18];
    const float* head_g    = (const float*)d_in[19];
    const float* head_bt   = (const float*)d_in[20];
    const float* head_W2   = (const float*)d_in[21];
    const float* head_b2   = (const float*)d_in[22];

    const int N = in_sizes[4];            // 50000
    const int E = in_sizes[2];            // 800000
    const int G = out_size;               // 256
    const int L = 3;

    // ---- workspace layout ----
    float* t        = (float*)d_ws;                  // N*128 fp32
    unsigned short* h16 = (unsigned short*)(t + (size_t)N * HID);  // N*128 bf16
    float* z        = (float*)(h16 + (size_t)N * HID);             // G*768
    float* zr       = z + (size_t)G * 768;           // G*128
    float* statsAll = zr + (size_t)G * HID;          // 7*256
    int*   deg      = (int*)(statsAll + 7 * 256);    // N
    int*   starts   = deg + N;                       // G+1
    int*   row_start= starts + (G + 1);              // N+1
    int*   cursor   = row_start + (N + 1);           // N
    int*   bsum     = cursor + N;                    // 256
    int*   src_perm = bsum + 256;                    // E
    int*   perm     = src_perm + E;                  // E
    unsigned short* wt = (unsigned short*)(perm + E);  // 212992 ushorts gemm weights
    unsigned* wef   = (unsigned*)(wt + 212992);      // 3*1024 u32 f16-pair We table
    size_t base_end = (size_t)((char*)(wef + 3 * 1024) - (char*)d_ws);
    size_t ea_off = (base_end + 63) & ~(size_t)63;   // 64B-align ea rows
    bool gath = (ea_off + (size_t)E * 8 * sizeof(unsigned)) <= ws_size;  // f16 rows: 32B/edge
    unsigned* eaH = (unsigned*)((char*)d_ws + ea_off);
    float* msums = statsAll + 6 * 256;

    (void)n_in;

    const float invN = 1.0f / (float)N;
    const float invG = 1.0f / (float)G;
    const int nb = (N + 255) / 256;
    const int gemmBlocks = (N + 127) / 128;

    // ---- CSR build + weight prep ----
    (void)hipMemsetAsync(statsAll, 0, 7 * 256 * sizeof(float) + (size_t)N * sizeof(int), stream);
    hist_kernel<<<(E + 255) / 256, 256, 0, stream>>>(dst, deg, E);
    block_sum_kernel<<<nb, 256, 0, stream>>>(deg, bsum, N);
    bsum_scan_kernel<<<1, 256, 0, stream>>>(bsum, nb, &row_start[N]);
    block_scan_kernel<<<nb, 256, 0, stream>>>(deg, bsum, row_start, cursor, N);
    scatter_kernel<<<(E + 255) / 256, 256, 0, stream>>>(src, dst, cursor, perm, src_perm, E);
    if (gath)
        gather_ea_f16<<<(E * 2 + 255) / 256, 256, 0, stream>>>(edge_attr, perm, eaH, E);
    starts_kernel<<<1, 512, 0, stream>>>(batch, starts, N, G);
    prep_weights<<<(8192 + 6 * 16384 + 255) / 256, 256, 0, stream>>>(Wp, conv_W1, conv_W2, wt);
    prep_wef16<<<(3 * 1024 + 255) / 256, 256, 0, stream>>>(conv_We, wef);

    const unsigned short* Wp_hi = wt;
    const unsigned short* Wp_lo = wt + 8192;

    // h16 = bf16(x @ Wp + bp)
    gemm_mfma<64, false, false, true><<<gemmBlocks, 256, 0, stream>>>(
        x, Wp_hi, Wp_lo, bp, nullptr, nullptr, nullptr, h16, nullptr, N, invN);

    for (int l = 0; l < L; ++l) {
        float* sI = statsAll + l * 512;
        float* sO = sI + 256;
        const unsigned short* W1hi = wt + 16384 + (size_t)(2 * l) * 32768;
        const unsigned short* W1lo = W1hi + 16384;
        const unsigned short* W2hi = wt + 16384 + (size_t)(2 * l + 1) * 32768;
        const unsigned short* W2lo = W2hi + 16384;
        if (gath)
            aggregate_f16<<<(N + 3) / 4, 256, 0, stream>>>(
                h16, eaH, src_perm, row_start, wef + (size_t)l * 1024,
                conv_be + l * HID, t, N);
        else
            aggregate_fp32<<<(N + 3) / 4, 256, 0, stream>>>(
                h16, edge_attr, perm, src_perm, row_start,
                conv_We + (size_t)l * EDIM * HID, conv_be + l * HID, t, N);
        gemm_mfma<128, false, true, false><<<gemmBlocks, 256, 0, stream>>>(
            t, W1hi, W1lo, conv_b1 + l * HID,
            nullptr, nullptr, nullptr, t, sI, N, invN);
        gemm_mfma<128, true, true, false><<<gemmBlocks, 256, 0, stream>>>(
            t, W2hi, W2lo, conv_b2 + l * HID,
            sI, conv_g1 + l * HID, conv_bt1 + l * HID, t, sO, N, invN);
        bn_apply_pool<<<G, 512, 0, stream>>>(
            t, h16, sO, bn_g + l * HID, bn_b + l * HID, starts, z, l, invN);
    }

    head_gemm1<<<G, 128, 0, stream>>>(z, head_W1, head_b1, zr, msums);
    head_final<<<G, 128, 0, stream>>>(zr, msums, head_g, head_bt, head_W2, head_b2,
                                      (float*)d_out, invG);
}

// Round 10
// 678.622 us; speedup vs baseline: 1.1053x; 1.0014x over previous
//
#include <hip/hip_runtime.h>
#include <hip/hip_bf16.h>
#include <hip/hip_fp16.h>

#define HID 128
#define EDIM 16

typedef float v4f __attribute__((ext_vector_type(4)));
typedef float v2f __attribute__((ext_vector_type(2)));
typedef short s8v __attribute__((ext_vector_type(8)));   // 8 bf16 (4 VGPRs) MFMA frag
typedef float f4v __attribute__((ext_vector_type(4)));   // MFMA acc
typedef unsigned int u8x __attribute__((ext_vector_type(8)));  // 8 dwords = 16 f16
typedef _Float16 h2v __attribute__((ext_vector_type(2)));      // f16 pair for fdot2

#define MFMA_BF16(a, b, c) __builtin_amdgcn_mfma_f32_16x16x32_bf16((a), (b), (c), 0, 0, 0)

__device__ __forceinline__ unsigned short bf16_rne(float v)
{
    unsigned u = __builtin_bit_cast(unsigned, v);
    return (unsigned short)((u + 0x7fffu + ((u >> 16) & 1u)) >> 16);
}

__device__ __forceinline__ unsigned pack2(float lo, float hi)
{
    return (unsigned)bf16_rne(lo) | ((unsigned)bf16_rne(hi) << 16);
}

__device__ __forceinline__ float bflo(unsigned u) { return __builtin_bit_cast(float, u << 16); }
__device__ __forceinline__ float bfhi(unsigned u) { return __builtin_bit_cast(float, u & 0xffff0000u); }

__device__ __forceinline__ v2f unpack2(unsigned u)
{
    v2f r; r.x = bflo(u); r.y = bfhi(u); return r;
}

__device__ __forceinline__ void split_bf16(float v, unsigned short& h, unsigned short& l)
{
    unsigned u = __builtin_bit_cast(unsigned, v);
    unsigned hu = (u + 0x7fffu + ((u >> 16) & 1u)) >> 16;
    h = (unsigned short)hu;
    float hf = __builtin_bit_cast(float, hu << 16);
    l = bf16_rne(v - hf);
}

__device__ __forceinline__ v2f vmax0(v2f a)
{
    v2f r; r.x = fmaxf(a.x, 0.f); r.y = fmaxf(a.y, 0.f); return r;
}

// pack two floats to f16x2 (RNE)
__device__ __forceinline__ unsigned pkh2(float lo, float hi)
{
    return (unsigned)__half_as_ushort(__float2half(lo)) |
           ((unsigned)__half_as_ushort(__float2half(hi)) << 16);
}

// d += ea.lo*w.lo + ea.hi*w.hi (fp32 accumulate). Builtin (NOT bare asm): bare
// VOP3P asm assembles wrong default modifiers (round-6 absmax 0.54).
__device__ __forceinline__ void dot2(float& d, unsigned ea, unsigned w)
{
    d = __builtin_amdgcn_fdot2(__builtin_bit_cast(h2v, ea),
                               __builtin_bit_cast(h2v, w), d, false);
}

// ================= CSR build =================
__global__ void hist_kernel(const int* __restrict__ dst, int* __restrict__ deg, int E)
{
    int e = blockIdx.x * 256 + threadIdx.x;
    if (e < E) atomicAdd(&deg[dst[e]], 1);
}

__global__ void block_sum_kernel(const int* __restrict__ deg, int* __restrict__ bsum, int Nn)
{
    int i = blockIdx.x * 256 + threadIdx.x;
    int v = (i < Nn) ? deg[i] : 0;
#pragma unroll
    for (int off = 32; off > 0; off >>= 1) v += __shfl_down(v, off, 64);
    __shared__ int ws[4];
    if ((threadIdx.x & 63) == 0) ws[threadIdx.x >> 6] = v;
    __syncthreads();
    if (threadIdx.x == 0) bsum[blockIdx.x] = ws[0] + ws[1] + ws[2] + ws[3];
}

__global__ void bsum_scan_kernel(int* bsum, int nb, int* total_out)
{
    __shared__ int sh[256];
    int tid = threadIdx.x;
    int v = (tid < nb) ? bsum[tid] : 0;
    sh[tid] = v;
    __syncthreads();
    for (int off = 1; off < 256; off <<= 1) {
        int tv = (tid >= off) ? sh[tid - off] : 0;
        __syncthreads();
        sh[tid] += tv;
        __syncthreads();
    }
    if (tid < nb) bsum[tid] = sh[tid] - v;
    if (tid == 255) *total_out = sh[255];
}

__global__ void block_scan_kernel(const int* __restrict__ deg, const int* __restrict__ bsum,
                                  int* __restrict__ row_start, int* __restrict__ cursor, int Nn)
{
    __shared__ int sh[256];
    int tid = threadIdx.x;
    int i = blockIdx.x * 256 + tid;
    int v = (i < Nn) ? deg[i] : 0;
    sh[tid] = v;
    __syncthreads();
    for (int off = 1; off < 256; off <<= 1) {
        int tv = (tid >= off) ? sh[tid - off] : 0;
        __syncthreads();
        sh[tid] += tv;
        __syncthreads();
    }
    if (i < Nn) {
        int excl = sh[tid] - v + bsum[blockIdx.x];
        row_start[i] = excl;
        cursor[i] = excl;
    }
}

// phase 1: permutation only (12B/edge traffic; scattered 4B writes live in L2)
__global__ void scatter_kernel(const int* __restrict__ src, const int* __restrict__ dst,
                               int* cursor, int* __restrict__ perm,
                               int* __restrict__ src_perm, int E)
{
    int e = blockIdx.x * 256 + threadIdx.x;
    if (e >= E) return;
    int pos = atomicAdd(&cursor[dst[e]], 1);
    perm[pos] = e;
    src_perm[pos] = src[e];
}

// phase 2: ea permute-copy + f16 convert — scattered READS, coalesced 16B writes.
// 2 threads per edge row; row = 8 dwords (16 f16).
__global__ void gather_ea_f16(const float* __restrict__ ea, const int* __restrict__ perm,
                              unsigned* __restrict__ eaH, int E)
{
    int idx = blockIdx.x * 256 + threadIdx.x;
    int p = idx >> 1, hf = idx & 1;
    if (p >= E) return;
    int e = perm[p];
    const float* ap = &ea[(size_t)e * EDIM + hf * 8];
    float4 f0 = *(const float4*)ap;
    float4 f1 = *(const float4*)(ap + 4);
    uint4 o;
    o.x = pkh2(f0.x, f0.y);
    o.y = pkh2(f0.z, f0.w);
    o.z = pkh2(f1.x, f1.y);
    o.w = pkh2(f1.z, f1.w);
    *(uint4*)&eaH[(size_t)p * 8 + hf * 4] = o;
}

// ================= weight prep: fp32 [K,128] -> transposed split-bf16 [128,K] hi/lo =================
__global__ void prep_weights(const float* __restrict__ Wp, const float* __restrict__ W1,
                             const float* __restrict__ W2, unsigned short* __restrict__ out)
{
    int idx = blockIdx.x * 256 + threadIdx.x;
    if (idx < 8192) {
        int n = idx >> 6, k = idx & 63;
        unsigned short h, l;
        split_bf16(Wp[k * 128 + n], h, l);
        out[idx] = h;
        out[8192 + idx] = l;
    } else {
        int j = idx - 8192;
        if (j >= 6 * 16384) return;
        int m2 = j >> 14;
        int r = j & 16383;
        int n = r >> 7, k = r & 127;
        int l = m2 >> 1;
        const float* Wsrc = (m2 & 1) ? (W2 + l * 16384) : (W1 + l * 16384);
        unsigned short h, lo;
        split_bf16(Wsrc[k * 128 + n], h, lo);
        int base = 16384 + m2 * 32768;
        out[base + r] = h;
        out[base + 16384 + r] = lo;
    }
}

// ====== Node-centric aggregation (r7 structure, 63 µs): f16 ea + fdot2 ======
// 1 wave/node, 2 ch/lane. ea rows wave-uniform -> SGPR (8 dwords/row);
// 16 dot2/edge. 8-edge groups: one lgkmcnt drain per 8 edges.
// h gathers rotated one group ahead (VMEM, counted).
// SPLIT: store output pre-split as bf16 hi/lo planes (bit-identical to the
// fp32-store-then-split the GEMM would do) so the W1 GEMM stages with zero
// conversion VALU.
__device__ __forceinline__ void edge_f16(v2f& acc, v2f bj, unsigned hu, const u8x& e,
                                         const unsigned* __restrict__ wpk0,
                                         const unsigned* __restrict__ wpk1)
{
    float m0 = bj.x + bflo(hu);
    float m1 = bj.y + bfhi(hu);
#pragma unroll
    for (int kp = 0; kp < 8; ++kp) {
        dot2(m0, e[kp], wpk0[kp]);
        dot2(m1, e[kp], wpk1[kp]);
    }
    acc.x += fmaxf(m0, 0.f);
    acc.y += fmaxf(m1, 0.f);
}

template<bool SPLIT>
__global__ __launch_bounds__(256, 8) void aggregate_f16(
    const unsigned short* __restrict__ h16, const unsigned* __restrict__ eaH,
    const int* __restrict__ src_perm, const int* __restrict__ row_start,
    const float* __restrict__ We, const float* __restrict__ be,
    float* __restrict__ t, unsigned short* __restrict__ tl, int Nn)
{
    int tid = threadIdx.x;
    int lane = tid & 63;
    int c = lane * 2;
    // f16 weight k-pairs per output channel (16 VGPRs)
    unsigned wpk0[8], wpk1[8];
#pragma unroll
    for (int kp = 0; kp < 8; ++kp) {
        wpk0[kp] = pkh2(We[(2 * kp) * HID + c],     We[(2 * kp + 1) * HID + c]);
        wpk1[kp] = pkh2(We[(2 * kp) * HID + c + 1], We[(2 * kp + 1) * HID + c + 1]);
    }
    v2f bj = *(const v2f*)&be[c];
    int node = blockIdx.x * 4 + (tid >> 6);
    if (node >= Nn) return;
    const unsigned* __restrict__ hw = (const unsigned*)h16 + lane;  // bf16 ch-pair per lane
    v2f acc = unpack2(hw[(unsigned)node << 6]);
    int p0 = __builtin_amdgcn_readfirstlane(row_start[node]);
    int p1 = __builtin_amdgcn_readfirstlane(row_start[node + 1]);
    int p = p0;

    int s0 = 0, s1 = 0, s2 = 0, s3 = 0, s4 = 0, s5 = 0, s6 = 0, s7 = 0;
    unsigned hu0 = 0, hu1 = 0, hu2 = 0, hu3 = 0, hu4 = 0, hu5 = 0, hu6 = 0, hu7 = 0;
    if (p + 8 <= p1) {
        s0 = src_perm[p];     s1 = src_perm[p + 1]; s2 = src_perm[p + 2]; s3 = src_perm[p + 3];
        s4 = src_perm[p + 4]; s5 = src_perm[p + 5]; s6 = src_perm[p + 6]; s7 = src_perm[p + 7];
        hu0 = hw[(unsigned)s0 << 6]; hu1 = hw[(unsigned)s1 << 6];
        hu2 = hw[(unsigned)s2 << 6]; hu3 = hw[(unsigned)s3 << 6];
        hu4 = hw[(unsigned)s4 << 6]; hu5 = hw[(unsigned)s5 << 6];
        hu6 = hw[(unsigned)s6 << 6]; hu7 = hw[(unsigned)s7 << 6];
    }
    while (p + 8 <= p1) {
        int np = p + 8;
        // current group's ea rows (SMEM, 8 x dwordx8)
        u8x e0 = *(const u8x*)(eaH + (size_t)(unsigned)(p    ) * 8);
        u8x e1 = *(const u8x*)(eaH + (size_t)(unsigned)(p + 1) * 8);
        u8x e2 = *(const u8x*)(eaH + (size_t)(unsigned)(p + 2) * 8);
        u8x e3 = *(const u8x*)(eaH + (size_t)(unsigned)(p + 3) * 8);
        u8x e4 = *(const u8x*)(eaH + (size_t)(unsigned)(p + 4) * 8);
        u8x e5 = *(const u8x*)(eaH + (size_t)(unsigned)(p + 5) * 8);
        u8x e6 = *(const u8x*)(eaH + (size_t)(unsigned)(p + 6) * 8);
        u8x e7 = *(const u8x*)(eaH + (size_t)(unsigned)(p + 7) * 8);
        // next group's src ids + h rows (prefetch)
        int t0 = 0, t1 = 0, t2 = 0, t3 = 0, t4 = 0, t5 = 0, t6 = 0, t7 = 0;
        unsigned hn0 = 0, hn1 = 0, hn2 = 0, hn3 = 0, hn4 = 0, hn5 = 0, hn6 = 0, hn7 = 0;
        if (np + 8 <= p1) {
            t0 = src_perm[np];     t1 = src_perm[np + 1]; t2 = src_perm[np + 2]; t3 = src_perm[np + 3];
            t4 = src_perm[np + 4]; t5 = src_perm[np + 5]; t6 = src_perm[np + 6]; t7 = src_perm[np + 7];
            hn0 = hw[(unsigned)t0 << 6]; hn1 = hw[(unsigned)t1 << 6];
            hn2 = hw[(unsigned)t2 << 6]; hn3 = hw[(unsigned)t3 << 6];
            hn4 = hw[(unsigned)t4 << 6]; hn5 = hw[(unsigned)t5 << 6];
            hn6 = hw[(unsigned)t6 << 6]; hn7 = hw[(unsigned)t7 << 6];
        }
        edge_f16(acc, bj, hu0, e0, wpk0, wpk1);
        edge_f16(acc, bj, hu1, e1, wpk0, wpk1);
        edge_f16(acc, bj, hu2, e2, wpk0, wpk1);
        edge_f16(acc, bj, hu3, e3, wpk0, wpk1);
        edge_f16(acc, bj, hu4, e4, wpk0, wpk1);
        edge_f16(acc, bj, hu5, e5, wpk0, wpk1);
        edge_f16(acc, bj, hu6, e6, wpk0, wpk1);
        edge_f16(acc, bj, hu7, e7, wpk0, wpk1);
        p = np;
        s0 = t0; s1 = t1; s2 = t2; s3 = t3; s4 = t4; s5 = t5; s6 = t6; s7 = t7;
        hu0 = hn0; hu1 = hn1; hu2 = hn2; hu3 = hn3;
        hu4 = hn4; hu5 = hn5; hu6 = hn6; hu7 = hn7;
    }
    for (; p < p1; ++p) {
        int s = src_perm[p];
        unsigned hu = hw[(unsigned)s << 6];
        u8x e = *(const u8x*)(eaH + (size_t)(unsigned)p * 8);
        edge_f16(acc, bj, hu, e, wpk0, wpk1);
    }
    if (SPLIT) {
        unsigned short h0, l0, h1, l1;
        split_bf16(acc.x, h0, l0);
        split_bf16(acc.y, h1, l1);
        ((unsigned*)t)[((unsigned)node << 6) + lane] = (unsigned)h0 | ((unsigned)h1 << 16);
        ((unsigned*)tl)[((unsigned)node << 6) + lane] = (unsigned)l0 | ((unsigned)l1 << 16);
    } else {
        *(v2f*)(t + ((unsigned)node << 7) + c) = acc;
    }
}

// ====== fallback (no workspace for eaH): round-0 fp32 path via perm indirection ======
__device__ __forceinline__ void matvp(const v4f& a0, const v4f& a1,
                                      const v4f& a2, const v4f& a3,
                                      const v2f* __restrict__ w, v2f& m)
{
    m += w[0] * a0.x;  m += w[1] * a0.y;  m += w[2] * a0.z;  m += w[3] * a0.w;
    m += w[4] * a1.x;  m += w[5] * a1.y;  m += w[6] * a1.z;  m += w[7] * a1.w;
    m += w[8] * a2.x;  m += w[9] * a2.y;  m += w[10] * a2.z; m += w[11] * a2.w;
    m += w[12] * a3.x; m += w[13] * a3.y; m += w[14] * a3.z; m += w[15] * a3.w;
}

__global__ __launch_bounds__(256, 8) void aggregate_fp32(
    const unsigned short* __restrict__ h16, const float* __restrict__ eaG,
    const int* __restrict__ perm, const int* __restrict__ src_perm,
    const int* __restrict__ row_start,
    const float* __restrict__ We, const float* __restrict__ be,
    float* __restrict__ t, int Nn)
{
    int tid = threadIdx.x;
    int lane = tid & 63;
    int c = lane * 2;
    v2f w[16];
#pragma unroll
    for (int k = 0; k < 16; ++k) w[k] = *(const v2f*)&We[k * HID + c];
    v2f bj = *(const v2f*)&be[c];
    int node = blockIdx.x * 4 + (tid >> 6);
    if (node >= Nn) return;
    const unsigned* __restrict__ hw = (const unsigned*)h16 + lane;
    v2f acc = unpack2(hw[(unsigned)node << 6]);
    int p0 = __builtin_amdgcn_readfirstlane(row_start[node]);
    int p1 = __builtin_amdgcn_readfirstlane(row_start[node + 1]);
    int p = p0;
    int s0 = 0, s1 = 0, s2 = 0, s3 = 0;
    if (p + 4 <= p1) { s0 = src_perm[p]; s1 = src_perm[p + 1]; s2 = src_perm[p + 2]; s3 = src_perm[p + 3]; }
    while (p + 4 <= p1) {
        int np = p + 4;
        int t0 = 0, t1 = 0, t2 = 0, t3 = 0;
        if (np + 4 <= p1) { t0 = src_perm[np]; t1 = src_perm[np + 1]; t2 = src_perm[np + 2]; t3 = src_perm[np + 3]; }
        unsigned hu0 = hw[(unsigned)s0 << 6];
        unsigned hu1 = hw[(unsigned)s1 << 6];
        unsigned hu2 = hw[(unsigned)s2 << 6];
        unsigned hu3 = hw[(unsigned)s3 << 6];
        int q0 = perm[p], q1 = perm[p + 1], q2 = perm[p + 2], q3 = perm[p + 3];
        const v4f* e0 = (const v4f*)(eaG + (size_t)(unsigned)q0 * EDIM);
        const v4f* e1 = (const v4f*)(eaG + (size_t)(unsigned)q1 * EDIM);
        const v4f* e2 = (const v4f*)(eaG + (size_t)(unsigned)q2 * EDIM);
        const v4f* e3 = (const v4f*)(eaG + (size_t)(unsigned)q3 * EDIM);
        v4f a00 = e0[0], a01 = e0[1], a02 = e0[2], a03 = e0[3];
        v4f a10 = e1[0], a11 = e1[1], a12 = e1[2], a13 = e1[3];
        v4f a20 = e2[0], a21 = e2[1], a22 = e2[2], a23 = e2[3];
        v4f a30 = e3[0], a31 = e3[1], a32 = e3[2], a33 = e3[3];
        v2f m0 = bj + unpack2(hu0), m1 = bj + unpack2(hu1);
        v2f m2 = bj + unpack2(hu2), m3 = bj + unpack2(hu3);
        matvp(a00, a01, a02, a03, w, m0);
        matvp(a10, a11, a12, a13, w, m1);
        matvp(a20, a21, a22, a23, w, m2);
        matvp(a30, a31, a32, a33, w, m3);
        acc += (vmax0(m0) + vmax0(m1)) + (vmax0(m2) + vmax0(m3));
        p = np;
        s0 = t0; s1 = t1; s2 = t2; s3 = t3;
    }
    for (; p < p1; ++p) {
        int s = src_perm[p];
        int q = perm[p];
        const v4f* e0 = (const v4f*)(eaG + (size_t)(unsigned)q * EDIM);
        v4f a0 = e0[0], a1 = e0[1], a2 = e0[2], a3 = e0[3];
        v2f m0 = bj + unpack2(hw[(unsigned)s << 6]);
        matvp(a0, a1, a2, a3, w, m0);
        acc += vmax0(m0);
    }
    *(v2f*)(t + ((unsigned)node << 7) + c) = acc;
}

// ================= split-bf16 MFMA GEMM =================
// A_SPLIT: A is a pre-split bf16 hi-plane (ushort [Nrows][K]), Alo the lo-plane;
// staging is a pure copy (no fp32 load, no split_bf16) — bit-identical math.
#define LPAD 40

template<int K, bool PRE_BN, bool POST_STATS, bool OUT_BF16, bool A_SPLIT>
__global__ __launch_bounds__(256) void gemm_mfma(
    const void* __restrict__ Ain, const unsigned short* __restrict__ Alo,
    const unsigned short* __restrict__ Wh,
    const unsigned short* __restrict__ Wl, const float* __restrict__ bias,
    const float* __restrict__ preStats, const float* __restrict__ preG, const float* __restrict__ preB,
    void* __restrict__ Cout, float* __restrict__ postStats, int Nrows, float invN)
{
    __shared__ __align__(16) unsigned short Ah[128 * LPAD], Al[128 * LPAD];
    __shared__ __align__(16) unsigned short Bh[128 * LPAD], Bl[128 * LPAD];
    __shared__ float sc[PRE_BN ? K : 1], sb[PRE_BN ? K : 1];
    int tid = threadIdx.x;
    int rbase = blockIdx.x * 128;
    if (PRE_BN) {
        if (tid < K) {
            float mean = preStats[tid] * invN;
            float var = preStats[K + tid] * invN - mean * mean;
            float rstd = rsqrtf(var + 1e-5f);
            float g = preG[tid];
            sc[tid] = rstd * g;
            sb[tid] = preB[tid] - mean * rstd * g;
        }
        __syncthreads();
    }
    int w = tid >> 6, nl = tid & 15, q = (tid >> 4) & 3;
    f4v acc[2][8];
#pragma unroll
    for (int mt = 0; mt < 2; ++mt)
#pragma unroll
        for (int nt = 0; nt < 8; ++nt)
#pragma unroll
            for (int r = 0; r < 4; ++r) acc[mt][nt][r] = 0.f;

    for (int ks = 0; ks < K / 32; ++ks) {
        int k0 = ks * 32;
        if (ks) __syncthreads();
#pragma unroll
        for (int i = 0; i < 4; ++i) {
            int cidx = tid + i * 256;
            int m = cidx >> 3, k4 = (cidx & 7) * 4;
            int gr = rbase + m;
            if (A_SPLIT) {
                const unsigned short* Ahg = (const unsigned short*)Ain;
                uint2 hp = make_uint2(0u, 0u), lp = make_uint2(0u, 0u);
                if (gr < Nrows) {
                    hp = *(const uint2*)&Ahg[(size_t)gr * K + k0 + k4];
                    lp = *(const uint2*)&Alo[(size_t)gr * K + k0 + k4];
                }
                *(uint2*)&Ah[m * LPAD + k4] = hp;
                *(uint2*)&Al[m * LPAD + k4] = lp;
            } else {
                const float* A = (const float*)Ain;
                float4 v = make_float4(0.f, 0.f, 0.f, 0.f);
                if (gr < Nrows) v = *(const float4*)&A[(size_t)gr * K + k0 + k4];
                if (PRE_BN) {
                    v.x = fmaxf(v.x * sc[k0 + k4]     + sb[k0 + k4],     0.f);
                    v.y = fmaxf(v.y * sc[k0 + k4 + 1] + sb[k0 + k4 + 1], 0.f);
                    v.z = fmaxf(v.z * sc[k0 + k4 + 2] + sb[k0 + k4 + 2], 0.f);
                    v.w = fmaxf(v.w * sc[k0 + k4 + 3] + sb[k0 + k4 + 3], 0.f);
                }
                unsigned short h0, l0, h1, l1, h2, l2, h3, l3;
                split_bf16(v.x, h0, l0); split_bf16(v.y, h1, l1);
                split_bf16(v.z, h2, l2); split_bf16(v.w, h3, l3);
                uint2 hp, lp;
                hp.x = (unsigned)h0 | ((unsigned)h1 << 16); hp.y = (unsigned)h2 | ((unsigned)h3 << 16);
                lp.x = (unsigned)l0 | ((unsigned)l1 << 16); lp.y = (unsigned)l2 | ((unsigned)l3 << 16);
                *(uint2*)&Ah[m * LPAD + k4] = hp;
                *(uint2*)&Al[m * LPAD + k4] = lp;
            }
        }
#pragma unroll
        for (int i = 0; i < 2; ++i) {
            int g = tid + i * 256;
            int n = g >> 2, kq = (g & 3) * 8;
            uint4 hv = *(const uint4*)&Wh[(size_t)n * K + k0 + kq];
            uint4 lv = *(const uint4*)&Wl[(size_t)n * K + k0 + kq];
            *(uint4*)&Bh[n * LPAD + kq] = hv;
            *(uint4*)&Bl[n * LPAD + kq] = lv;
        }
        __syncthreads();
        s8v ah0 = *(const s8v*)&Ah[(w * 32 + nl) * LPAD + q * 8];
        s8v ah1 = *(const s8v*)&Ah[(w * 32 + 16 + nl) * LPAD + q * 8];
        s8v al0 = *(const s8v*)&Al[(w * 32 + nl) * LPAD + q * 8];
        s8v al1 = *(const s8v*)&Al[(w * 32 + 16 + nl) * LPAD + q * 8];
#pragma unroll
        for (int nt = 0; nt < 8; ++nt) {
            s8v bh = *(const s8v*)&Bh[(nt * 16 + nl) * LPAD + q * 8];
            s8v bl = *(const s8v*)&Bl[(nt * 16 + nl) * LPAD + q * 8];
            acc[0][nt] = MFMA_BF16(ah0, bh, acc[0][nt]);
            acc[0][nt] = MFMA_BF16(ah0, bl, acc[0][nt]);
            acc[0][nt] = MFMA_BF16(al0, bh, acc[0][nt]);
            acc[1][nt] = MFMA_BF16(ah1, bh, acc[1][nt]);
            acc[1][nt] = MFMA_BF16(ah1, bl, acc[1][nt]);
            acc[1][nt] = MFMA_BF16(al1, bh, acc[1][nt]);
        }
    }
    __syncthreads();

    float* Cf = (float*)Cout;
    unsigned short* Ch = (unsigned short*)Cout;
    float* redS = (float*)Ah;
    float* redQ = (float*)Al;
#pragma unroll
    for (int nt = 0; nt < 8; ++nt) {
        int col = nt * 16 + nl;
        float bcol = bias[col];
        float sv = 0.f, qv = 0.f;
#pragma unroll
        for (int mt = 0; mt < 2; ++mt) {
#pragma unroll
            for (int r = 0; r < 4; ++r) {
                int grow = rbase + w * 32 + mt * 16 + q * 4 + r;
                if (grow < Nrows) {
                    float o = acc[mt][nt][r] + bcol;
                    if (OUT_BF16) Ch[(size_t)grow * HID + col] = bf16_rne(o);
                    else          Cf[(size_t)grow * HID + col] = o;
                    if (POST_STATS) { sv += o; qv += o * o; }
                }
            }
        }
        if (POST_STATS) {
            sv += __shfl_down(sv, 32, 64); sv += __shfl_down(sv, 16, 64);
            qv += __shfl_down(qv, 32, 64); qv += __shfl_down(qv, 16, 64);
            if ((tid & 63) < 16) { redS[w * 128 + col] = sv; redQ[w * 128 + col] = qv; }
        }
    }
    if (POST_STATS) {
        __syncthreads();
        if (tid < 128) {
            float S = redS[tid] + redS[128 + tid] + redS[256 + tid] + redS[384 + tid];
            float Q = redQ[tid] + redQ[128 + tid] + redQ[256 + tid] + redQ[384 + tid];
            atomicAdd(&postStats[tid], S);
            atomicAdd(&postStats[128 + tid], Q);
        }
    }
}

// ======== fused BN apply + ReLU + pool; h stored as packed bf16 (pool uses exact fp32) ========
__global__ void bn_apply_pool(const float* __restrict__ X, unsigned short* __restrict__ h16,
                              const float* __restrict__ stats, const float* __restrict__ g,
                              const float* __restrict__ b, const int* __restrict__ starts,
                              float* __restrict__ z, int l, float invN)
{
    int gph = blockIdx.x;
    int tid = threadIdx.x;
    int ch4 = (tid & 31) * 4, wk = tid >> 5;   // 16 walkers x 32 lanes(float4)
    float sc[4], sh[4];
#pragma unroll
    for (int u = 0; u < 4; ++u) {
        int j = ch4 + u;
        float mean = stats[j] * invN;
        float var = stats[128 + j] * invN - mean * mean;
        float rstd = rsqrtf(var + 1e-5f);
        float gg = g[j];
        sc[u] = rstd * gg;
        sh[u] = b[j] - mean * rstd * gg;
    }
    int s = starts[gph], e = starts[gph + 1];
    float4 sum = make_float4(0.f, 0.f, 0.f, 0.f);
    float4 mx = make_float4(0.f, 0.f, 0.f, 0.f);
    unsigned* hv32 = (unsigned*)h16;
    for (int n = s + wk; n < e; n += 16) {
        float4 v = *(const float4*)&X[(size_t)n * HID + ch4];
        v.x = fmaxf(v.x * sc[0] + sh[0], 0.f);
        v.y = fmaxf(v.y * sc[1] + sh[1], 0.f);
        v.z = fmaxf(v.z * sc[2] + sh[2], 0.f);
        v.w = fmaxf(v.w * sc[3] + sh[3], 0.f);
        uint2 pk;
        pk.x = pack2(v.x, v.y);
        pk.y = pack2(v.z, v.w);
        *(uint2*)&hv32[(size_t)n * 64 + (ch4 >> 1)] = pk;
        sum.x += v.x; sum.y += v.y; sum.z += v.z; sum.w += v.w;
        mx.x = fmaxf(mx.x, v.x); mx.y = fmaxf(mx.y, v.y);
        mx.z = fmaxf(mx.z, v.z); mx.w = fmaxf(mx.w, v.w);
    }
    __shared__ float ls[16 * 128], lm[16 * 128];
    *(float4*)&ls[wk * 128 + ch4] = sum;
    *(float4*)&lm[wk * 128 + ch4] = mx;
    __syncthreads();
    if (tid < 128) {
        float S = 0.f, M = 0.f;
#pragma unroll
        for (int k = 0; k < 16; ++k) {
            S += ls[k * 128 + tid];
            M = fmaxf(M, lm[k * 128 + tid]);
        }
        float cnt = (float)(e - s);
        z[(size_t)gph * 768 + l * 128 + tid] = S / fmaxf(cnt, 1.f);
        z[(size_t)gph * 768 + 384 + l * 128 + tid] = M;
    }
}

// ================= segment boundaries (batch sorted) =================
__global__ void starts_kernel(const int* __restrict__ batch, int* __restrict__ starts,
                              int Nn, int Gn)
{
    int g = blockIdx.x * blockDim.x + threadIdx.x;
    if (g > Gn) return;
    int lo = 0, hi = Nn;
    while (lo < hi) { int mid = (lo + hi) >> 1; if (batch[mid] < g) lo = mid + 1; else hi = mid; }
    starts[g] = lo;
}

// ================= head =================
__global__ void head_gemm1(const float* __restrict__ z, const float* __restrict__ W,
                           const float* __restrict__ bias, float* __restrict__ zr,
                           float* __restrict__ msums)
{
    __shared__ __align__(16) float zl[768];
    int g = blockIdx.x, j = threadIdx.x;
    for (int i = j; i < 768; i += 128) zl[i] = z[(size_t)g * 768 + i];
    __syncthreads();
    float acc = bias[j];
    for (int k = 0; k < 768; k += 4) {
        float4 a4 = *(const float4*)&zl[k];
        acc += a4.x * W[k * 128 + j] + a4.y * W[(k + 1) * 128 + j]
             + a4.z * W[(k + 2) * 128 + j] + a4.w * W[(k + 3) * 128 + j];
    }
    zr[(size_t)g * 128 + j] = acc;
    atomicAdd(&msums[j], acc);
    atomicAdd(&msums[128 + j], acc * acc);
}

__global__ void head_final(const float* __restrict__ zr, const float* __restrict__ msums,
                           const float* __restrict__ hg, const float* __restrict__ hb,
                           const float* __restrict__ W2, const float* __restrict__ b2,
                           float* __restrict__ out, float invG)
{
    int g = blockIdx.x, j = threadIdx.x;
    float mean = msums[j] * invG;
    float var = msums[128 + j] * invG - mean * mean;
    float rstd = rsqrtf(var + 1e-5f);
    float v = zr[(size_t)g * 128 + j];
    v = (v - mean) * rstd * hg[j] + hb[j];
    v = fmaxf(v, 0.f);
    float p = v * W2[j];
#pragma unroll
    for (int off = 32; off > 0; off >>= 1) p += __shfl_down(p, off, 64);
    __shared__ float partial[2];
    if ((j & 63) == 0) partial[j >> 6] = p;
    __syncthreads();
    if (j == 0) out[g] = partial[0] + partial[1] + b2[0];
}

extern "C" void kernel_launch(void* const* d_in, const int* in_sizes, int n_in,
                              void* d_out, int out_size, void* d_ws, size_t ws_size,
                              hipStream_t stream)
{
    const float* x         = (const float*)d_in[0];
    const float* edge_attr = (const float*)d_in[1];
    const int*   src       = (const int*)d_in[2];
    const int*   dst       = (const int*)d_in[3];
    const int*   batch     = (const int*)d_in[4];
    const float* Wp        = (const float*)d_in[5];
    const float* bp        = (const float*)d_in[6];
    const float* conv_We   = (const float*)d_in[7];
    const float* conv_be   = (const float*)d_in[8];
    const float* conv_W1   = (const float*)d_in[9];
    const float* conv_b1   = (const float*)d_in[10];
    const float* conv_g1   = (const float*)d_in[11];
    const float* conv_bt1  = (const float*)d_in[12];
    const float* conv_W2   = (const float*)d_in[13];
    const float* conv_b2   = (const float*)d_in[14];
    const float* bn_g      = (const float*)d_in[15];
    const float* bn_b      = (const float*)d_in[16];
    const float* head_W1   = (const float*)d_in[17];
    const float* head_b1   = (const float*)d_in[18];
    const float* head_g    = (const float*)d_in[19];
    const float* head_bt   = (const float*)d_in[20];
    const float* head_W2   = (const float*)d_in[21];
    const float* head_b2   = (const float*)d_in[22];

    const int N = in_sizes[4];            // 50000
    const int E = in_sizes[2];            // 800000
    const int G = out_size;               // 256
    const int L = 3;

    // ---- workspace layout ----
    float* t        = (float*)d_ws;                  // N*128 fp32
    unsigned short* h16 = (unsigned short*)(t + (size_t)N * HID);  // N*128 bf16
    float* z        = (float*)(h16 + (size_t)N * HID);             // G*768
    float* zr       = z + (size_t)G * 768;           // G*128
    float* statsAll = zr + (size_t)G * HID;          // 7*256
    int*   deg      = (int*)(statsAll + 7 * 256);    // N
    int*   starts   = deg + N;                       // G+1
    int*   row_start= starts + (G + 1);              // N+1
    int*   cursor   = row_start + (N + 1);           // N
    int*   bsum     = cursor + N;                    // 256
    int*   src_perm = bsum + 256;                    // E
    int*   perm     = src_perm + E;                  // E
    unsigned short* wt = (unsigned short*)(perm + E);  // 212992 ushorts gemm weights
    size_t base_end = (size_t)((char*)(wt + 212992) - (char*)d_ws);
    size_t ea_off = (base_end + 63) & ~(size_t)63;   // 64B-align ea rows
    bool gath = (ea_off + (size_t)E * 8 * sizeof(unsigned)) <= ws_size;  // f16 rows: 32B/edge
    unsigned* eaH = (unsigned*)((char*)d_ws + ea_off);
    // pre-split aggregate output planes (hi/lo bf16), after eaH
    size_t split_off = ea_off + (gath ? (size_t)E * 8 * sizeof(unsigned) : 0);
    split_off = (split_off + 63) & ~(size_t)63;
    bool splt = gath && (split_off + (size_t)N * HID * 2 * sizeof(unsigned short)) <= ws_size;
    unsigned short* th = (unsigned short*)((char*)d_ws + split_off);
    unsigned short* tlp = th + (size_t)N * HID;
    float* msums = statsAll + 6 * 256;

    (void)n_in;

    const float invN = 1.0f / (float)N;
    const float invG = 1.0f / (float)G;
    const int nb = (N + 255) / 256;
    const int gemmBlocks = (N + 127) / 128;

    // ---- CSR build + weight prep ----
    (void)hipMemsetAsync(statsAll, 0, 7 * 256 * sizeof(float) + (size_t)N * sizeof(int), stream);
    hist_kernel<<<(E + 255) / 256, 256, 0, stream>>>(dst, deg, E);
    block_sum_kernel<<<nb, 256, 0, stream>>>(deg, bsum, N);
    bsum_scan_kernel<<<1, 256, 0, stream>>>(bsum, nb, &row_start[N]);
    block_scan_kernel<<<nb, 256, 0, stream>>>(deg, bsum, row_start, cursor, N);
    scatter_kernel<<<(E + 255) / 256, 256, 0, stream>>>(src, dst, cursor, perm, src_perm, E);
    if (gath)
        gather_ea_f16<<<(E * 2 + 255) / 256, 256, 0, stream>>>(edge_attr, perm, eaH, E);
    starts_kernel<<<1, 512, 0, stream>>>(batch, starts, N, G);
    prep_weights<<<(8192 + 6 * 16384 + 255) / 256, 256, 0, stream>>>(Wp, conv_W1, conv_W2, wt);

    const unsigned short* Wp_hi = wt;
    const unsigned short* Wp_lo = wt + 8192;

    // h16 = bf16(x @ Wp + bp)
    gemm_mfma<64, false, false, true, false><<<gemmBlocks, 256, 0, stream>>>(
        x, nullptr, Wp_hi, Wp_lo, bp, nullptr, nullptr, nullptr, h16, nullptr, N, invN);

    for (int l = 0; l < L; ++l) {
        float* sI = statsAll + l * 512;
        float* sO = sI + 256;
        const unsigned short* W1hi = wt + 16384 + (size_t)(2 * l) * 32768;
        const unsigned short* W1lo = W1hi + 16384;
        const unsigned short* W2hi = wt + 16384 + (size_t)(2 * l + 1) * 32768;
        const unsigned short* W2lo = W2hi + 16384;
        if (splt) {
            // aggregate writes pre-split bf16 planes; W1 gemm stages with zero conversion
            aggregate_f16<true><<<(N + 3) / 4, 256, 0, stream>>>(
                h16, eaH, src_perm, row_start,
                conv_We + (size_t)l * EDIM * HID, conv_be + l * HID, (float*)th, tlp, N);
            gemm_mfma<128, false, true, false, true><<<gemmBlocks, 256, 0, stream>>>(
                th, tlp, W1hi, W1lo, conv_b1 + l * HID,
                nullptr, nullptr, nullptr, t, sI, N, invN);
        } else if (gath) {
            aggregate_f16<false><<<(N + 3) / 4, 256, 0, stream>>>(
                h16, eaH, src_perm, row_start,
                conv_We + (size_t)l * EDIM * HID, conv_be + l * HID, t, nullptr, N);
            gemm_mfma<128, false, true, false, false><<<gemmBlocks, 256, 0, stream>>>(
                t, nullptr, W1hi, W1lo, conv_b1 + l * HID,
                nullptr, nullptr, nullptr, t, sI, N, invN);
        } else {
            aggregate_fp32<<<(N + 3) / 4, 256, 0, stream>>>(
                h16, edge_attr, perm, src_perm, row_start,
                conv_We + (size_t)l * EDIM * HID, conv_be + l * HID, t, N);
            gemm_mfma<128, false, true, false, false><<<gemmBlocks, 256, 0, stream>>>(
                t, nullptr, W1hi, W1lo, conv_b1 + l * HID,
                nullptr, nullptr, nullptr, t, sI, N, invN);
        }
        gemm_mfma<128, true, true, false, false><<<gemmBlocks, 256, 0, stream>>>(
            t, nullptr, W2hi, W2lo, conv_b2 + l * HID,
            sI, conv_g1 + l * HID, conv_bt1 + l * HID, t, sO, N, invN);
        bn_apply_pool<<<G, 512, 0, stream>>>(
            t, h16, sO, bn_g + l * HID, bn_b + l * HID, starts, z, l, invN);
    }

    head_gemm1<<<G, 128, 0, stream>>>(z, head_W1, head_b1, zr, msums);
    head_final<<<G, 128, 0, stream>>>(zr, msums, head_g, head_bt, head_W2, head_b2,
                                      (float*)d_out, invG);
}

// Round 11
// 635.012 us; speedup vs baseline: 1.1812x; 1.0687x over previous
//
#include <hip/hip_runtime.h>
#include <hip/hip_bf16.h>
#include <hip/hip_fp16.h>

#define HID 128
#define EDIM 16
#define NSTAT 16   // stat-slot copies to break atomic serialization

typedef float v4f __attribute__((ext_vector_type(4)));
typedef float v2f __attribute__((ext_vector_type(2)));
typedef short s8v __attribute__((ext_vector_type(8)));   // 8 bf16 (4 VGPRs) MFMA frag
typedef float f4v __attribute__((ext_vector_type(4)));   // MFMA acc
typedef unsigned int u8x __attribute__((ext_vector_type(8)));  // 8 dwords = 16 f16
typedef _Float16 h2v __attribute__((ext_vector_type(2)));      // f16 pair for fdot2

#define MFMA_BF16(a, b, c) __builtin_amdgcn_mfma_f32_16x16x32_bf16((a), (b), (c), 0, 0, 0)

__device__ __forceinline__ unsigned short bf16_rne(float v)
{
    unsigned u = __builtin_bit_cast(unsigned, v);
    return (unsigned short)((u + 0x7fffu + ((u >> 16) & 1u)) >> 16);
}

__device__ __forceinline__ unsigned pack2(float lo, float hi)
{
    return (unsigned)bf16_rne(lo) | ((unsigned)bf16_rne(hi) << 16);
}

__device__ __forceinline__ float bflo(unsigned u) { return __builtin_bit_cast(float, u << 16); }
__device__ __forceinline__ float bfhi(unsigned u) { return __builtin_bit_cast(float, u & 0xffff0000u); }

__device__ __forceinline__ v2f unpack2(unsigned u)
{
    v2f r; r.x = bflo(u); r.y = bfhi(u); return r;
}

__device__ __forceinline__ void split_bf16(float v, unsigned short& h, unsigned short& l)
{
    unsigned u = __builtin_bit_cast(unsigned, v);
    unsigned hu = (u + 0x7fffu + ((u >> 16) & 1u)) >> 16;
    h = (unsigned short)hu;
    float hf = __builtin_bit_cast(float, hu << 16);
    l = bf16_rne(v - hf);
}

__device__ __forceinline__ v2f vmax0(v2f a)
{
    v2f r; r.x = fmaxf(a.x, 0.f); r.y = fmaxf(a.y, 0.f); return r;
}

// pack two floats to f16x2 (RNE)
__device__ __forceinline__ unsigned pkh2(float lo, float hi)
{
    return (unsigned)__half_as_ushort(__float2half(lo)) |
           ((unsigned)__half_as_ushort(__float2half(hi)) << 16);
}

// d += ea.lo*w.lo + ea.hi*w.hi (fp32 accumulate). Builtin (NOT bare asm): bare
// VOP3P asm assembles wrong default modifiers (round-6 absmax 0.54).
__device__ __forceinline__ void dot2(float& d, unsigned ea, unsigned w)
{
    d = __builtin_amdgcn_fdot2(__builtin_bit_cast(h2v, ea),
                               __builtin_bit_cast(h2v, w), d, false);
}

// ================= CSR build =================
__global__ void hist_kernel(const int* __restrict__ dst, int* __restrict__ deg, int E)
{
    int e = blockIdx.x * 256 + threadIdx.x;
    if (e < E) atomicAdd(&deg[dst[e]], 1);
}

__global__ void block_sum_kernel(const int* __restrict__ deg, int* __restrict__ bsum, int Nn)
{
    int i = blockIdx.x * 256 + threadIdx.x;
    int v = (i < Nn) ? deg[i] : 0;
#pragma unroll
    for (int off = 32; off > 0; off >>= 1) v += __shfl_down(v, off, 64);
    __shared__ int ws[4];
    if ((threadIdx.x & 63) == 0) ws[threadIdx.x >> 6] = v;
    __syncthreads();
    if (threadIdx.x == 0) bsum[blockIdx.x] = ws[0] + ws[1] + ws[2] + ws[3];
}

__global__ void bsum_scan_kernel(int* bsum, int nb, int* total_out)
{
    __shared__ int sh[256];
    int tid = threadIdx.x;
    int v = (tid < nb) ? bsum[tid] : 0;
    sh[tid] = v;
    __syncthreads();
    for (int off = 1; off < 256; off <<= 1) {
        int tv = (tid >= off) ? sh[tid - off] : 0;
        __syncthreads();
        sh[tid] += tv;
        __syncthreads();
    }
    if (tid < nb) bsum[tid] = sh[tid] - v;
    if (tid == 255) *total_out = sh[255];
}

__global__ void block_scan_kernel(const int* __restrict__ deg, const int* __restrict__ bsum,
                                  int* __restrict__ row_start, int* __restrict__ cursor, int Nn)
{
    __shared__ int sh[256];
    int tid = threadIdx.x;
    int i = blockIdx.x * 256 + tid;
    int v = (i < Nn) ? deg[i] : 0;
    sh[tid] = v;
    __syncthreads();
    for (int off = 1; off < 256; off <<= 1) {
        int tv = (tid >= off) ? sh[tid - off] : 0;
        __syncthreads();
        sh[tid] += tv;
        __syncthreads();
    }
    if (i < Nn) {
        int excl = sh[tid] - v + bsum[blockIdx.x];
        row_start[i] = excl;
        cursor[i] = excl;
    }
}

// phase 1: permutation only (12B/edge traffic; scattered 4B writes live in L2)
__global__ void scatter_kernel(const int* __restrict__ src, const int* __restrict__ dst,
                               int* cursor, int* __restrict__ perm,
                               int* __restrict__ src_perm, int E)
{
    int e = blockIdx.x * 256 + threadIdx.x;
    if (e >= E) return;
    int pos = atomicAdd(&cursor[dst[e]], 1);
    perm[pos] = e;
    src_perm[pos] = src[e];
}

// phase 2: ea permute-copy + f16 convert — scattered READS, coalesced 16B writes.
// 2 threads per edge row; row = 8 dwords (16 f16).
__global__ void gather_ea_f16(const float* __restrict__ ea, const int* __restrict__ perm,
                              unsigned* __restrict__ eaH, int E)
{
    int idx = blockIdx.x * 256 + threadIdx.x;
    int p = idx >> 1, hf = idx & 1;
    if (p >= E) return;
    int e = perm[p];
    const float* ap = &ea[(size_t)e * EDIM + hf * 8];
    float4 f0 = *(const float4*)ap;
    float4 f1 = *(const float4*)(ap + 4);
    uint4 o;
    o.x = pkh2(f0.x, f0.y);
    o.y = pkh2(f0.z, f0.w);
    o.z = pkh2(f1.x, f1.y);
    o.w = pkh2(f1.z, f1.w);
    *(uint4*)&eaH[(size_t)p * 8 + hf * 4] = o;
}

// ================= weight prep: fp32 [K,128] -> transposed split-bf16 [128,K] hi/lo =================
__global__ void prep_weights(const float* __restrict__ Wp, const float* __restrict__ W1,
                             const float* __restrict__ W2, unsigned short* __restrict__ out)
{
    int idx = blockIdx.x * 256 + threadIdx.x;
    if (idx < 8192) {
        int n = idx >> 6, k = idx & 63;
        unsigned short h, l;
        split_bf16(Wp[k * 128 + n], h, l);
        out[idx] = h;
        out[8192 + idx] = l;
    } else {
        int j = idx - 8192;
        if (j >= 6 * 16384) return;
        int m2 = j >> 14;
        int r = j & 16383;
        int n = r >> 7, k = r & 127;
        int l = m2 >> 1;
        const float* Wsrc = (m2 & 1) ? (W2 + l * 16384) : (W1 + l * 16384);
        unsigned short h, lo;
        split_bf16(Wsrc[k * 128 + n], h, lo);
        int base = 16384 + m2 * 32768;
        out[base + r] = h;
        out[base + 16384 + r] = lo;
    }
}

// ====== Node-centric aggregation (r7 structure, 63 µs): f16 ea + fdot2 ======
// 1 wave/node, 2 ch/lane. ea rows wave-uniform -> SGPR (8 dwords/row);
// 16 dot2/edge. 8-edge groups: one lgkmcnt drain per 8 edges.
// h gathers rotated one group ahead (VMEM, counted).
__device__ __forceinline__ void edge_f16(v2f& acc, v2f bj, unsigned hu, const u8x& e,
                                         const unsigned* __restrict__ wpk0,
                                         const unsigned* __restrict__ wpk1)
{
    float m0 = bj.x + bflo(hu);
    float m1 = bj.y + bfhi(hu);
#pragma unroll
    for (int kp = 0; kp < 8; ++kp) {
        dot2(m0, e[kp], wpk0[kp]);
        dot2(m1, e[kp], wpk1[kp]);
    }
    acc.x += fmaxf(m0, 0.f);
    acc.y += fmaxf(m1, 0.f);
}

__global__ __launch_bounds__(256, 8) void aggregate_f16(
    const unsigned short* __restrict__ h16, const unsigned* __restrict__ eaH,
    const int* __restrict__ src_perm, const int* __restrict__ row_start,
    const float* __restrict__ We, const float* __restrict__ be,
    float* __restrict__ t, int Nn)
{
    int tid = threadIdx.x;
    int lane = tid & 63;
    int c = lane * 2;
    // f16 weight k-pairs per output channel (16 VGPRs)
    unsigned wpk0[8], wpk1[8];
#pragma unroll
    for (int kp = 0; kp < 8; ++kp) {
        wpk0[kp] = pkh2(We[(2 * kp) * HID + c],     We[(2 * kp + 1) * HID + c]);
        wpk1[kp] = pkh2(We[(2 * kp) * HID + c + 1], We[(2 * kp + 1) * HID + c + 1]);
    }
    v2f bj = *(const v2f*)&be[c];
    int node = blockIdx.x * 4 + (tid >> 6);
    if (node >= Nn) return;
    const unsigned* __restrict__ hw = (const unsigned*)h16 + lane;  // bf16 ch-pair per lane
    v2f acc = unpack2(hw[(unsigned)node << 6]);
    int p0 = __builtin_amdgcn_readfirstlane(row_start[node]);
    int p1 = __builtin_amdgcn_readfirstlane(row_start[node + 1]);
    int p = p0;

    int s0 = 0, s1 = 0, s2 = 0, s3 = 0, s4 = 0, s5 = 0, s6 = 0, s7 = 0;
    unsigned hu0 = 0, hu1 = 0, hu2 = 0, hu3 = 0, hu4 = 0, hu5 = 0, hu6 = 0, hu7 = 0;
    if (p + 8 <= p1) {
        s0 = src_perm[p];     s1 = src_perm[p + 1]; s2 = src_perm[p + 2]; s3 = src_perm[p + 3];
        s4 = src_perm[p + 4]; s5 = src_perm[p + 5]; s6 = src_perm[p + 6]; s7 = src_perm[p + 7];
        hu0 = hw[(unsigned)s0 << 6]; hu1 = hw[(unsigned)s1 << 6];
        hu2 = hw[(unsigned)s2 << 6]; hu3 = hw[(unsigned)s3 << 6];
        hu4 = hw[(unsigned)s4 << 6]; hu5 = hw[(unsigned)s5 << 6];
        hu6 = hw[(unsigned)s6 << 6]; hu7 = hw[(unsigned)s7 << 6];
    }
    while (p + 8 <= p1) {
        int np = p + 8;
        // current group's ea rows (SMEM, 8 x dwordx8)
        u8x e0 = *(const u8x*)(eaH + (size_t)(unsigned)(p    ) * 8);
        u8x e1 = *(const u8x*)(eaH + (size_t)(unsigned)(p + 1) * 8);
        u8x e2 = *(const u8x*)(eaH + (size_t)(unsigned)(p + 2) * 8);
        u8x e3 = *(const u8x*)(eaH + (size_t)(unsigned)(p + 3) * 8);
        u8x e4 = *(const u8x*)(eaH + (size_t)(unsigned)(p + 4) * 8);
        u8x e5 = *(const u8x*)(eaH + (size_t)(unsigned)(p + 5) * 8);
        u8x e6 = *(const u8x*)(eaH + (size_t)(unsigned)(p + 6) * 8);
        u8x e7 = *(const u8x*)(eaH + (size_t)(unsigned)(p + 7) * 8);
        // next group's src ids + h rows (prefetch)
        int t0 = 0, t1 = 0, t2 = 0, t3 = 0, t4 = 0, t5 = 0, t6 = 0, t7 = 0;
        unsigned hn0 = 0, hn1 = 0, hn2 = 0, hn3 = 0, hn4 = 0, hn5 = 0, hn6 = 0, hn7 = 0;
        if (np + 8 <= p1) {
            t0 = src_perm[np];     t1 = src_perm[np + 1]; t2 = src_perm[np + 2]; t3 = src_perm[np + 3];
            t4 = src_perm[np + 4]; t5 = src_perm[np + 5]; t6 = src_perm[np + 6]; t7 = src_perm[np + 7];
            hn0 = hw[(unsigned)t0 << 6]; hn1 = hw[(unsigned)t1 << 6];
            hn2 = hw[(unsigned)t2 << 6]; hn3 = hw[(unsigned)t3 << 6];
            hn4 = hw[(unsigned)t4 << 6]; hn5 = hw[(unsigned)t5 << 6];
            hn6 = hw[(unsigned)t6 << 6]; hn7 = hw[(unsigned)t7 << 6];
        }
        edge_f16(acc, bj, hu0, e0, wpk0, wpk1);
        edge_f16(acc, bj, hu1, e1, wpk0, wpk1);
        edge_f16(acc, bj, hu2, e2, wpk0, wpk1);
        edge_f16(acc, bj, hu3, e3, wpk0, wpk1);
        edge_f16(acc, bj, hu4, e4, wpk0, wpk1);
        edge_f16(acc, bj, hu5, e5, wpk0, wpk1);
        edge_f16(acc, bj, hu6, e6, wpk0, wpk1);
        edge_f16(acc, bj, hu7, e7, wpk0, wpk1);
        p = np;
        s0 = t0; s1 = t1; s2 = t2; s3 = t3; s4 = t4; s5 = t5; s6 = t6; s7 = t7;
        hu0 = hn0; hu1 = hn1; hu2 = hn2; hu3 = hn3;
        hu4 = hn4; hu5 = hn5; hu6 = hn6; hu7 = hn7;
    }
    for (; p < p1; ++p) {
        int s = src_perm[p];
        unsigned hu = hw[(unsigned)s << 6];
        u8x e = *(const u8x*)(eaH + (size_t)(unsigned)p * 8);
        edge_f16(acc, bj, hu, e, wpk0, wpk1);
    }
    *(v2f*)(t + ((unsigned)node << 7) + c) = acc;
}

// ====== fallback (no workspace for eaH): round-0 fp32 path via perm indirection ======
__device__ __forceinline__ void matvp(const v4f& a0, const v4f& a1,
                                      const v4f& a2, const v4f& a3,
                                      const v2f* __restrict__ w, v2f& m)
{
    m += w[0] * a0.x;  m += w[1] * a0.y;  m += w[2] * a0.z;  m += w[3] * a0.w;
    m += w[4] * a1.x;  m += w[5] * a1.y;  m += w[6] * a1.z;  m += w[7] * a1.w;
    m += w[8] * a2.x;  m += w[9] * a2.y;  m += w[10] * a2.z; m += w[11] * a2.w;
    m += w[12] * a3.x; m += w[13] * a3.y; m += w[14] * a3.z; m += w[15] * a3.w;
}

__global__ __launch_bounds__(256, 8) void aggregate_fp32(
    const unsigned short* __restrict__ h16, const float* __restrict__ eaG,
    const int* __restrict__ perm, const int* __restrict__ src_perm,
    const int* __restrict__ row_start,
    const float* __restrict__ We, const float* __restrict__ be,
    float* __restrict__ t, int Nn)
{
    int tid = threadIdx.x;
    int lane = tid & 63;
    int c = lane * 2;
    v2f w[16];
#pragma unroll
    for (int k = 0; k < 16; ++k) w[k] = *(const v2f*)&We[k * HID + c];
    v2f bj = *(const v2f*)&be[c];
    int node = blockIdx.x * 4 + (tid >> 6);
    if (node >= Nn) return;
    const unsigned* __restrict__ hw = (const unsigned*)h16 + lane;
    v2f acc = unpack2(hw[(unsigned)node << 6]);
    int p0 = __builtin_amdgcn_readfirstlane(row_start[node]);
    int p1 = __builtin_amdgcn_readfirstlane(row_start[node + 1]);
    int p = p0;
    int s0 = 0, s1 = 0, s2 = 0, s3 = 0;
    if (p + 4 <= p1) { s0 = src_perm[p]; s1 = src_perm[p + 1]; s2 = src_perm[p + 2]; s3 = src_perm[p + 3]; }
    while (p + 4 <= p1) {
        int np = p + 4;
        int t0 = 0, t1 = 0, t2 = 0, t3 = 0;
        if (np + 4 <= p1) { t0 = src_perm[np]; t1 = src_perm[np + 1]; t2 = src_perm[np + 2]; t3 = src_perm[np + 3]; }
        unsigned hu0 = hw[(unsigned)s0 << 6];
        unsigned hu1 = hw[(unsigned)s1 << 6];
        unsigned hu2 = hw[(unsigned)s2 << 6];
        unsigned hu3 = hw[(unsigned)s3 << 6];
        int q0 = perm[p], q1 = perm[p + 1], q2 = perm[p + 2], q3 = perm[p + 3];
        const v4f* e0 = (const v4f*)(eaG + (size_t)(unsigned)q0 * EDIM);
        const v4f* e1 = (const v4f*)(eaG + (size_t)(unsigned)q1 * EDIM);
        const v4f* e2 = (const v4f*)(eaG + (size_t)(unsigned)q2 * EDIM);
        const v4f* e3 = (const v4f*)(eaG + (size_t)(unsigned)q3 * EDIM);
        v4f a00 = e0[0], a01 = e0[1], a02 = e0[2], a03 = e0[3];
        v4f a10 = e1[0], a11 = e1[1], a12 = e1[2], a13 = e1[3];
        v4f a20 = e2[0], a21 = e2[1], a22 = e2[2], a23 = e2[3];
        v4f a30 = e3[0], a31 = e3[1], a32 = e3[2], a33 = e3[3];
        v2f m0 = bj + unpack2(hu0), m1 = bj + unpack2(hu1);
        v2f m2 = bj + unpack2(hu2), m3 = bj + unpack2(hu3);
        matvp(a00, a01, a02, a03, w, m0);
        matvp(a10, a11, a12, a13, w, m1);
        matvp(a20, a21, a22, a23, w, m2);
        matvp(a30, a31, a32, a33, w, m3);
        acc += (vmax0(m0) + vmax0(m1)) + (vmax0(m2) + vmax0(m3));
        p = np;
        s0 = t0; s1 = t1; s2 = t2; s3 = t3;
    }
    for (; p < p1; ++p) {
        int s = src_perm[p];
        int q = perm[p];
        const v4f* e0 = (const v4f*)(eaG + (size_t)(unsigned)q * EDIM);
        v4f a0 = e0[0], a1 = e0[1], a2 = e0[2], a3 = e0[3];
        v2f m0 = bj + unpack2(hw[(unsigned)s << 6]);
        matvp(a0, a1, a2, a3, w, m0);
        acc += vmax0(m0);
    }
    *(v2f*)(t + ((unsigned)node << 7) + c) = acc;
}

// ================= split-bf16 MFMA GEMM =================
// Stats are NSTAT-way slot-striped: producer block b adds into slot (b & 15);
// consumers sum the 16 slots. Breaks the 391-contender fp32-atomic serial tail.
#define LPAD 40

template<int K, bool PRE_BN, bool POST_STATS, bool OUT_BF16>
__global__ __launch_bounds__(256) void gemm_mfma(
    const float* __restrict__ A, const unsigned short* __restrict__ Wh,
    const unsigned short* __restrict__ Wl, const float* __restrict__ bias,
    const float* __restrict__ preStats, const float* __restrict__ preG, const float* __restrict__ preB,
    void* __restrict__ Cout, float* __restrict__ postStats, int Nrows, float invN)
{
    __shared__ __align__(16) unsigned short Ah[128 * LPAD], Al[128 * LPAD];
    __shared__ __align__(16) unsigned short Bh[128 * LPAD], Bl[128 * LPAD];
    __shared__ float sc[PRE_BN ? K : 1], sb[PRE_BN ? K : 1];
    int tid = threadIdx.x;
    int rbase = blockIdx.x * 128;
    if (PRE_BN) {
        if (tid < K) {
            float Sm = 0.f, Qm = 0.f;
#pragma unroll
            for (int cpy = 0; cpy < NSTAT; ++cpy) {
                Sm += preStats[(cpy << 8) + tid];
                Qm += preStats[(cpy << 8) + 128 + tid];
            }
            float mean = Sm * invN;
            float var = Qm * invN - mean * mean;
            float rstd = rsqrtf(var + 1e-5f);
            float g = preG[tid];
            sc[tid] = rstd * g;
            sb[tid] = preB[tid] - mean * rstd * g;
        }
        __syncthreads();
    }
    int w = tid >> 6, nl = tid & 15, q = (tid >> 4) & 3;
    f4v acc[2][8];
#pragma unroll
    for (int mt = 0; mt < 2; ++mt)
#pragma unroll
        for (int nt = 0; nt < 8; ++nt)
#pragma unroll
            for (int r = 0; r < 4; ++r) acc[mt][nt][r] = 0.f;

    for (int ks = 0; ks < K / 32; ++ks) {
        int k0 = ks * 32;
        if (ks) __syncthreads();
#pragma unroll
        for (int i = 0; i < 4; ++i) {
            int cidx = tid + i * 256;
            int m = cidx >> 3, k4 = (cidx & 7) * 4;
            int gr = rbase + m;
            float4 v = make_float4(0.f, 0.f, 0.f, 0.f);
            if (gr < Nrows) v = *(const float4*)&A[(size_t)gr * K + k0 + k4];
            if (PRE_BN) {
                v.x = fmaxf(v.x * sc[k0 + k4]     + sb[k0 + k4],     0.f);
                v.y = fmaxf(v.y * sc[k0 + k4 + 1] + sb[k0 + k4 + 1], 0.f);
                v.z = fmaxf(v.z * sc[k0 + k4 + 2] + sb[k0 + k4 + 2], 0.f);
                v.w = fmaxf(v.w * sc[k0 + k4 + 3] + sb[k0 + k4 + 3], 0.f);
            }
            unsigned short h0, l0, h1, l1, h2, l2, h3, l3;
            split_bf16(v.x, h0, l0); split_bf16(v.y, h1, l1);
            split_bf16(v.z, h2, l2); split_bf16(v.w, h3, l3);
            uint2 hp, lp;
            hp.x = (unsigned)h0 | ((unsigned)h1 << 16); hp.y = (unsigned)h2 | ((unsigned)h3 << 16);
            lp.x = (unsigned)l0 | ((unsigned)l1 << 16); lp.y = (unsigned)l2 | ((unsigned)l3 << 16);
            *(uint2*)&Ah[m * LPAD + k4] = hp;
            *(uint2*)&Al[m * LPAD + k4] = lp;
        }
#pragma unroll
        for (int i = 0; i < 2; ++i) {
            int g = tid + i * 256;
            int n = g >> 2, kq = (g & 3) * 8;
            uint4 hv = *(const uint4*)&Wh[(size_t)n * K + k0 + kq];
            uint4 lv = *(const uint4*)&Wl[(size_t)n * K + k0 + kq];
            *(uint4*)&Bh[n * LPAD + kq] = hv;
            *(uint4*)&Bl[n * LPAD + kq] = lv;
        }
        __syncthreads();
        s8v ah0 = *(const s8v*)&Ah[(w * 32 + nl) * LPAD + q * 8];
        s8v ah1 = *(const s8v*)&Ah[(w * 32 + 16 + nl) * LPAD + q * 8];
        s8v al0 = *(const s8v*)&Al[(w * 32 + nl) * LPAD + q * 8];
        s8v al1 = *(const s8v*)&Al[(w * 32 + 16 + nl) * LPAD + q * 8];
#pragma unroll
        for (int nt = 0; nt < 8; ++nt) {
            s8v bh = *(const s8v*)&Bh[(nt * 16 + nl) * LPAD + q * 8];
            s8v bl = *(const s8v*)&Bl[(nt * 16 + nl) * LPAD + q * 8];
            acc[0][nt] = MFMA_BF16(ah0, bh, acc[0][nt]);
            acc[0][nt] = MFMA_BF16(ah0, bl, acc[0][nt]);
            acc[0][nt] = MFMA_BF16(al0, bh, acc[0][nt]);
            acc[1][nt] = MFMA_BF16(ah1, bh, acc[1][nt]);
            acc[1][nt] = MFMA_BF16(ah1, bl, acc[1][nt]);
            acc[1][nt] = MFMA_BF16(al1, bh, acc[1][nt]);
        }
    }
    __syncthreads();

    float* Cf = (float*)Cout;
    unsigned short* Ch = (unsigned short*)Cout;
    float* redS = (float*)Ah;
    float* redQ = (float*)Al;
#pragma unroll
    for (int nt = 0; nt < 8; ++nt) {
        int col = nt * 16 + nl;
        float bcol = bias[col];
        float sv = 0.f, qv = 0.f;
#pragma unroll
        for (int mt = 0; mt < 2; ++mt) {
#pragma unroll
            for (int r = 0; r < 4; ++r) {
                int grow = rbase + w * 32 + mt * 16 + q * 4 + r;
                if (grow < Nrows) {
                    float o = acc[mt][nt][r] + bcol;
                    if (OUT_BF16) Ch[(size_t)grow * HID + col] = bf16_rne(o);
                    else          Cf[(size_t)grow * HID + col] = o;
                    if (POST_STATS) { sv += o; qv += o * o; }
                }
            }
        }
        if (POST_STATS) {
            sv += __shfl_down(sv, 32, 64); sv += __shfl_down(sv, 16, 64);
            qv += __shfl_down(qv, 32, 64); qv += __shfl_down(qv, 16, 64);
            if ((tid & 63) < 16) { redS[w * 128 + col] = sv; redQ[w * 128 + col] = qv; }
        }
    }
    if (POST_STATS) {
        __syncthreads();
        if (tid < 128) {
            float S = redS[tid] + redS[128 + tid] + redS[256 + tid] + redS[384 + tid];
            float Q = redQ[tid] + redQ[128 + tid] + redQ[256 + tid] + redQ[384 + tid];
            int cp = (blockIdx.x & (NSTAT - 1)) << 8;   // slot-striped: ~25 contenders/addr
            atomicAdd(&postStats[cp + tid], S);
            atomicAdd(&postStats[cp + 128 + tid], Q);
        }
    }
}

// ======== fused BN apply + ReLU + pool; h stored as packed bf16 (pool uses exact fp32) ========
__global__ void bn_apply_pool(const float* __restrict__ X, unsigned short* __restrict__ h16,
                              const float* __restrict__ stats, const float* __restrict__ g,
                              const float* __restrict__ b, const int* __restrict__ starts,
                              float* __restrict__ z, int l, float invN)
{
    int gph = blockIdx.x;
    int tid = threadIdx.x;
    int ch4 = (tid & 31) * 4, wk = tid >> 5;   // 16 walkers x 32 lanes(float4)
    float sc[4], sh[4];
#pragma unroll
    for (int u = 0; u < 4; ++u) {
        int j = ch4 + u;
        float Sm = 0.f, Qm = 0.f;
#pragma unroll
        for (int cpy = 0; cpy < NSTAT; ++cpy) {
            Sm += stats[(cpy << 8) + j];
            Qm += stats[(cpy << 8) + 128 + j];
        }
        float mean = Sm * invN;
        float var = Qm * invN - mean * mean;
        float rstd = rsqrtf(var + 1e-5f);
        float gg = g[j];
        sc[u] = rstd * gg;
        sh[u] = b[j] - mean * rstd * gg;
    }
    int s = starts[gph], e = starts[gph + 1];
    float4 sum = make_float4(0.f, 0.f, 0.f, 0.f);
    float4 mx = make_float4(0.f, 0.f, 0.f, 0.f);
    unsigned* hv32 = (unsigned*)h16;
    for (int n = s + wk; n < e; n += 16) {
        float4 v = *(const float4*)&X[(size_t)n * HID + ch4];
        v.x = fmaxf(v.x * sc[0] + sh[0], 0.f);
        v.y = fmaxf(v.y * sc[1] + sh[1], 0.f);
        v.z = fmaxf(v.z * sc[2] + sh[2], 0.f);
        v.w = fmaxf(v.w * sc[3] + sh[3], 0.f);
        uint2 pk;
        pk.x = pack2(v.x, v.y);
        pk.y = pack2(v.z, v.w);
        *(uint2*)&hv32[(size_t)n * 64 + (ch4 >> 1)] = pk;
        sum.x += v.x; sum.y += v.y; sum.z += v.z; sum.w += v.w;
        mx.x = fmaxf(mx.x, v.x); mx.y = fmaxf(mx.y, v.y);
        mx.z = fmaxf(mx.z, v.z); mx.w = fmaxf(mx.w, v.w);
    }
    __shared__ float ls[16 * 128], lm[16 * 128];
    *(float4*)&ls[wk * 128 + ch4] = sum;
    *(float4*)&lm[wk * 128 + ch4] = mx;
    __syncthreads();
    if (tid < 128) {
        float S = 0.f, M = 0.f;
#pragma unroll
        for (int k = 0; k < 16; ++k) {
            S += ls[k * 128 + tid];
            M = fmaxf(M, lm[k * 128 + tid]);
        }
        float cnt = (float)(e - s);
        z[(size_t)gph * 768 + l * 128 + tid] = S / fmaxf(cnt, 1.f);
        z[(size_t)gph * 768 + 384 + l * 128 + tid] = M;
    }
}

// ================= segment boundaries (batch sorted) =================
__global__ void starts_kernel(const int* __restrict__ batch, int* __restrict__ starts,
                              int Nn, int Gn)
{
    int g = blockIdx.x * blockDim.x + threadIdx.x;
    if (g > Gn) return;
    int lo = 0, hi = Nn;
    while (lo < hi) { int mid = (lo + hi) >> 1; if (batch[mid] < g) lo = mid + 1; else hi = mid; }
    starts[g] = lo;
}

// ================= head =================
__global__ void head_gemm1(const float* __restrict__ z, const float* __restrict__ W,
                           const float* __restrict__ bias, float* __restrict__ zr,
                           float* __restrict__ msums)
{
    __shared__ __align__(16) float zl[768];
    int g = blockIdx.x, j = threadIdx.x;
    for (int i = j; i < 768; i += 128) zl[i] = z[(size_t)g * 768 + i];
    __syncthreads();
    float acc = bias[j];
    for (int k = 0; k < 768; k += 4) {
        float4 a4 = *(const float4*)&zl[k];
        acc += a4.x * W[k * 128 + j] + a4.y * W[(k + 1) * 128 + j]
             + a4.z * W[(k + 2) * 128 + j] + a4.w * W[(k + 3) * 128 + j];
    }
    zr[(size_t)g * 128 + j] = acc;
    int cp = (g & (NSTAT - 1)) << 8;   // slot-striped msums
    atomicAdd(&msums[cp + j], acc);
    atomicAdd(&msums[cp + 128 + j], acc * acc);
}

__global__ void head_final(const float* __restrict__ zr, const float* __restrict__ msums,
                           const float* __restrict__ hg, const float* __restrict__ hb,
                           const float* __restrict__ W2, const float* __restrict__ b2,
                           float* __restrict__ out, float invG)
{
    int g = blockIdx.x, j = threadIdx.x;
    float Sm = 0.f, Qm = 0.f;
#pragma unroll
    for (int cpy = 0; cpy < NSTAT; ++cpy) {
        Sm += msums[(cpy << 8) + j];
        Qm += msums[(cpy << 8) + 128 + j];
    }
    float mean = Sm * invG;
    float var = Qm * invG - mean * mean;
    float rstd = rsqrtf(var + 1e-5f);
    float v = zr[(size_t)g * 128 + j];
    v = (v - mean) * rstd * hg[j] + hb[j];
    v = fmaxf(v, 0.f);
    float p = v * W2[j];
#pragma unroll
    for (int off = 32; off > 0; off >>= 1) p += __shfl_down(p, off, 64);
    __shared__ float partial[2];
    if ((j & 63) == 0) partial[j >> 6] = p;
    __syncthreads();
    if (j == 0) out[g] = partial[0] + partial[1] + b2[0];
}

extern "C" void kernel_launch(void* const* d_in, const int* in_sizes, int n_in,
                              void* d_out, int out_size, void* d_ws, size_t ws_size,
                              hipStream_t stream)
{
    const float* x         = (const float*)d_in[0];
    const float* edge_attr = (const float*)d_in[1];
    const int*   src       = (const int*)d_in[2];
    const int*   dst       = (const int*)d_in[3];
    const int*   batch     = (const int*)d_in[4];
    const float* Wp        = (const float*)d_in[5];
    const float* bp        = (const float*)d_in[6];
    const float* conv_We   = (const float*)d_in[7];
    const float* conv_be   = (const float*)d_in[8];
    const float* conv_W1   = (const float*)d_in[9];
    const float* conv_b1   = (const float*)d_in[10];
    const float* conv_g1   = (const float*)d_in[11];
    const float* conv_bt1  = (const float*)d_in[12];
    const float* conv_W2   = (const float*)d_in[13];
    const float* conv_b2   = (const float*)d_in[14];
    const float* bn_g      = (const float*)d_in[15];
    const float* bn_b      = (const float*)d_in[16];
    const float* head_W1   = (const float*)d_in[17];
    const float* head_b1   = (const float*)d_in[18];
    const float* head_g    = (const float*)d_in[19];
    const float* head_bt   = (const float*)d_in[20];
    const float* head_W2   = (const float*)d_in[21];
    const float* head_b2   = (const float*)d_in[22];

    const int N = in_sizes[4];            // 50000
    const int E = in_sizes[2];            // 800000
    const int G = out_size;               // 256
    const int L = 3;

    // ---- workspace layout ----
    const int SLOT = NSTAT * 256;                    // 4096 floats per stat set
    float* t        = (float*)d_ws;                  // N*128 fp32
    unsigned short* h16 = (unsigned short*)(t + (size_t)N * HID);  // N*128 bf16
    float* z        = (float*)(h16 + (size_t)N * HID);             // G*768
    float* zr       = z + (size_t)G * 768;           // G*128
    float* statsAll = zr + (size_t)G * HID;          // 7 sets x SLOT
    int*   deg      = (int*)(statsAll + 7 * SLOT);   // N
    int*   starts   = deg + N;                       // G+1
    int*   row_start= starts + (G + 1);              // N+1
    int*   cursor   = row_start + (N + 1);           // N
    int*   bsum     = cursor + N;                    // 256
    int*   src_perm = bsum + 256;                    // E
    int*   perm     = src_perm + E;                  // E
    unsigned short* wt = (unsigned short*)(perm + E);  // 212992 ushorts gemm weights
    size_t base_end = (size_t)((char*)(wt + 212992) - (char*)d_ws);
    size_t ea_off = (base_end + 63) & ~(size_t)63;   // 64B-align ea rows
    bool gath = (ea_off + (size_t)E * 8 * sizeof(unsigned)) <= ws_size;  // f16 rows: 32B/edge
    unsigned* eaH = (unsigned*)((char*)d_ws + ea_off);
    float* msums = statsAll + 6 * SLOT;

    (void)n_in;

    const float invN = 1.0f / (float)N;
    const float invG = 1.0f / (float)G;
    const int nb = (N + 255) / 256;
    const int gemmBlocks = (N + 127) / 128;

    // ---- CSR build + weight prep ----
    (void)hipMemsetAsync(statsAll, 0, 7 * SLOT * sizeof(float) + (size_t)N * sizeof(int), stream);
    hist_kernel<<<(E + 255) / 256, 256, 0, stream>>>(dst, deg, E);
    block_sum_kernel<<<nb, 256, 0, stream>>>(deg, bsum, N);
    bsum_scan_kernel<<<1, 256, 0, stream>>>(bsum, nb, &row_start[N]);
    block_scan_kernel<<<nb, 256, 0, stream>>>(deg, bsum, row_start, cursor, N);
    scatter_kernel<<<(E + 255) / 256, 256, 0, stream>>>(src, dst, cursor, perm, src_perm, E);
    if (gath)
        gather_ea_f16<<<(E * 2 + 255) / 256, 256, 0, stream>>>(edge_attr, perm, eaH, E);
    starts_kernel<<<1, 512, 0, stream>>>(batch, starts, N, G);
    prep_weights<<<(8192 + 6 * 16384 + 255) / 256, 256, 0, stream>>>(Wp, conv_W1, conv_W2, wt);

    const unsigned short* Wp_hi = wt;
    const unsigned short* Wp_lo = wt + 8192;

    // h16 = bf16(x @ Wp + bp)
    gemm_mfma<64, false, false, true><<<gemmBlocks, 256, 0, stream>>>(
        x, Wp_hi, Wp_lo, bp, nullptr, nullptr, nullptr, h16, nullptr, N, invN);

    for (int l = 0; l < L; ++l) {
        float* sI = statsAll + (size_t)(2 * l) * SLOT;
        float* sO = sI + SLOT;
        const unsigned short* W1hi = wt + 16384 + (size_t)(2 * l) * 32768;
        const unsigned short* W1lo = W1hi + 16384;
        const unsigned short* W2hi = wt + 16384 + (size_t)(2 * l + 1) * 32768;
        const unsigned short* W2lo = W2hi + 16384;
        if (gath)
            aggregate_f16<<<(N + 3) / 4, 256, 0, stream>>>(
                h16, eaH, src_perm, row_start,
                conv_We + (size_t)l * EDIM * HID, conv_be + l * HID, t, N);
        else
            aggregate_fp32<<<(N + 3) / 4, 256, 0, stream>>>(
                h16, edge_attr, perm, src_perm, row_start,
                conv_We + (size_t)l * EDIM * HID, conv_be + l * HID, t, N);
        gemm_mfma<128, false, true, false><<<gemmBlocks, 256, 0, stream>>>(
            t, W1hi, W1lo, conv_b1 + l * HID,
            nullptr, nullptr, nullptr, t, sI, N, invN);
        gemm_mfma<128, true, true, false><<<gemmBlocks, 256, 0, stream>>>(
            t, W2hi, W2lo, conv_b2 + l * HID,
            sI, conv_g1 + l * HID, conv_bt1 + l * HID, t, sO, N, invN);
        bn_apply_pool<<<G, 512, 0, stream>>>(
            t, h16, sO, bn_g + l * HID, bn_b + l * HID, starts, z, l, invN);
    }

    head_gemm1<<<G, 128, 0, stream>>>(z, head_W1, head_b1, zr, msums);
    head_final<<<G, 128, 0, stream>>>(zr, msums, head_g, head_bt, head_W2, head_b2,
                                      (float*)d_out, invG);
}

// Round 12
// 631.790 us; speedup vs baseline: 1.1872x; 1.0051x over previous
//
#include <hip/hip_runtime.h>
#include <hip/hip_bf16.h>
#include <hip/hip_fp16.h>

#define HID 128
#define EDIM 16
#define NSTAT 16   // stat-slot copies to break atomic serialization

typedef float v4f __attribute__((ext_vector_type(4)));
typedef float v2f __attribute__((ext_vector_type(2)));
typedef short s8v __attribute__((ext_vector_type(8)));   // 8 bf16 (4 VGPRs) MFMA frag
typedef float f4v __attribute__((ext_vector_type(4)));   // MFMA acc
typedef unsigned int u8x __attribute__((ext_vector_type(8)));  // 8 dwords = 16 f16
typedef _Float16 h2v __attribute__((ext_vector_type(2)));      // f16 pair for fdot2

#define MFMA_BF16(a, b, c) __builtin_amdgcn_mfma_f32_16x16x32_bf16((a), (b), (c), 0, 0, 0)

__device__ __forceinline__ unsigned short bf16_rne(float v)
{
    unsigned u = __builtin_bit_cast(unsigned, v);
    return (unsigned short)((u + 0x7fffu + ((u >> 16) & 1u)) >> 16);
}

__device__ __forceinline__ unsigned pack2(float lo, float hi)
{
    return (unsigned)bf16_rne(lo) | ((unsigned)bf16_rne(hi) << 16);
}

__device__ __forceinline__ float bflo(unsigned u) { return __builtin_bit_cast(float, u << 16); }
__device__ __forceinline__ float bfhi(unsigned u) { return __builtin_bit_cast(float, u & 0xffff0000u); }

__device__ __forceinline__ v2f unpack2(unsigned u)
{
    v2f r; r.x = bflo(u); r.y = bfhi(u); return r;
}

__device__ __forceinline__ void split_bf16(float v, unsigned short& h, unsigned short& l)
{
    unsigned u = __builtin_bit_cast(unsigned, v);
    unsigned hu = (u + 0x7fffu + ((u >> 16) & 1u)) >> 16;
    h = (unsigned short)hu;
    float hf = __builtin_bit_cast(float, hu << 16);
    l = bf16_rne(v - hf);
}

__device__ __forceinline__ v2f vmax0(v2f a)
{
    v2f r; r.x = fmaxf(a.x, 0.f); r.y = fmaxf(a.y, 0.f); return r;
}

// pack two floats to f16x2 (RNE)
__device__ __forceinline__ unsigned pkh2(float lo, float hi)
{
    return (unsigned)__half_as_ushort(__float2half(lo)) |
           ((unsigned)__half_as_ushort(__float2half(hi)) << 16);
}

// d += ea.lo*w.lo + ea.hi*w.hi (fp32 accumulate). Builtin (NOT bare asm): bare
// VOP3P asm assembles wrong default modifiers (round-6 absmax 0.54).
__device__ __forceinline__ void dot2(float& d, unsigned ea, unsigned w)
{
    d = __builtin_amdgcn_fdot2(__builtin_bit_cast(h2v, ea),
                               __builtin_bit_cast(h2v, w), d, false);
}

// ================= CSR build =================
__global__ void hist_kernel(const int* __restrict__ dst, int* __restrict__ deg, int E)
{
    int e = blockIdx.x * 256 + threadIdx.x;
    if (e < E) atomicAdd(&deg[dst[e]], 1);
}

__global__ void block_sum_kernel(const int* __restrict__ deg, int* __restrict__ bsum, int Nn)
{
    int i = blockIdx.x * 256 + threadIdx.x;
    int v = (i < Nn) ? deg[i] : 0;
#pragma unroll
    for (int off = 32; off > 0; off >>= 1) v += __shfl_down(v, off, 64);
    __shared__ int ws[4];
    if ((threadIdx.x & 63) == 0) ws[threadIdx.x >> 6] = v;
    __syncthreads();
    if (threadIdx.x == 0) bsum[blockIdx.x] = ws[0] + ws[1] + ws[2] + ws[3];
}

__global__ void bsum_scan_kernel(int* bsum, int nb, int* total_out)
{
    __shared__ int sh[256];
    int tid = threadIdx.x;
    int v = (tid < nb) ? bsum[tid] : 0;
    sh[tid] = v;
    __syncthreads();
    for (int off = 1; off < 256; off <<= 1) {
        int tv = (tid >= off) ? sh[tid - off] : 0;
        __syncthreads();
        sh[tid] += tv;
        __syncthreads();
    }
    if (tid < nb) bsum[tid] = sh[tid] - v;
    if (tid == 255) *total_out = sh[255];
}

__global__ void block_scan_kernel(const int* __restrict__ deg, const int* __restrict__ bsum,
                                  int* __restrict__ row_start, int* __restrict__ cursor, int Nn)
{
    __shared__ int sh[256];
    int tid = threadIdx.x;
    int i = blockIdx.x * 256 + tid;
    int v = (i < Nn) ? deg[i] : 0;
    sh[tid] = v;
    __syncthreads();
    for (int off = 1; off < 256; off <<= 1) {
        int tv = (tid >= off) ? sh[tid - off] : 0;
        __syncthreads();
        sh[tid] += tv;
        __syncthreads();
    }
    if (i < Nn) {
        int excl = sh[tid] - v + bsum[blockIdx.x];
        row_start[i] = excl;
        cursor[i] = excl;
    }
}

// phase 1: permutation only (12B/edge traffic; scattered 4B writes live in L2)
__global__ void scatter_kernel(const int* __restrict__ src, const int* __restrict__ dst,
                               int* cursor, int* __restrict__ perm,
                               int* __restrict__ src_perm, int E)
{
    int e = blockIdx.x * 256 + threadIdx.x;
    if (e >= E) return;
    int pos = atomicAdd(&cursor[dst[e]], 1);
    perm[pos] = e;
    src_perm[pos] = src[e];
}

// phase 2: ea permute-copy + f16 convert — scattered READS, coalesced 16B writes.
// 2 threads per edge row; row = 8 dwords (16 f16).
__global__ void gather_ea_f16(const float* __restrict__ ea, const int* __restrict__ perm,
                              unsigned* __restrict__ eaH, int E)
{
    int idx = blockIdx.x * 256 + threadIdx.x;
    int p = idx >> 1, hf = idx & 1;
    if (p >= E) return;
    int e = perm[p];
    const float* ap = &ea[(size_t)e * EDIM + hf * 8];
    float4 f0 = *(const float4*)ap;
    float4 f1 = *(const float4*)(ap + 4);
    uint4 o;
    o.x = pkh2(f0.x, f0.y);
    o.y = pkh2(f0.z, f0.w);
    o.z = pkh2(f1.x, f1.y);
    o.w = pkh2(f1.z, f1.w);
    *(uint4*)&eaH[(size_t)p * 8 + hf * 4] = o;
}

// ================= weight prep: fp32 [K,128] -> transposed split-bf16 [128,K] hi/lo =================
__global__ void prep_weights(const float* __restrict__ Wp, const float* __restrict__ W1,
                             const float* __restrict__ W2, unsigned short* __restrict__ out)
{
    int idx = blockIdx.x * 256 + threadIdx.x;
    if (idx < 8192) {
        int n = idx >> 6, k = idx & 63;
        unsigned short h, l;
        split_bf16(Wp[k * 128 + n], h, l);
        out[idx] = h;
        out[8192 + idx] = l;
    } else {
        int j = idx - 8192;
        if (j >= 6 * 16384) return;
        int m2 = j >> 14;
        int r = j & 16383;
        int n = r >> 7, k = r & 127;
        int l = m2 >> 1;
        const float* Wsrc = (m2 & 1) ? (W2 + l * 16384) : (W1 + l * 16384);
        unsigned short h, lo;
        split_bf16(Wsrc[k * 128 + n], h, lo);
        int base = 16384 + m2 * 32768;
        out[base + r] = h;
        out[base + 16384 + r] = lo;
    }
}

// ====== Node-centric aggregation (r7 structure, ~62 µs): f16 ea + fdot2 ======
// 1 wave/node, 2 ch/lane. ea rows wave-uniform -> SGPR (8 dwords/row);
// 16 dot2/edge. 8-edge groups: one lgkmcnt drain per 8 edges.
// h gathers rotated one group ahead (VMEM, counted).
// PACK: store each output channel as u32 = bf16_hi | (bf16_lo<<16) IN t (same
// 4B/elem) so the W1 GEMM stages with bit-ops only — bit-identical to
// fp32-store-then-split (split-at-producer == split-at-consumer).
__device__ __forceinline__ void edge_f16(v2f& acc, v2f bj, unsigned hu, const u8x& e,
                                         const unsigned* __restrict__ wpk0,
                                         const unsigned* __restrict__ wpk1)
{
    float m0 = bj.x + bflo(hu);
    float m1 = bj.y + bfhi(hu);
#pragma unroll
    for (int kp = 0; kp < 8; ++kp) {
        dot2(m0, e[kp], wpk0[kp]);
        dot2(m1, e[kp], wpk1[kp]);
    }
    acc.x += fmaxf(m0, 0.f);
    acc.y += fmaxf(m1, 0.f);
}

template<bool PACK>
__global__ __launch_bounds__(256, 8) void aggregate_f16(
    const unsigned short* __restrict__ h16, const unsigned* __restrict__ eaH,
    const int* __restrict__ src_perm, const int* __restrict__ row_start,
    const float* __restrict__ We, const float* __restrict__ be,
    float* __restrict__ t, int Nn)
{
    int tid = threadIdx.x;
    int lane = tid & 63;
    int c = lane * 2;
    // f16 weight k-pairs per output channel (16 VGPRs)
    unsigned wpk0[8], wpk1[8];
#pragma unroll
    for (int kp = 0; kp < 8; ++kp) {
        wpk0[kp] = pkh2(We[(2 * kp) * HID + c],     We[(2 * kp + 1) * HID + c]);
        wpk1[kp] = pkh2(We[(2 * kp) * HID + c + 1], We[(2 * kp + 1) * HID + c + 1]);
    }
    v2f bj = *(const v2f*)&be[c];
    int node = blockIdx.x * 4 + (tid >> 6);
    if (node >= Nn) return;
    const unsigned* __restrict__ hw = (const unsigned*)h16 + lane;  // bf16 ch-pair per lane
    v2f acc = unpack2(hw[(unsigned)node << 6]);
    int p0 = __builtin_amdgcn_readfirstlane(row_start[node]);
    int p1 = __builtin_amdgcn_readfirstlane(row_start[node + 1]);
    int p = p0;

    int s0 = 0, s1 = 0, s2 = 0, s3 = 0, s4 = 0, s5 = 0, s6 = 0, s7 = 0;
    unsigned hu0 = 0, hu1 = 0, hu2 = 0, hu3 = 0, hu4 = 0, hu5 = 0, hu6 = 0, hu7 = 0;
    if (p + 8 <= p1) {
        s0 = src_perm[p];     s1 = src_perm[p + 1]; s2 = src_perm[p + 2]; s3 = src_perm[p + 3];
        s4 = src_perm[p + 4]; s5 = src_perm[p + 5]; s6 = src_perm[p + 6]; s7 = src_perm[p + 7];
        hu0 = hw[(unsigned)s0 << 6]; hu1 = hw[(unsigned)s1 << 6];
        hu2 = hw[(unsigned)s2 << 6]; hu3 = hw[(unsigned)s3 << 6];
        hu4 = hw[(unsigned)s4 << 6]; hu5 = hw[(unsigned)s5 << 6];
        hu6 = hw[(unsigned)s6 << 6]; hu7 = hw[(unsigned)s7 << 6];
    }
    while (p + 8 <= p1) {
        int np = p + 8;
        // current group's ea rows (SMEM, 8 x dwordx8)
        u8x e0 = *(const u8x*)(eaH + (size_t)(unsigned)(p    ) * 8);
        u8x e1 = *(const u8x*)(eaH + (size_t)(unsigned)(p + 1) * 8);
        u8x e2 = *(const u8x*)(eaH + (size_t)(unsigned)(p + 2) * 8);
        u8x e3 = *(const u8x*)(eaH + (size_t)(unsigned)(p + 3) * 8);
        u8x e4 = *(const u8x*)(eaH + (size_t)(unsigned)(p + 4) * 8);
        u8x e5 = *(const u8x*)(eaH + (size_t)(unsigned)(p + 5) * 8);
        u8x e6 = *(const u8x*)(eaH + (size_t)(unsigned)(p + 6) * 8);
        u8x e7 = *(const u8x*)(eaH + (size_t)(unsigned)(p + 7) * 8);
        // next group's src ids + h rows (prefetch)
        int t0 = 0, t1 = 0, t2 = 0, t3 = 0, t4 = 0, t5 = 0, t6 = 0, t7 = 0;
        unsigned hn0 = 0, hn1 = 0, hn2 = 0, hn3 = 0, hn4 = 0, hn5 = 0, hn6 = 0, hn7 = 0;
        if (np + 8 <= p1) {
            t0 = src_perm[np];     t1 = src_perm[np + 1]; t2 = src_perm[np + 2]; t3 = src_perm[np + 3];
            t4 = src_perm[np + 4]; t5 = src_perm[np + 5]; t6 = src_perm[np + 6]; t7 = src_perm[np + 7];
            hn0 = hw[(unsigned)t0 << 6]; hn1 = hw[(unsigned)t1 << 6];
            hn2 = hw[(unsigned)t2 << 6]; hn3 = hw[(unsigned)t3 << 6];
            hn4 = hw[(unsigned)t4 << 6]; hn5 = hw[(unsigned)t5 << 6];
            hn6 = hw[(unsigned)t6 << 6]; hn7 = hw[(unsigned)t7 << 6];
        }
        edge_f16(acc, bj, hu0, e0, wpk0, wpk1);
        edge_f16(acc, bj, hu1, e1, wpk0, wpk1);
        edge_f16(acc, bj, hu2, e2, wpk0, wpk1);
        edge_f16(acc, bj, hu3, e3, wpk0, wpk1);
        edge_f16(acc, bj, hu4, e4, wpk0, wpk1);
        edge_f16(acc, bj, hu5, e5, wpk0, wpk1);
        edge_f16(acc, bj, hu6, e6, wpk0, wpk1);
        edge_f16(acc, bj, hu7, e7, wpk0, wpk1);
        p = np;
        s0 = t0; s1 = t1; s2 = t2; s3 = t3; s4 = t4; s5 = t5; s6 = t6; s7 = t7;
        hu0 = hn0; hu1 = hn1; hu2 = hn2; hu3 = hn3;
        hu4 = hn4; hu5 = hn5; hu6 = hn6; hu7 = hn7;
    }
    for (; p < p1; ++p) {
        int s = src_perm[p];
        unsigned hu = hw[(unsigned)s << 6];
        u8x e = *(const u8x*)(eaH + (size_t)(unsigned)p * 8);
        edge_f16(acc, bj, hu, e, wpk0, wpk1);
    }
    if (PACK) {
        unsigned short h0, l0, h1, l1;
        split_bf16(acc.x, h0, l0);
        split_bf16(acc.y, h1, l1);
        uint2 pk;
        pk.x = (unsigned)h0 | ((unsigned)l0 << 16);
        pk.y = (unsigned)h1 | ((unsigned)l1 << 16);
        *(uint2*)((unsigned*)t + ((unsigned)node << 7) + c) = pk;
    } else {
        *(v2f*)(t + ((unsigned)node << 7) + c) = acc;
    }
}

// ====== fallback (no workspace for eaH): round-0 fp32 path via perm indirection ======
__device__ __forceinline__ void matvp(const v4f& a0, const v4f& a1,
                                      const v4f& a2, const v4f& a3,
                                      const v2f* __restrict__ w, v2f& m)
{
    m += w[0] * a0.x;  m += w[1] * a0.y;  m += w[2] * a0.z;  m += w[3] * a0.w;
    m += w[4] * a1.x;  m += w[5] * a1.y;  m += w[6] * a1.z;  m += w[7] * a1.w;
    m += w[8] * a2.x;  m += w[9] * a2.y;  m += w[10] * a2.z; m += w[11] * a2.w;
    m += w[12] * a3.x; m += w[13] * a3.y; m += w[14] * a3.z; m += w[15] * a3.w;
}

__global__ __launch_bounds__(256, 8) void aggregate_fp32(
    const unsigned short* __restrict__ h16, const float* __restrict__ eaG,
    const int* __restrict__ perm, const int* __restrict__ src_perm,
    const int* __restrict__ row_start,
    const float* __restrict__ We, const float* __restrict__ be,
    float* __restrict__ t, int Nn)
{
    int tid = threadIdx.x;
    int lane = tid & 63;
    int c = lane * 2;
    v2f w[16];
#pragma unroll
    for (int k = 0; k < 16; ++k) w[k] = *(const v2f*)&We[k * HID + c];
    v2f bj = *(const v2f*)&be[c];
    int node = blockIdx.x * 4 + (tid >> 6);
    if (node >= Nn) return;
    const unsigned* __restrict__ hw = (const unsigned*)h16 + lane;
    v2f acc = unpack2(hw[(unsigned)node << 6]);
    int p0 = __builtin_amdgcn_readfirstlane(row_start[node]);
    int p1 = __builtin_amdgcn_readfirstlane(row_start[node + 1]);
    int p = p0;
    int s0 = 0, s1 = 0, s2 = 0, s3 = 0;
    if (p + 4 <= p1) { s0 = src_perm[p]; s1 = src_perm[p + 1]; s2 = src_perm[p + 2]; s3 = src_perm[p + 3]; }
    while (p + 4 <= p1) {
        int np = p + 4;
        int t0 = 0, t1 = 0, t2 = 0, t3 = 0;
        if (np + 4 <= p1) { t0 = src_perm[np]; t1 = src_perm[np + 1]; t2 = src_perm[np + 2]; t3 = src_perm[np + 3]; }
        unsigned hu0 = hw[(unsigned)s0 << 6];
        unsigned hu1 = hw[(unsigned)s1 << 6];
        unsigned hu2 = hw[(unsigned)s2 << 6];
        unsigned hu3 = hw[(unsigned)s3 << 6];
        int q0 = perm[p], q1 = perm[p + 1], q2 = perm[p + 2], q3 = perm[p + 3];
        const v4f* e0 = (const v4f*)(eaG + (size_t)(unsigned)q0 * EDIM);
        const v4f* e1 = (const v4f*)(eaG + (size_t)(unsigned)q1 * EDIM);
        const v4f* e2 = (const v4f*)(eaG + (size_t)(unsigned)q2 * EDIM);
        const v4f* e3 = (const v4f*)(eaG + (size_t)(unsigned)q3 * EDIM);
        v4f a00 = e0[0], a01 = e0[1], a02 = e0[2], a03 = e0[3];
        v4f a10 = e1[0], a11 = e1[1], a12 = e1[2], a13 = e1[3];
        v4f a20 = e2[0], a21 = e2[1], a22 = e2[2], a23 = e2[3];
        v4f a30 = e3[0], a31 = e3[1], a32 = e3[2], a33 = e3[3];
        v2f m0 = bj + unpack2(hu0), m1 = bj + unpack2(hu1);
        v2f m2 = bj + unpack2(hu2), m3 = bj + unpack2(hu3);
        matvp(a00, a01, a02, a03, w, m0);
        matvp(a10, a11, a12, a13, w, m1);
        matvp(a20, a21, a22, a23, w, m2);
        matvp(a30, a31, a32, a33, w, m3);
        acc += (vmax0(m0) + vmax0(m1)) + (vmax0(m2) + vmax0(m3));
        p = np;
        s0 = t0; s1 = t1; s2 = t2; s3 = t3;
    }
    for (; p < p1; ++p) {
        int s = src_perm[p];
        int q = perm[p];
        const v4f* e0 = (const v4f*)(eaG + (size_t)(unsigned)q * EDIM);
        v4f a0 = e0[0], a1 = e0[1], a2 = e0[2], a3 = e0[3];
        v2f m0 = bj + unpack2(hw[(unsigned)s << 6]);
        matvp(a0, a1, a2, a3, w, m0);
        acc += vmax0(m0);
    }
    *(v2f*)(t + ((unsigned)node << 7) + c) = acc;
}

// ================= split-bf16 MFMA GEMM =================
// Stats are NSTAT-way slot-striped (r11, −44 µs): producer block b adds into
// slot (b & 15); consumers sum the 16 slots.
// A_PACK: A rows are packed-split u32 (hi | lo<<16) — staging is bit-ops only.
#define LPAD 40

template<int K, bool PRE_BN, bool POST_STATS, bool OUT_BF16, bool A_PACK>
__global__ __launch_bounds__(256) void gemm_mfma(
    const float* __restrict__ A, const unsigned short* __restrict__ Wh,
    const unsigned short* __restrict__ Wl, const float* __restrict__ bias,
    const float* __restrict__ preStats, const float* __restrict__ preG, const float* __restrict__ preB,
    void* __restrict__ Cout, float* __restrict__ postStats, int Nrows, float invN)
{
    __shared__ __align__(16) unsigned short Ah[128 * LPAD], Al[128 * LPAD];
    __shared__ __align__(16) unsigned short Bh[128 * LPAD], Bl[128 * LPAD];
    __shared__ float sc[PRE_BN ? K : 1], sb[PRE_BN ? K : 1];
    int tid = threadIdx.x;
    int rbase = blockIdx.x * 128;
    if (PRE_BN) {
        if (tid < K) {
            float Sm = 0.f, Qm = 0.f;
#pragma unroll
            for (int cpy = 0; cpy < NSTAT; ++cpy) {
                Sm += preStats[(cpy << 8) + tid];
                Qm += preStats[(cpy << 8) + 128 + tid];
            }
            float mean = Sm * invN;
            float var = Qm * invN - mean * mean;
            float rstd = rsqrtf(var + 1e-5f);
            float g = preG[tid];
            sc[tid] = rstd * g;
            sb[tid] = preB[tid] - mean * rstd * g;
        }
        __syncthreads();
    }
    int w = tid >> 6, nl = tid & 15, q = (tid >> 4) & 3;
    f4v acc[2][8];
#pragma unroll
    for (int mt = 0; mt < 2; ++mt)
#pragma unroll
        for (int nt = 0; nt < 8; ++nt)
#pragma unroll
            for (int r = 0; r < 4; ++r) acc[mt][nt][r] = 0.f;

    for (int ks = 0; ks < K / 32; ++ks) {
        int k0 = ks * 32;
        if (ks) __syncthreads();
#pragma unroll
        for (int i = 0; i < 4; ++i) {
            int cidx = tid + i * 256;
            int m = cidx >> 3, k4 = (cidx & 7) * 4;
            int gr = rbase + m;
            uint2 hp, lp;
            if (A_PACK) {
                uint4 v = make_uint4(0u, 0u, 0u, 0u);
                if (gr < Nrows) v = *(const uint4*)((const unsigned*)A + (size_t)gr * K + k0 + k4);
                hp.x = (v.x & 0xffffu) | (v.y << 16);
                hp.y = (v.z & 0xffffu) | (v.w << 16);
                lp.x = (v.x >> 16) | (v.y & 0xffff0000u);
                lp.y = (v.z >> 16) | (v.w & 0xffff0000u);
            } else {
                float4 v = make_float4(0.f, 0.f, 0.f, 0.f);
                if (gr < Nrows) v = *(const float4*)&A[(size_t)gr * K + k0 + k4];
                if (PRE_BN) {
                    v.x = fmaxf(v.x * sc[k0 + k4]     + sb[k0 + k4],     0.f);
                    v.y = fmaxf(v.y * sc[k0 + k4 + 1] + sb[k0 + k4 + 1], 0.f);
                    v.z = fmaxf(v.z * sc[k0 + k4 + 2] + sb[k0 + k4 + 2], 0.f);
                    v.w = fmaxf(v.w * sc[k0 + k4 + 3] + sb[k0 + k4 + 3], 0.f);
                }
                unsigned short h0, l0, h1, l1, h2, l2, h3, l3;
                split_bf16(v.x, h0, l0); split_bf16(v.y, h1, l1);
                split_bf16(v.z, h2, l2); split_bf16(v.w, h3, l3);
                hp.x = (unsigned)h0 | ((unsigned)h1 << 16); hp.y = (unsigned)h2 | ((unsigned)h3 << 16);
                lp.x = (unsigned)l0 | ((unsigned)l1 << 16); lp.y = (unsigned)l2 | ((unsigned)l3 << 16);
            }
            *(uint2*)&Ah[m * LPAD + k4] = hp;
            *(uint2*)&Al[m * LPAD + k4] = lp;
        }
#pragma unroll
        for (int i = 0; i < 2; ++i) {
            int g = tid + i * 256;
            int n = g >> 2, kq = (g & 3) * 8;
            uint4 hv = *(const uint4*)&Wh[(size_t)n * K + k0 + kq];
            uint4 lv = *(const uint4*)&Wl[(size_t)n * K + k0 + kq];
            *(uint4*)&Bh[n * LPAD + kq] = hv;
            *(uint4*)&Bl[n * LPAD + kq] = lv;
        }
        __syncthreads();
        s8v ah0 = *(const s8v*)&Ah[(w * 32 + nl) * LPAD + q * 8];
        s8v ah1 = *(const s8v*)&Ah[(w * 32 + 16 + nl) * LPAD + q * 8];
        s8v al0 = *(const s8v*)&Al[(w * 32 + nl) * LPAD + q * 8];
        s8v al1 = *(const s8v*)&Al[(w * 32 + 16 + nl) * LPAD + q * 8];
#pragma unroll
        for (int nt = 0; nt < 8; ++nt) {
            s8v bh = *(const s8v*)&Bh[(nt * 16 + nl) * LPAD + q * 8];
            s8v bl = *(const s8v*)&Bl[(nt * 16 + nl) * LPAD + q * 8];
            acc[0][nt] = MFMA_BF16(ah0, bh, acc[0][nt]);
            acc[0][nt] = MFMA_BF16(ah0, bl, acc[0][nt]);
            acc[0][nt] = MFMA_BF16(al0, bh, acc[0][nt]);
            acc[1][nt] = MFMA_BF16(ah1, bh, acc[1][nt]);
            acc[1][nt] = MFMA_BF16(ah1, bl, acc[1][nt]);
            acc[1][nt] = MFMA_BF16(al1, bh, acc[1][nt]);
        }
    }
    __syncthreads();

    float* Cf = (float*)Cout;
    unsigned short* Ch = (unsigned short*)Cout;
    float* redS = (float*)Ah;
    float* redQ = (float*)Al;
#pragma unroll
    for (int nt = 0; nt < 8; ++nt) {
        int col = nt * 16 + nl;
        float bcol = bias[col];
        float sv = 0.f, qv = 0.f;
#pragma unroll
        for (int mt = 0; mt < 2; ++mt) {
#pragma unroll
            for (int r = 0; r < 4; ++r) {
                int grow = rbase + w * 32 + mt * 16 + q * 4 + r;
                if (grow < Nrows) {
                    float o = acc[mt][nt][r] + bcol;
                    if (OUT_BF16) Ch[(size_t)grow * HID + col] = bf16_rne(o);
                    else          Cf[(size_t)grow * HID + col] = o;
                    if (POST_STATS) { sv += o; qv += o * o; }
                }
            }
        }
        if (POST_STATS) {
            sv += __shfl_down(sv, 32, 64); sv += __shfl_down(sv, 16, 64);
            qv += __shfl_down(qv, 32, 64); qv += __shfl_down(qv, 16, 64);
            if ((tid & 63) < 16) { redS[w * 128 + col] = sv; redQ[w * 128 + col] = qv; }
        }
    }
    if (POST_STATS) {
        __syncthreads();
        if (tid < 128) {
            float S = redS[tid] + redS[128 + tid] + redS[256 + tid] + redS[384 + tid];
            float Q = redQ[tid] + redQ[128 + tid] + redQ[256 + tid] + redQ[384 + tid];
            int cp = (blockIdx.x & (NSTAT - 1)) << 8;   // slot-striped: ~25 contenders/addr
            atomicAdd(&postStats[cp + tid], S);
            atomicAdd(&postStats[cp + 128 + tid], Q);
        }
    }
}

// ======== fused BN apply + ReLU + pool; h stored as packed bf16 (pool uses exact fp32) ========
__global__ void bn_apply_pool(const float* __restrict__ X, unsigned short* __restrict__ h16,
                              const float* __restrict__ stats, const float* __restrict__ g,
                              const float* __restrict__ b, const int* __restrict__ starts,
                              float* __restrict__ z, int l, float invN)
{
    int gph = blockIdx.x;
    int tid = threadIdx.x;
    int ch4 = (tid & 31) * 4, wk = tid >> 5;   // 16 walkers x 32 lanes(float4)
    float sc[4], sh[4];
#pragma unroll
    for (int u = 0; u < 4; ++u) {
        int j = ch4 + u;
        float Sm = 0.f, Qm = 0.f;
#pragma unroll
        for (int cpy = 0; cpy < NSTAT; ++cpy) {
            Sm += stats[(cpy << 8) + j];
            Qm += stats[(cpy << 8) + 128 + j];
        }
        float mean = Sm * invN;
        float var = Qm * invN - mean * mean;
        float rstd = rsqrtf(var + 1e-5f);
        float gg = g[j];
        sc[u] = rstd * gg;
        sh[u] = b[j] - mean * rstd * gg;
    }
    int s = starts[gph], e = starts[gph + 1];
    float4 sum = make_float4(0.f, 0.f, 0.f, 0.f);
    float4 mx = make_float4(0.f, 0.f, 0.f, 0.f);
    unsigned* hv32 = (unsigned*)h16;
    for (int n = s + wk; n < e; n += 16) {
        float4 v = *(const float4*)&X[(size_t)n * HID + ch4];
        v.x = fmaxf(v.x * sc[0] + sh[0], 0.f);
        v.y = fmaxf(v.y * sc[1] + sh[1], 0.f);
        v.z = fmaxf(v.z * sc[2] + sh[2], 0.f);
        v.w = fmaxf(v.w * sc[3] + sh[3], 0.f);
        uint2 pk;
        pk.x = pack2(v.x, v.y);
        pk.y = pack2(v.z, v.w);
        *(uint2*)&hv32[(size_t)n * 64 + (ch4 >> 1)] = pk;
        sum.x += v.x; sum.y += v.y; sum.z += v.z; sum.w += v.w;
        mx.x = fmaxf(mx.x, v.x); mx.y = fmaxf(mx.y, v.y);
        mx.z = fmaxf(mx.z, v.z); mx.w = fmaxf(mx.w, v.w);
    }
    __shared__ float ls[16 * 128], lm[16 * 128];
    *(float4*)&ls[wk * 128 + ch4] = sum;
    *(float4*)&lm[wk * 128 + ch4] = mx;
    __syncthreads();
    if (tid < 128) {
        float S = 0.f, M = 0.f;
#pragma unroll
        for (int k = 0; k < 16; ++k) {
            S += ls[k * 128 + tid];
            M = fmaxf(M, lm[k * 128 + tid]);
        }
        float cnt = (float)(e - s);
        z[(size_t)gph * 768 + l * 128 + tid] = S / fmaxf(cnt, 1.f);
        z[(size_t)gph * 768 + 384 + l * 128 + tid] = M;
    }
}

// ================= segment boundaries (batch sorted) =================
__global__ void starts_kernel(const int* __restrict__ batch, int* __restrict__ starts,
                              int Nn, int Gn)
{
    int g = blockIdx.x * blockDim.x + threadIdx.x;
    if (g > Gn) return;
    int lo = 0, hi = Nn;
    while (lo < hi) { int mid = (lo + hi) >> 1; if (batch[mid] < g) lo = mid + 1; else hi = mid; }
    starts[g] = lo;
}

// ================= head =================
__global__ void head_gemm1(const float* __restrict__ z, const float* __restrict__ W,
                           const float* __restrict__ bias, float* __restrict__ zr,
                           float* __restrict__ msums)
{
    __shared__ __align__(16) float zl[768];
    int g = blockIdx.x, j = threadIdx.x;
    for (int i = j; i < 768; i += 128) zl[i] = z[(size_t)g * 768 + i];
    __syncthreads();
    float acc = bias[j];
    for (int k = 0; k < 768; k += 4) {
        float4 a4 = *(const float4*)&zl[k];
        acc += a4.x * W[k * 128 + j] + a4.y * W[(k + 1) * 128 + j]
             + a4.z * W[(k + 2) * 128 + j] + a4.w * W[(k + 3) * 128 + j];
    }
    zr[(size_t)g * 128 + j] = acc;
    int cp = (g & (NSTAT - 1)) << 8;   // slot-striped msums
    atomicAdd(&msums[cp + j], acc);
    atomicAdd(&msums[cp + 128 + j], acc * acc);
}

__global__ void head_final(const float* __restrict__ zr, const float* __restrict__ msums,
                           const float* __restrict__ hg, const float* __restrict__ hb,
                           const float* __restrict__ W2, const float* __restrict__ b2,
                           float* __restrict__ out, float invG)
{
    int g = blockIdx.x, j = threadIdx.x;
    float Sm = 0.f, Qm = 0.f;
#pragma unroll
    for (int cpy = 0; cpy < NSTAT; ++cpy) {
        Sm += msums[(cpy << 8) + j];
        Qm += msums[(cpy << 8) + 128 + j];
    }
    float mean = Sm * invG;
    float var = Qm * invG - mean * mean;
    float rstd = rsqrtf(var + 1e-5f);
    float v = zr[(size_t)g * 128 + j];
    v = (v - mean) * rstd * hg[j] + hb[j];
    v = fmaxf(v, 0.f);
    float p = v * W2[j];
#pragma unroll
    for (int off = 32; off > 0; off >>= 1) p += __shfl_down(p, off, 64);
    __shared__ float partial[2];
    if ((j & 63) == 0) partial[j >> 6] = p;
    __syncthreads();
    if (j == 0) out[g] = partial[0] + partial[1] + b2[0];
}

extern "C" void kernel_launch(void* const* d_in, const int* in_sizes, int n_in,
                              void* d_out, int out_size, void* d_ws, size_t ws_size,
                              hipStream_t stream)
{
    const float* x         = (const float*)d_in[0];
    const float* edge_attr = (const float*)d_in[1];
    const int*   src       = (const int*)d_in[2];
    const int*   dst       = (const int*)d_in[3];
    const int*   batch     = (const int*)d_in[4];
    const float* Wp        = (const float*)d_in[5];
    const float* bp        = (const float*)d_in[6];
    const float* conv_We   = (const float*)d_in[7];
    const float* conv_be   = (const float*)d_in[8];
    const float* conv_W1   = (const float*)d_in[9];
    const float* conv_b1   = (const float*)d_in[10];
    const float* conv_g1   = (const float*)d_in[11];
    const float* conv_bt1  = (const float*)d_in[12];
    const float* conv_W2   = (const float*)d_in[13];
    const float* conv_b2   = (const float*)d_in[14];
    const float* bn_g      = (const float*)d_in[15];
    const float* bn_b      = (const float*)d_in[16];
    const float* head_W1   = (const float*)d_in[17];
    const float* head_b1   = (const float*)d_in[18];
    const float* head_g    = (const float*)d_in[19];
    const float* head_bt   = (const float*)d_in[20];
    const float* head_W2   = (const float*)d_in[21];
    const float* head_b2   = (const float*)d_in[22];

    const int N = in_sizes[4];            // 50000
    const int E = in_sizes[2];            // 800000
    const int G = out_size;               // 256
    const int L = 3;

    // ---- workspace layout ----
    const int SLOT = NSTAT * 256;                    // 4096 floats per stat set
    float* t        = (float*)d_ws;                  // N*128 fp32
    unsigned short* h16 = (unsigned short*)(t + (size_t)N * HID);  // N*128 bf16
    float* z        = (float*)(h16 + (size_t)N * HID);             // G*768
    float* zr       = z + (size_t)G * 768;           // G*128
    float* statsAll = zr + (size_t)G * HID;          // 7 sets x SLOT
    int*   deg      = (int*)(statsAll + 7 * SLOT);   // N
    int*   starts   = deg + N;                       // G+1
    int*   row_start= starts + (G + 1);              // N+1
    int*   cursor   = row_start + (N + 1);           // N
    int*   bsum     = cursor + N;                    // 256
    int*   src_perm = bsum + 256;                    // E
    int*   perm     = src_perm + E;                  // E
    unsigned short* wt = (unsigned short*)(perm + E);  // 212992 ushorts gemm weights
    size_t base_end = (size_t)((char*)(wt + 212992) - (char*)d_ws);
    size_t ea_off = (base_end + 63) & ~(size_t)63;   // 64B-align ea rows
    bool gath = (ea_off + (size_t)E * 8 * sizeof(unsigned)) <= ws_size;  // f16 rows: 32B/edge
    unsigned* eaH = (unsigned*)((char*)d_ws + ea_off);
    float* msums = statsAll + 6 * SLOT;

    (void)n_in;

    const float invN = 1.0f / (float)N;
    const float invG = 1.0f / (float)G;
    const int nb = (N + 255) / 256;
    const int gemmBlocks = (N + 127) / 128;

    // ---- CSR build + weight prep ----
    (void)hipMemsetAsync(statsAll, 0, 7 * SLOT * sizeof(float) + (size_t)N * sizeof(int), stream);
    hist_kernel<<<(E + 255) / 256, 256, 0, stream>>>(dst, deg, E);
    block_sum_kernel<<<nb, 256, 0, stream>>>(deg, bsum, N);
    bsum_scan_kernel<<<1, 256, 0, stream>>>(bsum, nb, &row_start[N]);
    block_scan_kernel<<<nb, 256, 0, stream>>>(deg, bsum, row_start, cursor, N);
    scatter_kernel<<<(E + 255) / 256, 256, 0, stream>>>(src, dst, cursor, perm, src_perm, E);
    if (gath)
        gather_ea_f16<<<(E * 2 + 255) / 256, 256, 0, stream>>>(edge_attr, perm, eaH, E);
    starts_kernel<<<1, 512, 0, stream>>>(batch, starts, N, G);
    prep_weights<<<(8192 + 6 * 16384 + 255) / 256, 256, 0, stream>>>(Wp, conv_W1, conv_W2, wt);

    const unsigned short* Wp_hi = wt;
    const unsigned short* Wp_lo = wt + 8192;

    // h16 = bf16(x @ Wp + bp)
    gemm_mfma<64, false, false, true, false><<<gemmBlocks, 256, 0, stream>>>(
        x, Wp_hi, Wp_lo, bp, nullptr, nullptr, nullptr, h16, nullptr, N, invN);

    for (int l = 0; l < L; ++l) {
        float* sI = statsAll + (size_t)(2 * l) * SLOT;
        float* sO = sI + SLOT;
        const unsigned short* W1hi = wt + 16384 + (size_t)(2 * l) * 32768;
        const unsigned short* W1lo = W1hi + 16384;
        const unsigned short* W2hi = wt + 16384 + (size_t)(2 * l + 1) * 32768;
        const unsigned short* W2lo = W2hi + 16384;
        if (gath) {
            // aggregate stores packed-split u32 in t; W1 gemm stages with bit-ops only
            aggregate_f16<true><<<(N + 3) / 4, 256, 0, stream>>>(
                h16, eaH, src_perm, row_start,
                conv_We + (size_t)l * EDIM * HID, conv_be + l * HID, t, N);
            gemm_mfma<128, false, true, false, true><<<gemmBlocks, 256, 0, stream>>>(
                t, W1hi, W1lo, conv_b1 + l * HID,
                nullptr, nullptr, nullptr, t, sI, N, invN);
        } else {
            aggregate_fp32<<<(N + 3) / 4, 256, 0, stream>>>(
                h16, edge_attr, perm, src_perm, row_start,
                conv_We + (size_t)l * EDIM * HID, conv_be + l * HID, t, N);
            gemm_mfma<128, false, true, false, false><<<gemmBlocks, 256, 0, stream>>>(
                t, W1hi, W1lo, conv_b1 + l * HID,
                nullptr, nullptr, nullptr, t, sI, N, invN);
        }
        gemm_mfma<128, true, true, false, false><<<gemmBlocks, 256, 0, stream>>>(
            t, W2hi, W2lo, conv_b2 + l * HID,
            sI, conv_g1 + l * HID, conv_bt1 + l * HID, t, sO, N, invN);
        bn_apply_pool<<<G, 512, 0, stream>>>(
            t, h16, sO, bn_g + l * HID, bn_b + l * HID, starts, z, l, invN);
    }

    head_gemm1<<<G, 128, 0, stream>>>(z, head_W1, head_b1, zr, msums);
    head_final<<<G, 128, 0, stream>>>(zr, msums, head_g, head_bt, head_W2, head_b2,
                                      (float*)d_out, invG);
}

// Round 13
// 622.153 us; speedup vs baseline: 1.2056x; 1.0155x over previous
//
#include <hip/hip_runtime.h>
#include <hip/hip_bf16.h>
#include <hip/hip_fp16.h>

#define HID 128
#define EDIM 16
#define NSTAT 16   // stat-slot copies to break atomic serialization

typedef float v4f __attribute__((ext_vector_type(4)));
typedef float v2f __attribute__((ext_vector_type(2)));
typedef short s8v __attribute__((ext_vector_type(8)));   // 8 bf16 (4 VGPRs) MFMA frag
typedef float f4v __attribute__((ext_vector_type(4)));   // MFMA acc
typedef unsigned int u8x __attribute__((ext_vector_type(8)));  // 8 dwords = 16 f16
typedef _Float16 h2v __attribute__((ext_vector_type(2)));      // f16 pair for fdot2

#define MFMA_BF16(a, b, c) __builtin_amdgcn_mfma_f32_16x16x32_bf16((a), (b), (c), 0, 0, 0)

__device__ __forceinline__ unsigned short bf16_rne(float v)
{
    unsigned u = __builtin_bit_cast(unsigned, v);
    return (unsigned short)((u + 0x7fffu + ((u >> 16) & 1u)) >> 16);
}

__device__ __forceinline__ unsigned pack2(float lo, float hi)
{
    return (unsigned)bf16_rne(lo) | ((unsigned)bf16_rne(hi) << 16);
}

__device__ __forceinline__ float bflo(unsigned u) { return __builtin_bit_cast(float, u << 16); }
__device__ __forceinline__ float bfhi(unsigned u) { return __builtin_bit_cast(float, u & 0xffff0000u); }

__device__ __forceinline__ v2f unpack2(unsigned u)
{
    v2f r; r.x = bflo(u); r.y = bfhi(u); return r;
}

__device__ __forceinline__ void split_bf16(float v, unsigned short& h, unsigned short& l)
{
    unsigned u = __builtin_bit_cast(unsigned, v);
    unsigned hu = (u + 0x7fffu + ((u >> 16) & 1u)) >> 16;
    h = (unsigned short)hu;
    float hf = __builtin_bit_cast(float, hu << 16);
    l = bf16_rne(v - hf);
}

__device__ __forceinline__ v2f vmax0(v2f a)
{
    v2f r; r.x = fmaxf(a.x, 0.f); r.y = fmaxf(a.y, 0.f); return r;
}

// pack two floats to f16x2 (RNE)
__device__ __forceinline__ unsigned pkh2(float lo, float hi)
{
    return (unsigned)__half_as_ushort(__float2half(lo)) |
           ((unsigned)__half_as_ushort(__float2half(hi)) << 16);
}

// d += ea.lo*w.lo + ea.hi*w.hi (fp32 accumulate). Builtin (NOT bare asm): bare
// VOP3P asm assembles wrong default modifiers (round-6 absmax 0.54).
__device__ __forceinline__ void dot2(float& d, unsigned ea, unsigned w)
{
    d = __builtin_amdgcn_fdot2(__builtin_bit_cast(h2v, ea),
                               __builtin_bit_cast(h2v, w), d, false);
}

// ================= CSR build =================
__global__ void hist_kernel(const int* __restrict__ dst, int* __restrict__ deg, int E)
{
    int e = blockIdx.x * 256 + threadIdx.x;
    if (e < E) atomicAdd(&deg[dst[e]], 1);
}

__global__ void block_sum_kernel(const int* __restrict__ deg, int* __restrict__ bsum, int Nn)
{
    int i = blockIdx.x * 256 + threadIdx.x;
    int v = (i < Nn) ? deg[i] : 0;
#pragma unroll
    for (int off = 32; off > 0; off >>= 1) v += __shfl_down(v, off, 64);
    __shared__ int ws[4];
    if ((threadIdx.x & 63) == 0) ws[threadIdx.x >> 6] = v;
    __syncthreads();
    if (threadIdx.x == 0) bsum[blockIdx.x] = ws[0] + ws[1] + ws[2] + ws[3];
}

__global__ void bsum_scan_kernel(int* bsum, int nb, int* total_out)
{
    __shared__ int sh[256];
    int tid = threadIdx.x;
    int v = (tid < nb) ? bsum[tid] : 0;
    sh[tid] = v;
    __syncthreads();
    for (int off = 1; off < 256; off <<= 1) {
        int tv = (tid >= off) ? sh[tid - off] : 0;
        __syncthreads();
        sh[tid] += tv;
        __syncthreads();
    }
    if (tid < nb) bsum[tid] = sh[tid] - v;
    if (tid == 255) *total_out = sh[255];
}

// block-level CSR scan + (last block) graph segment starts — one fused dispatch
__global__ void block_scan_kernel(const int* __restrict__ deg, const int* __restrict__ bsum,
                                  int* __restrict__ row_start, int* __restrict__ cursor,
                                  const int* __restrict__ batch, int* __restrict__ starts,
                                  int Nn, int Gn)
{
    __shared__ int sh[256];
    int tid = threadIdx.x;
    int i = blockIdx.x * 256 + tid;
    int v = (i < Nn) ? deg[i] : 0;
    sh[tid] = v;
    __syncthreads();
    for (int off = 1; off < 256; off <<= 1) {
        int tv = (tid >= off) ? sh[tid - off] : 0;
        __syncthreads();
        sh[tid] += tv;
        __syncthreads();
    }
    if (i < Nn) {
        int excl = sh[tid] - v + bsum[blockIdx.x];
        row_start[i] = excl;
        cursor[i] = excl;
    }
    if (blockIdx.x == gridDim.x - 1) {
        for (int g = tid; g <= Gn; g += 256) {
            int lo = 0, hi = Nn;
            while (lo < hi) { int mid = (lo + hi) >> 1; if (batch[mid] < g) lo = mid + 1; else hi = mid; }
            starts[g] = lo;
        }
    }
}

// fused scatter + ea f16 conversion: COALESCED ea read (thread e owns row e),
// scattered 32B f16 write to eaH[pos] — replaces the separate gather dispatch.
__global__ void scatter_ea_kernel(const int* __restrict__ src, const int* __restrict__ dst,
                                  const float* __restrict__ ea,
                                  int* cursor, int* __restrict__ perm,
                                  int* __restrict__ src_perm, unsigned* __restrict__ eaH,
                                  int E, int doEa)
{
    int e = blockIdx.x * 256 + threadIdx.x;
    if (e >= E) return;
    int pos = atomicAdd(&cursor[dst[e]], 1);
    perm[pos] = e;
    src_perm[pos] = src[e];
    if (doEa) {
        const float* ap = &ea[(size_t)e * EDIM];
        float4 f0 = *(const float4*)ap;
        float4 f1 = *(const float4*)(ap + 4);
        float4 f2 = *(const float4*)(ap + 8);
        float4 f3 = *(const float4*)(ap + 12);
        uint4 o0, o1;
        o0.x = pkh2(f0.x, f0.y); o0.y = pkh2(f0.z, f0.w);
        o0.z = pkh2(f1.x, f1.y); o0.w = pkh2(f1.z, f1.w);
        o1.x = pkh2(f2.x, f2.y); o1.y = pkh2(f2.z, f2.w);
        o1.z = pkh2(f3.x, f3.y); o1.w = pkh2(f3.z, f3.w);
        *(uint4*)&eaH[(size_t)pos * 8] = o0;
        *(uint4*)&eaH[(size_t)pos * 8 + 4] = o1;
    }
}

// ================= weight prep: fp32 [K,128] -> transposed split-bf16 [128,K] hi/lo =================
__global__ void prep_weights(const float* __restrict__ Wp, const float* __restrict__ W1,
                             const float* __restrict__ W2, unsigned short* __restrict__ out)
{
    int idx = blockIdx.x * 256 + threadIdx.x;
    if (idx < 8192) {
        int n = idx >> 6, k = idx & 63;
        unsigned short h, l;
        split_bf16(Wp[k * 128 + n], h, l);
        out[idx] = h;
        out[8192 + idx] = l;
    } else {
        int j = idx - 8192;
        if (j >= 6 * 16384) return;
        int m2 = j >> 14;
        int r = j & 16383;
        int n = r >> 7, k = r & 127;
        int l = m2 >> 1;
        const float* Wsrc = (m2 & 1) ? (W2 + l * 16384) : (W1 + l * 16384);
        unsigned short h, lo;
        split_bf16(Wsrc[k * 128 + n], h, lo);
        int base = 16384 + m2 * 32768;
        out[base + r] = h;
        out[base + 16384 + r] = lo;
    }
}

// ====== Node-centric aggregation (r7 structure, ~62 µs): f16 ea + fdot2 ======
// 1 wave/node, 2 ch/lane. ea rows wave-uniform -> SGPR (8 dwords/row);
// 16 dot2/edge. 8-edge groups: one lgkmcnt drain per 8 edges.
// h gathers rotated one group ahead (VMEM, counted).
// PACK: store each output channel as u32 = bf16_hi | (bf16_lo<<16) IN t (same
// 4B/elem) so the W1 GEMM stages with bit-ops only — bit-identical to
// fp32-store-then-split (split-at-producer == split-at-consumer).
__device__ __forceinline__ void edge_f16(v2f& acc, v2f bj, unsigned hu, const u8x& e,
                                         const unsigned* __restrict__ wpk0,
                                         const unsigned* __restrict__ wpk1)
{
    float m0 = bj.x + bflo(hu);
    float m1 = bj.y + bfhi(hu);
#pragma unroll
    for (int kp = 0; kp < 8; ++kp) {
        dot2(m0, e[kp], wpk0[kp]);
        dot2(m1, e[kp], wpk1[kp]);
    }
    acc.x += fmaxf(m0, 0.f);
    acc.y += fmaxf(m1, 0.f);
}

template<bool PACK>
__global__ __launch_bounds__(256, 8) void aggregate_f16(
    const unsigned short* __restrict__ h16, const unsigned* __restrict__ eaH,
    const int* __restrict__ src_perm, const int* __restrict__ row_start,
    const float* __restrict__ We, const float* __restrict__ be,
    float* __restrict__ t, int Nn)
{
    int tid = threadIdx.x;
    int lane = tid & 63;
    int c = lane * 2;
    // f16 weight k-pairs per output channel (16 VGPRs)
    unsigned wpk0[8], wpk1[8];
#pragma unroll
    for (int kp = 0; kp < 8; ++kp) {
        wpk0[kp] = pkh2(We[(2 * kp) * HID + c],     We[(2 * kp + 1) * HID + c]);
        wpk1[kp] = pkh2(We[(2 * kp) * HID + c + 1], We[(2 * kp + 1) * HID + c + 1]);
    }
    v2f bj = *(const v2f*)&be[c];
    int node = blockIdx.x * 4 + (tid >> 6);
    if (node >= Nn) return;
    const unsigned* __restrict__ hw = (const unsigned*)h16 + lane;  // bf16 ch-pair per lane
    v2f acc = unpack2(hw[(unsigned)node << 6]);
    int p0 = __builtin_amdgcn_readfirstlane(row_start[node]);
    int p1 = __builtin_amdgcn_readfirstlane(row_start[node + 1]);
    int p = p0;

    int s0 = 0, s1 = 0, s2 = 0, s3 = 0, s4 = 0, s5 = 0, s6 = 0, s7 = 0;
    unsigned hu0 = 0, hu1 = 0, hu2 = 0, hu3 = 0, hu4 = 0, hu5 = 0, hu6 = 0, hu7 = 0;
    if (p + 8 <= p1) {
        s0 = src_perm[p];     s1 = src_perm[p + 1]; s2 = src_perm[p + 2]; s3 = src_perm[p + 3];
        s4 = src_perm[p + 4]; s5 = src_perm[p + 5]; s6 = src_perm[p + 6]; s7 = src_perm[p + 7];
        hu0 = hw[(unsigned)s0 << 6]; hu1 = hw[(unsigned)s1 << 6];
        hu2 = hw[(unsigned)s2 << 6]; hu3 = hw[(unsigned)s3 << 6];
        hu4 = hw[(unsigned)s4 << 6]; hu5 = hw[(unsigned)s5 << 6];
        hu6 = hw[(unsigned)s6 << 6]; hu7 = hw[(unsigned)s7 << 6];
    }
    while (p + 8 <= p1) {
        int np = p + 8;
        // current group's ea rows (SMEM, 8 x dwordx8)
        u8x e0 = *(const u8x*)(eaH + (size_t)(unsigned)(p    ) * 8);
        u8x e1 = *(const u8x*)(eaH + (size_t)(unsigned)(p + 1) * 8);
        u8x e2 = *(const u8x*)(eaH + (size_t)(unsigned)(p + 2) * 8);
        u8x e3 = *(const u8x*)(eaH + (size_t)(unsigned)(p + 3) * 8);
        u8x e4 = *(const u8x*)(eaH + (size_t)(unsigned)(p + 4) * 8);
        u8x e5 = *(const u8x*)(eaH + (size_t)(unsigned)(p + 5) * 8);
        u8x e6 = *(const u8x*)(eaH + (size_t)(unsigned)(p + 6) * 8);
        u8x e7 = *(const u8x*)(eaH + (size_t)(unsigned)(p + 7) * 8);
        // next group's src ids + h rows (prefetch)
        int t0 = 0, t1 = 0, t2 = 0, t3 = 0, t4 = 0, t5 = 0, t6 = 0, t7 = 0;
        unsigned hn0 = 0, hn1 = 0, hn2 = 0, hn3 = 0, hn4 = 0, hn5 = 0, hn6 = 0, hn7 = 0;
        if (np + 8 <= p1) {
            t0 = src_perm[np];     t1 = src_perm[np + 1]; t2 = src_perm[np + 2]; t3 = src_perm[np + 3];
            t4 = src_perm[np + 4]; t5 = src_perm[np + 5]; t6 = src_perm[np + 6]; t7 = src_perm[np + 7];
            hn0 = hw[(unsigned)t0 << 6]; hn1 = hw[(unsigned)t1 << 6];
            hn2 = hw[(unsigned)t2 << 6]; hn3 = hw[(unsigned)t3 << 6];
            hn4 = hw[(unsigned)t4 << 6]; hn5 = hw[(unsigned)t5 << 6];
            hn6 = hw[(unsigned)t6 << 6]; hn7 = hw[(unsigned)t7 << 6];
        }
        edge_f16(acc, bj, hu0, e0, wpk0, wpk1);
        edge_f16(acc, bj, hu1, e1, wpk0, wpk1);
        edge_f16(acc, bj, hu2, e2, wpk0, wpk1);
        edge_f16(acc, bj, hu3, e3, wpk0, wpk1);
        edge_f16(acc, bj, hu4, e4, wpk0, wpk1);
        edge_f16(acc, bj, hu5, e5, wpk0, wpk1);
        edge_f16(acc, bj, hu6, e6, wpk0, wpk1);
        edge_f16(acc, bj, hu7, e7, wpk0, wpk1);
        p = np;
        s0 = t0; s1 = t1; s2 = t2; s3 = t3; s4 = t4; s5 = t5; s6 = t6; s7 = t7;
        hu0 = hn0; hu1 = hn1; hu2 = hn2; hu3 = hn3;
        hu4 = hn4; hu5 = hn5; hu6 = hn6; hu7 = hn7;
    }
    for (; p < p1; ++p) {
        int s = src_perm[p];
        unsigned hu = hw[(unsigned)s << 6];
        u8x e = *(const u8x*)(eaH + (size_t)(unsigned)p * 8);
        edge_f16(acc, bj, hu, e, wpk0, wpk1);
    }
    if (PACK) {
        unsigned short h0, l0, h1, l1;
        split_bf16(acc.x, h0, l0);
        split_bf16(acc.y, h1, l1);
        uint2 pk;
        pk.x = (unsigned)h0 | ((unsigned)l0 << 16);
        pk.y = (unsigned)h1 | ((unsigned)l1 << 16);
        *(uint2*)((unsigned*)t + ((unsigned)node << 7) + c) = pk;
    } else {
        *(v2f*)(t + ((unsigned)node << 7) + c) = acc;
    }
}

// ====== fallback (no workspace for eaH): round-0 fp32 path via perm indirection ======
__device__ __forceinline__ void matvp(const v4f& a0, const v4f& a1,
                                      const v4f& a2, const v4f& a3,
                                      const v2f* __restrict__ w, v2f& m)
{
    m += w[0] * a0.x;  m += w[1] * a0.y;  m += w[2] * a0.z;  m += w[3] * a0.w;
    m += w[4] * a1.x;  m += w[5] * a1.y;  m += w[6] * a1.z;  m += w[7] * a1.w;
    m += w[8] * a2.x;  m += w[9] * a2.y;  m += w[10] * a2.z; m += w[11] * a2.w;
    m += w[12] * a3.x; m += w[13] * a3.y; m += w[14] * a3.z; m += w[15] * a3.w;
}

__global__ __launch_bounds__(256, 8) void aggregate_fp32(
    const unsigned short* __restrict__ h16, const float* __restrict__ eaG,
    const int* __restrict__ perm, const int* __restrict__ src_perm,
    const int* __restrict__ row_start,
    const float* __restrict__ We, const float* __restrict__ be,
    float* __restrict__ t, int Nn)
{
    int tid = threadIdx.x;
    int lane = tid & 63;
    int c = lane * 2;
    v2f w[16];
#pragma unroll
    for (int k = 0; k < 16; ++k) w[k] = *(const v2f*)&We[k * HID + c];
    v2f bj = *(const v2f*)&be[c];
    int node = blockIdx.x * 4 + (tid >> 6);
    if (node >= Nn) return;
    const unsigned* __restrict__ hw = (const unsigned*)h16 + lane;
    v2f acc = unpack2(hw[(unsigned)node << 6]);
    int p0 = __builtin_amdgcn_readfirstlane(row_start[node]);
    int p1 = __builtin_amdgcn_readfirstlane(row_start[node + 1]);
    int p = p0;
    int s0 = 0, s1 = 0, s2 = 0, s3 = 0;
    if (p + 4 <= p1) { s0 = src_perm[p]; s1 = src_perm[p + 1]; s2 = src_perm[p + 2]; s3 = src_perm[p + 3]; }
    while (p + 4 <= p1) {
        int np = p + 4;
        int t0 = 0, t1 = 0, t2 = 0, t3 = 0;
        if (np + 4 <= p1) { t0 = src_perm[np]; t1 = src_perm[np + 1]; t2 = src_perm[np + 2]; t3 = src_perm[np + 3]; }
        unsigned hu0 = hw[(unsigned)s0 << 6];
        unsigned hu1 = hw[(unsigned)s1 << 6];
        unsigned hu2 = hw[(unsigned)s2 << 6];
        unsigned hu3 = hw[(unsigned)s3 << 6];
        int q0 = perm[p], q1 = perm[p + 1], q2 = perm[p + 2], q3 = perm[p + 3];
        const v4f* e0 = (const v4f*)(eaG + (size_t)(unsigned)q0 * EDIM);
        const v4f* e1 = (const v4f*)(eaG + (size_t)(unsigned)q1 * EDIM);
        const v4f* e2 = (const v4f*)(eaG + (size_t)(unsigned)q2 * EDIM);
        const v4f* e3 = (const v4f*)(eaG + (size_t)(unsigned)q3 * EDIM);
        v4f a00 = e0[0], a01 = e0[1], a02 = e0[2], a03 = e0[3];
        v4f a10 = e1[0], a11 = e1[1], a12 = e1[2], a13 = e1[3];
        v4f a20 = e2[0], a21 = e2[1], a22 = e2[2], a23 = e2[3];
        v4f a30 = e3[0], a31 = e3[1], a32 = e3[2], a33 = e3[3];
        v2f m0 = bj + unpack2(hu0), m1 = bj + unpack2(hu1);
        v2f m2 = bj + unpack2(hu2), m3 = bj + unpack2(hu3);
        matvp(a00, a01, a02, a03, w, m0);
        matvp(a10, a11, a12, a13, w, m1);
        matvp(a20, a21, a22, a23, w, m2);
        matvp(a30, a31, a32, a33, w, m3);
        acc += (vmax0(m0) + vmax0(m1)) + (vmax0(m2) + vmax0(m3));
        p = np;
        s0 = t0; s1 = t1; s2 = t2; s3 = t3;
    }
    for (; p < p1; ++p) {
        int s = src_perm[p];
        int q = perm[p];
        const v4f* e0 = (const v4f*)(eaG + (size_t)(unsigned)q * EDIM);
        v4f a0 = e0[0], a1 = e0[1], a2 = e0[2], a3 = e0[3];
        v2f m0 = bj + unpack2(hw[(unsigned)s << 6]);
        matvp(a0, a1, a2, a3, w, m0);
        acc += vmax0(m0);
    }
    *(v2f*)(t + ((unsigned)node << 7) + c) = acc;
}

// ================= split-bf16 MFMA GEMM =================
// Stats are NSTAT-way slot-striped (r11, −44 µs): producer block b adds into
// slot (b & 15); consumers sum the 16 slots.
// A_PACK: A rows are packed-split u32 (hi | lo<<16) — staging is bit-ops only.
#define LPAD 40

template<int K, bool PRE_BN, bool POST_STATS, bool OUT_BF16, bool A_PACK>
__global__ __launch_bounds__(256) void gemm_mfma(
    const float* __restrict__ A, const unsigned short* __restrict__ Wh,
    const unsigned short* __restrict__ Wl, const float* __restrict__ bias,
    const float* __restrict__ preStats, const float* __restrict__ preG, const float* __restrict__ preB,
    void* __restrict__ Cout, float* __restrict__ postStats, int Nrows, float invN)
{
    __shared__ __align__(16) unsigned short Ah[128 * LPAD], Al[128 * LPAD];
    __shared__ __align__(16) unsigned short Bh[128 * LPAD], Bl[128 * LPAD];
    __shared__ float sc[PRE_BN ? K : 1], sb[PRE_BN ? K : 1];
    int tid = threadIdx.x;
    int rbase = blockIdx.x * 128;
    if (PRE_BN) {
        if (tid < K) {
            float Sm = 0.f, Qm = 0.f;
#pragma unroll
            for (int cpy = 0; cpy < NSTAT; ++cpy) {
                Sm += preStats[(cpy << 8) + tid];
                Qm += preStats[(cpy << 8) + 128 + tid];
            }
            float mean = Sm * invN;
            float var = Qm * invN - mean * mean;
            float rstd = rsqrtf(var + 1e-5f);
            float g = preG[tid];
            sc[tid] = rstd * g;
            sb[tid] = preB[tid] - mean * rstd * g;
        }
        __syncthreads();
    }
    int w = tid >> 6, nl = tid & 15, q = (tid >> 4) & 3;
    f4v acc[2][8];
#pragma unroll
    for (int mt = 0; mt < 2; ++mt)
#pragma unroll
        for (int nt = 0; nt < 8; ++nt)
#pragma unroll
            for (int r = 0; r < 4; ++r) acc[mt][nt][r] = 0.f;

    for (int ks = 0; ks < K / 32; ++ks) {
        int k0 = ks * 32;
        if (ks) __syncthreads();
#pragma unroll
        for (int i = 0; i < 4; ++i) {
            int cidx = tid + i * 256;
            int m = cidx >> 3, k4 = (cidx & 7) * 4;
            int gr = rbase + m;
            uint2 hp, lp;
            if (A_PACK) {
                uint4 v = make_uint4(0u, 0u, 0u, 0u);
                if (gr < Nrows) v = *(const uint4*)((const unsigned*)A + (size_t)gr * K + k0 + k4);
                hp.x = (v.x & 0xffffu) | (v.y << 16);
                hp.y = (v.z & 0xffffu) | (v.w << 16);
                lp.x = (v.x >> 16) | (v.y & 0xffff0000u);
                lp.y = (v.z >> 16) | (v.w & 0xffff0000u);
            } else {
                float4 v = make_float4(0.f, 0.f, 0.f, 0.f);
                if (gr < Nrows) v = *(const float4*)&A[(size_t)gr * K + k0 + k4];
                if (PRE_BN) {
                    v.x = fmaxf(v.x * sc[k0 + k4]     + sb[k0 + k4],     0.f);
                    v.y = fmaxf(v.y * sc[k0 + k4 + 1] + sb[k0 + k4 + 1], 0.f);
                    v.z = fmaxf(v.z * sc[k0 + k4 + 2] + sb[k0 + k4 + 2], 0.f);
                    v.w = fmaxf(v.w * sc[k0 + k4 + 3] + sb[k0 + k4 + 3], 0.f);
                }
                unsigned short h0, l0, h1, l1, h2, l2, h3, l3;
                split_bf16(v.x, h0, l0); split_bf16(v.y, h1, l1);
                split_bf16(v.z, h2, l2); split_bf16(v.w, h3, l3);
                hp.x = (unsigned)h0 | ((unsigned)h1 << 16); hp.y = (unsigned)h2 | ((unsigned)h3 << 16);
                lp.x = (unsigned)l0 | ((unsigned)l1 << 16); lp.y = (unsigned)l2 | ((unsigned)l3 << 16);
            }
            *(uint2*)&Ah[m * LPAD + k4] = hp;
            *(uint2*)&Al[m * LPAD + k4] = lp;
        }
#pragma unroll
        for (int i = 0; i < 2; ++i) {
            int g = tid + i * 256;
            int n = g >> 2, kq = (g & 3) * 8;
            uint4 hv = *(const uint4*)&Wh[(size_t)n * K + k0 + kq];
            uint4 lv = *(const uint4*)&Wl[(size_t)n * K + k0 + kq];
            *(uint4*)&Bh[n * LPAD + kq] = hv;
            *(uint4*)&Bl[n * LPAD + kq] = lv;
        }
        __syncthreads();
        s8v ah0 = *(const s8v*)&Ah[(w * 32 + nl) * LPAD + q * 8];
        s8v ah1 = *(const s8v*)&Ah[(w * 32 + 16 + nl) * LPAD + q * 8];
        s8v al0 = *(const s8v*)&Al[(w * 32 + nl) * LPAD + q * 8];
        s8v al1 = *(const s8v*)&Al[(w * 32 + 16 + nl) * LPAD + q * 8];
#pragma unroll
        for (int nt = 0; nt < 8; ++nt) {
            s8v bh = *(const s8v*)&Bh[(nt * 16 + nl) * LPAD + q * 8];
            s8v bl = *(const s8v*)&Bl[(nt * 16 + nl) * LPAD + q * 8];
            acc[0][nt] = MFMA_BF16(ah0, bh, acc[0][nt]);
            acc[0][nt] = MFMA_BF16(ah0, bl, acc[0][nt]);
            acc[0][nt] = MFMA_BF16(al0, bh, acc[0][nt]);
            acc[1][nt] = MFMA_BF16(ah1, bh, acc[1][nt]);
            acc[1][nt] = MFMA_BF16(ah1, bl, acc[1][nt]);
            acc[1][nt] = MFMA_BF16(al1, bh, acc[1][nt]);
        }
    }
    __syncthreads();

    float* Cf = (float*)Cout;
    unsigned short* Ch = (unsigned short*)Cout;
    float* redS = (float*)Ah;
    float* redQ = (float*)Al;
#pragma unroll
    for (int nt = 0; nt < 8; ++nt) {
        int col = nt * 16 + nl;
        float bcol = bias[col];
        float sv = 0.f, qv = 0.f;
#pragma unroll
        for (int mt = 0; mt < 2; ++mt) {
#pragma unroll
            for (int r = 0; r < 4; ++r) {
                int grow = rbase + w * 32 + mt * 16 + q * 4 + r;
                if (grow < Nrows) {
                    float o = acc[mt][nt][r] + bcol;
                    if (OUT_BF16) Ch[(size_t)grow * HID + col] = bf16_rne(o);
                    else          Cf[(size_t)grow * HID + col] = o;
                    if (POST_STATS) { sv += o; qv += o * o; }
                }
            }
        }
        if (POST_STATS) {
            sv += __shfl_down(sv, 32, 64); sv += __shfl_down(sv, 16, 64);
            qv += __shfl_down(qv, 32, 64); qv += __shfl_down(qv, 16, 64);
            if ((tid & 63) < 16) { redS[w * 128 + col] = sv; redQ[w * 128 + col] = qv; }
        }
    }
    if (POST_STATS) {
        __syncthreads();
        if (tid < 128) {
            float S = redS[tid] + redS[128 + tid] + redS[256 + tid] + redS[384 + tid];
            float Q = redQ[tid] + redQ[128 + tid] + redQ[256 + tid] + redQ[384 + tid];
            int cp = (blockIdx.x & (NSTAT - 1)) << 8;   // slot-striped: ~25 contenders/addr
            atomicAdd(&postStats[cp + tid], S);
            atomicAdd(&postStats[cp + 128 + tid], Q);
        }
    }
}

// ======== fused BN apply + ReLU + pool; h stored as packed bf16 (pool uses exact fp32) ========
__global__ void bn_apply_pool(const float* __restrict__ X, unsigned short* __restrict__ h16,
                              const float* __restrict__ stats, const float* __restrict__ g,
                              const float* __restrict__ b, const int* __restrict__ starts,
                              float* __restrict__ z, int l, float invN)
{
    int gph = blockIdx.x;
    int tid = threadIdx.x;
    int ch4 = (tid & 31) * 4, wk = tid >> 5;   // 16 walkers x 32 lanes(float4)
    float sc[4], sh[4];
#pragma unroll
    for (int u = 0; u < 4; ++u) {
        int j = ch4 + u;
        float Sm = 0.f, Qm = 0.f;
#pragma unroll
        for (int cpy = 0; cpy < NSTAT; ++cpy) {
            Sm += stats[(cpy << 8) + j];
            Qm += stats[(cpy << 8) + 128 + j];
        }
        float mean = Sm * invN;
        float var = Qm * invN - mean * mean;
        float rstd = rsqrtf(var + 1e-5f);
        float gg = g[j];
        sc[u] = rstd * gg;
        sh[u] = b[j] - mean * rstd * gg;
    }
    int s = starts[gph], e = starts[gph + 1];
    float4 sum = make_float4(0.f, 0.f, 0.f, 0.f);
    float4 mx = make_float4(0.f, 0.f, 0.f, 0.f);
    unsigned* hv32 = (unsigned*)h16;
    for (int n = s + wk; n < e; n += 16) {
        float4 v = *(const float4*)&X[(size_t)n * HID + ch4];
        v.x = fmaxf(v.x * sc[0] + sh[0], 0.f);
        v.y = fmaxf(v.y * sc[1] + sh[1], 0.f);
        v.z = fmaxf(v.z * sc[2] + sh[2], 0.f);
        v.w = fmaxf(v.w * sc[3] + sh[3], 0.f);
        uint2 pk;
        pk.x = pack2(v.x, v.y);
        pk.y = pack2(v.z, v.w);
        *(uint2*)&hv32[(size_t)n * 64 + (ch4 >> 1)] = pk;
        sum.x += v.x; sum.y += v.y; sum.z += v.z; sum.w += v.w;
        mx.x = fmaxf(mx.x, v.x); mx.y = fmaxf(mx.y, v.y);
        mx.z = fmaxf(mx.z, v.z); mx.w = fmaxf(mx.w, v.w);
    }
    __shared__ float ls[16 * 128], lm[16 * 128];
    *(float4*)&ls[wk * 128 + ch4] = sum;
    *(float4*)&lm[wk * 128 + ch4] = mx;
    __syncthreads();
    if (tid < 128) {
        float S = 0.f, M = 0.f;
#pragma unroll
        for (int k = 0; k < 16; ++k) {
            S += ls[k * 128 + tid];
            M = fmaxf(M, lm[k * 128 + tid]);
        }
        float cnt = (float)(e - s);
        z[(size_t)gph * 768 + l * 128 + tid] = S / fmaxf(cnt, 1.f);
        z[(size_t)gph * 768 + 384 + l * 128 + tid] = M;
    }
}

// ================= head =================
// 512 threads: 4-way K-split (192/thread vs 768) + LDS reduce — 4x the waves,
// 4x shorter serial FMA chain (old version ran at 0.5 waves/SIMD).
__global__ void head_gemm1(const float* __restrict__ z, const float* __restrict__ W,
                           const float* __restrict__ bias, float* __restrict__ zr,
                           float* __restrict__ msums)
{
    __shared__ __align__(16) float zl[768];
    __shared__ float part[512];
    int g = blockIdx.x, j = threadIdx.x;
    for (int i = j; i < 768; i += 512) zl[i] = z[(size_t)g * 768 + i];
    __syncthreads();
    int ch = j & 127, kq = j >> 7;       // 4 k-quarters x 128 channels
    int kbase = kq * 192;
    float acc = 0.f;
    for (int k = 0; k < 192; k += 4) {
        float4 a4 = *(const float4*)&zl[kbase + k];
        acc += a4.x * W[(kbase + k) * 128 + ch] + a4.y * W[(kbase + k + 1) * 128 + ch]
             + a4.z * W[(kbase + k + 2) * 128 + ch] + a4.w * W[(kbase + k + 3) * 128 + ch];
    }
    part[j] = acc;
    __syncthreads();
    if (j < 128) {
        float v = part[j] + part[128 + j] + part[256 + j] + part[384 + j] + bias[j];
        zr[(size_t)g * 128 + j] = v;
        int cp = (g & (NSTAT - 1)) << 8;   // slot-striped msums
        atomicAdd(&msums[cp + j], v);
        atomicAdd(&msums[cp + 128 + j], v * v);
    }
}

__global__ void head_final(const float* __restrict__ zr, const float* __restrict__ msums,
                           const float* __restrict__ hg, const float* __restrict__ hb,
                           const float* __restrict__ W2, const float* __restrict__ b2,
                           float* __restrict__ out, float invG)
{
    int g = blockIdx.x, j = threadIdx.x;
    float Sm = 0.f, Qm = 0.f;
#pragma unroll
    for (int cpy = 0; cpy < NSTAT; ++cpy) {
        Sm += msums[(cpy << 8) + j];
        Qm += msums[(cpy << 8) + 128 + j];
    }
    float mean = Sm * invG;
    float var = Qm * invG - mean * mean;
    float rstd = rsqrtf(var + 1e-5f);
    float v = zr[(size_t)g * 128 + j];
    v = (v - mean) * rstd * hg[j] + hb[j];
    v = fmaxf(v, 0.f);
    float p = v * W2[j];
#pragma unroll
    for (int off = 32; off > 0; off >>= 1) p += __shfl_down(p, off, 64);
    __shared__ float partial[2];
    if ((j & 63) == 0) partial[j >> 6] = p;
    __syncthreads();
    if (j == 0) out[g] = partial[0] + partial[1] + b2[0];
}

extern "C" void kernel_launch(void* const* d_in, const int* in_sizes, int n_in,
                              void* d_out, int out_size, void* d_ws, size_t ws_size,
                              hipStream_t stream)
{
    const float* x         = (const float*)d_in[0];
    const float* edge_attr = (const float*)d_in[1];
    const int*   src       = (const int*)d_in[2];
    const int*   dst       = (const int*)d_in[3];
    const int*   batch     = (const int*)d_in[4];
    const float* Wp        = (const float*)d_in[5];
    const float* bp        = (const float*)d_in[6];
    const float* conv_We   = (const float*)d_in[7];
    const float* conv_be   = (const float*)d_in[8];
    const float* conv_W1   = (const float*)d_in[9];
    const float* conv_b1   = (const float*)d_in[10];
    const float* conv_g1   = (const float*)d_in[11];
    const float* conv_bt1  = (const float*)d_in[12];
    const float* conv_W2   = (const float*)d_in[13];
    const float* conv_b2   = (const float*)d_in[14];
    const float* bn_g      = (const float*)d_in[15];
    const float* bn_b      = (const float*)d_in[16];
    const float* head_W1   = (const float*)d_in[17];
    const float* head_b1   = (const float*)d_in[18];
    const float* head_g    = (const float*)d_in[19];
    const float* head_bt   = (const float*)d_in[20];
    const float* head_W2   = (const float*)d_in[21];
    const float* head_b2   = (const float*)d_in[22];

    const int N = in_sizes[4];            // 50000
    const int E = in_sizes[2];            // 800000
    const int G = out_size;               // 256
    const int L = 3;

    // ---- workspace layout ----
    const int SLOT = NSTAT * 256;                    // 4096 floats per stat set
    float* t        = (float*)d_ws;                  // N*128 fp32
    unsigned short* h16 = (unsigned short*)(t + (size_t)N * HID);  // N*128 bf16
    float* z        = (float*)(h16 + (size_t)N * HID);             // G*768
    float* zr       = z + (size_t)G * 768;           // G*128
    float* statsAll = zr + (size_t)G * HID;          // 7 sets x SLOT
    int*   deg      = (int*)(statsAll + 7 * SLOT);   // N
    int*   starts   = deg + N;                       // G+1
    int*   row_start= starts + (G + 1);              // N+1
    int*   cursor   = row_start + (N + 1);           // N
    int*   bsum     = cursor + N;                    // 256
    int*   src_perm = bsum + 256;                    // E
    int*   perm     = src_perm + E;                  // E
    unsigned short* wt = (unsigned short*)(perm + E);  // 212992 ushorts gemm weights
    size_t base_end = (size_t)((char*)(wt + 212992) - (char*)d_ws);
    size_t ea_off = (base_end + 63) & ~(size_t)63;   // 64B-align ea rows
    bool gath = (ea_off + (size_t)E * 8 * sizeof(unsigned)) <= ws_size;  // f16 rows: 32B/edge
    unsigned* eaH = (unsigned*)((char*)d_ws + ea_off);
    float* msums = statsAll + 6 * SLOT;

    (void)n_in;

    const float invN = 1.0f / (float)N;
    const float invG = 1.0f / (float)G;
    const int nb = (N + 255) / 256;
    const int gemmBlocks = (N + 127) / 128;

    // ---- CSR build + weight prep ----
    (void)hipMemsetAsync(statsAll, 0, 7 * SLOT * sizeof(float) + (size_t)N * sizeof(int), stream);
    hist_kernel<<<(E + 255) / 256, 256, 0, stream>>>(dst, deg, E);
    block_sum_kernel<<<nb, 256, 0, stream>>>(deg, bsum, N);
    bsum_scan_kernel<<<1, 256, 0, stream>>>(bsum, nb, &row_start[N]);
    block_scan_kernel<<<nb, 256, 0, stream>>>(deg, bsum, row_start, cursor, batch, starts, N, G);
    scatter_ea_kernel<<<(E + 255) / 256, 256, 0, stream>>>(
        src, dst, edge_attr, cursor, perm, src_perm, eaH, E, gath ? 1 : 0);
    prep_weights<<<(8192 + 6 * 16384 + 255) / 256, 256, 0, stream>>>(Wp, conv_W1, conv_W2, wt);

    const unsigned short* Wp_hi = wt;
    const unsigned short* Wp_lo = wt + 8192;

    // h16 = bf16(x @ Wp + bp)
    gemm_mfma<64, false, false, true, false><<<gemmBlocks, 256, 0, stream>>>(
        x, Wp_hi, Wp_lo, bp, nullptr, nullptr, nullptr, h16, nullptr, N, invN);

    for (int l = 0; l < L; ++l) {
        float* sI = statsAll + (size_t)(2 * l) * SLOT;
        float* sO = sI + SLOT;
        const unsigned short* W1hi = wt + 16384 + (size_t)(2 * l) * 32768;
        const unsigned short* W1lo = W1hi + 16384;
        const unsigned short* W2hi = wt + 16384 + (size_t)(2 * l + 1) * 32768;
        const unsigned short* W2lo = W2hi + 16384;
        if (gath) {
            // aggregate stores packed-split u32 in t; W1 gemm stages with bit-ops only
            aggregate_f16<true><<<(N + 3) / 4, 256, 0, stream>>>(
                h16, eaH, src_perm, row_start,
                conv_We + (size_t)l * EDIM * HID, conv_be + l * HID, t, N);
            gemm_mfma<128, false, true, false, true><<<gemmBlocks, 256, 0, stream>>>(
                t, W1hi, W1lo, conv_b1 + l * HID,
                nullptr, nullptr, nullptr, t, sI, N, invN);
        } else {
            aggregate_fp32<<<(N + 3) / 4, 256, 0, stream>>>(
                h16, edge_attr, perm, src_perm, row_start,
                conv_We + (size_t)l * EDIM * HID, conv_be + l * HID, t, N);
            gemm_mfma<128, false, true, false, false><<<gemmBlocks, 256, 0, stream>>>(
                t, W1hi, W1lo, conv_b1 + l * HID,
                nullptr, nullptr, nullptr, t, sI, N, invN);
        }
        gemm_mfma<128, true, true, false, false><<<gemmBlocks, 256, 0, stream>>>(
            t, W2hi, W2lo, conv_b2 + l * HID,
            sI, conv_g1 + l * HID, conv_bt1 + l * HID, t, sO, N, invN);
        bn_apply_pool<<<G, 512, 0, stream>>>(
            t, h16, sO, bn_g + l * HID, bn_b + l * HID, starts, z, l, invN);
    }

    head_gemm1<<<G, 512, 0, stream>>>(z, head_W1, head_b1, zr, msums);
    head_final<<<G, 128, 0, stream>>>(zr, msums, head_g, head_bt, head_W2, head_b2,
                                      (float*)d_out, invG);
}

// Round 14
// 615.867 us; speedup vs baseline: 1.2179x; 1.0102x over previous
//
#include <hip/hip_runtime.h>
#include <hip/hip_bf16.h>
#include <hip/hip_fp16.h>

#define HID 128
#define EDIM 16
#define NSTAT 16   // stat-slot copies to break atomic serialization

typedef float v4f __attribute__((ext_vector_type(4)));
typedef float v2f __attribute__((ext_vector_type(2)));
typedef short s8v __attribute__((ext_vector_type(8)));   // 8 bf16 (4 VGPRs) MFMA frag
typedef float f4v __attribute__((ext_vector_type(4)));   // MFMA acc
typedef unsigned int u8x __attribute__((ext_vector_type(8)));  // 8 dwords = 16 f16
typedef _Float16 h2v __attribute__((ext_vector_type(2)));      // f16 pair for fdot2

#define MFMA_BF16(a, b, c) __builtin_amdgcn_mfma_f32_16x16x32_bf16((a), (b), (c), 0, 0, 0)

__device__ __forceinline__ unsigned short bf16_rne(float v)
{
    unsigned u = __builtin_bit_cast(unsigned, v);
    return (unsigned short)((u + 0x7fffu + ((u >> 16) & 1u)) >> 16);
}

__device__ __forceinline__ unsigned pack2(float lo, float hi)
{
    return (unsigned)bf16_rne(lo) | ((unsigned)bf16_rne(hi) << 16);
}

__device__ __forceinline__ float bflo(unsigned u) { return __builtin_bit_cast(float, u << 16); }
__device__ __forceinline__ float bfhi(unsigned u) { return __builtin_bit_cast(float, u & 0xffff0000u); }

__device__ __forceinline__ v2f unpack2(unsigned u)
{
    v2f r; r.x = bflo(u); r.y = bfhi(u); return r;
}

__device__ __forceinline__ void split_bf16(float v, unsigned short& h, unsigned short& l)
{
    unsigned u = __builtin_bit_cast(unsigned, v);
    unsigned hu = (u + 0x7fffu + ((u >> 16) & 1u)) >> 16;
    h = (unsigned short)hu;
    float hf = __builtin_bit_cast(float, hu << 16);
    l = bf16_rne(v - hf);
}

__device__ __forceinline__ v2f vmax0(v2f a)
{
    v2f r; r.x = fmaxf(a.x, 0.f); r.y = fmaxf(a.y, 0.f); return r;
}

// pack two floats to f16x2 (RNE)
__device__ __forceinline__ unsigned pkh2(float lo, float hi)
{
    return (unsigned)__half_as_ushort(__float2half(lo)) |
           ((unsigned)__half_as_ushort(__float2half(hi)) << 16);
}

// d += ea.lo*w.lo + ea.hi*w.hi (fp32 accumulate). Builtin (NOT bare asm): bare
// VOP3P asm assembles wrong default modifiers (round-6 absmax 0.54).
__device__ __forceinline__ void dot2(float& d, unsigned ea, unsigned w)
{
    d = __builtin_amdgcn_fdot2(__builtin_bit_cast(h2v, ea),
                               __builtin_bit_cast(h2v, w), d, false);
}

// ================= CSR build =================
__global__ void hist_kernel(const int* __restrict__ dst, int* __restrict__ deg, int E)
{
    int e = blockIdx.x * 256 + threadIdx.x;
    if (e < E) atomicAdd(&deg[dst[e]], 1);
}

__global__ void block_sum_kernel(const int* __restrict__ deg, int* __restrict__ bsum, int Nn)
{
    int i = blockIdx.x * 256 + threadIdx.x;
    int v = (i < Nn) ? deg[i] : 0;
#pragma unroll
    for (int off = 32; off > 0; off >>= 1) v += __shfl_down(v, off, 64);
    __shared__ int ws[4];
    if ((threadIdx.x & 63) == 0) ws[threadIdx.x >> 6] = v;
    __syncthreads();
    if (threadIdx.x == 0) bsum[blockIdx.x] = ws[0] + ws[1] + ws[2] + ws[3];
}

__global__ void bsum_scan_kernel(int* bsum, int nb, int* total_out)
{
    __shared__ int sh[256];
    int tid = threadIdx.x;
    int v = (tid < nb) ? bsum[tid] : 0;
    sh[tid] = v;
    __syncthreads();
    for (int off = 1; off < 256; off <<= 1) {
        int tv = (tid >= off) ? sh[tid - off] : 0;
        __syncthreads();
        sh[tid] += tv;
        __syncthreads();
    }
    if (tid < nb) bsum[tid] = sh[tid] - v;
    if (tid == 255) *total_out = sh[255];
}

// block-level CSR scan + (last block) graph segment starts — one fused dispatch
__global__ void block_scan_kernel(const int* __restrict__ deg, const int* __restrict__ bsum,
                                  int* __restrict__ row_start, int* __restrict__ cursor,
                                  const int* __restrict__ batch, int* __restrict__ starts,
                                  int Nn, int Gn)
{
    __shared__ int sh[256];
    int tid = threadIdx.x;
    int i = blockIdx.x * 256 + tid;
    int v = (i < Nn) ? deg[i] : 0;
    sh[tid] = v;
    __syncthreads();
    for (int off = 1; off < 256; off <<= 1) {
        int tv = (tid >= off) ? sh[tid - off] : 0;
        __syncthreads();
        sh[tid] += tv;
        __syncthreads();
    }
    if (i < Nn) {
        int excl = sh[tid] - v + bsum[blockIdx.x];
        row_start[i] = excl;
        cursor[i] = excl;
    }
    if (blockIdx.x == gridDim.x - 1) {
        for (int g = tid; g <= Gn; g += 256) {
            int lo = 0, hi = Nn;
            while (lo < hi) { int mid = (lo + hi) >> 1; if (batch[mid] < g) lo = mid + 1; else hi = mid; }
            starts[g] = lo;
        }
    }
}

// phase 1: permutation only (12B/edge traffic; scattered 4B writes live in L2)
__global__ void scatter_kernel(const int* __restrict__ src, const int* __restrict__ dst,
                               int* cursor, int* __restrict__ perm,
                               int* __restrict__ src_perm, int E)
{
    int e = blockIdx.x * 256 + threadIdx.x;
    if (e >= E) return;
    int pos = atomicAdd(&cursor[dst[e]], 1);
    perm[pos] = e;
    src_perm[pos] = src[e];
}

// phase 2: ea permute-copy + f16 convert — scattered READS (no RFO),
// fully COALESCED 16B writes (r13's fused scatter-write form caused 3x write
// amplification: 103 MB WRITE_SIZE, 81 µs). 2 threads per edge row.
__global__ void gather_ea_f16(const float* __restrict__ ea, const int* __restrict__ perm,
                              unsigned* __restrict__ eaH, int E)
{
    int idx = blockIdx.x * 256 + threadIdx.x;
    int p = idx >> 1, hf = idx & 1;
    if (p >= E) return;
    int e = perm[p];
    const float* ap = &ea[(size_t)e * EDIM + hf * 8];
    float4 f0 = *(const float4*)ap;
    float4 f1 = *(const float4*)(ap + 4);
    uint4 o;
    o.x = pkh2(f0.x, f0.y);
    o.y = pkh2(f0.z, f0.w);
    o.z = pkh2(f1.x, f1.y);
    o.w = pkh2(f1.z, f1.w);
    *(uint4*)&eaH[(size_t)p * 8 + hf * 4] = o;
}

// ================= weight prep: fp32 [K,128] -> transposed split-bf16 [128,K] hi/lo =================
__global__ void prep_weights(const float* __restrict__ Wp, const float* __restrict__ W1,
                             const float* __restrict__ W2, unsigned short* __restrict__ out)
{
    int idx = blockIdx.x * 256 + threadIdx.x;
    if (idx < 8192) {
        int n = idx >> 6, k = idx & 63;
        unsigned short h, l;
        split_bf16(Wp[k * 128 + n], h, l);
        out[idx] = h;
        out[8192 + idx] = l;
    } else {
        int j = idx - 8192;
        if (j >= 6 * 16384) return;
        int m2 = j >> 14;
        int r = j & 16383;
        int n = r >> 7, k = r & 127;
        int l = m2 >> 1;
        const float* Wsrc = (m2 & 1) ? (W2 + l * 16384) : (W1 + l * 16384);
        unsigned short h, lo;
        split_bf16(Wsrc[k * 128 + n], h, lo);
        int base = 16384 + m2 * 32768;
        out[base + r] = h;
        out[base + 16384 + r] = lo;
    }
}

// ====== Node-centric aggregation (r7 structure, ~62 µs): f16 ea + fdot2 ======
// 1 wave/node, 2 ch/lane. ea rows wave-uniform -> SGPR (8 dwords/row);
// 16 dot2/edge. 8-edge groups: one lgkmcnt drain per 8 edges.
// h gathers rotated one group ahead (VMEM, counted).
// PACK: store each output channel as u32 = bf16_hi | (bf16_lo<<16) IN t (same
// 4B/elem) so the W1 GEMM stages with bit-ops only — bit-identical to
// fp32-store-then-split (split-at-producer == split-at-consumer).
__device__ __forceinline__ void edge_f16(v2f& acc, v2f bj, unsigned hu, const u8x& e,
                                         const unsigned* __restrict__ wpk0,
                                         const unsigned* __restrict__ wpk1)
{
    float m0 = bj.x + bflo(hu);
    float m1 = bj.y + bfhi(hu);
#pragma unroll
    for (int kp = 0; kp < 8; ++kp) {
        dot2(m0, e[kp], wpk0[kp]);
        dot2(m1, e[kp], wpk1[kp]);
    }
    acc.x += fmaxf(m0, 0.f);
    acc.y += fmaxf(m1, 0.f);
}

template<bool PACK>
__global__ __launch_bounds__(256, 8) void aggregate_f16(
    const unsigned short* __restrict__ h16, const unsigned* __restrict__ eaH,
    const int* __restrict__ src_perm, const int* __restrict__ row_start,
    const float* __restrict__ We, const float* __restrict__ be,
    float* __restrict__ t, int Nn)
{
    int tid = threadIdx.x;
    int lane = tid & 63;
    int c = lane * 2;
    // f16 weight k-pairs per output channel (16 VGPRs)
    unsigned wpk0[8], wpk1[8];
#pragma unroll
    for (int kp = 0; kp < 8; ++kp) {
        wpk0[kp] = pkh2(We[(2 * kp) * HID + c],     We[(2 * kp + 1) * HID + c]);
        wpk1[kp] = pkh2(We[(2 * kp) * HID + c + 1], We[(2 * kp + 1) * HID + c + 1]);
    }
    v2f bj = *(const v2f*)&be[c];
    int node = blockIdx.x * 4 + (tid >> 6);
    if (node >= Nn) return;
    const unsigned* __restrict__ hw = (const unsigned*)h16 + lane;  // bf16 ch-pair per lane
    v2f acc = unpack2(hw[(unsigned)node << 6]);
    int p0 = __builtin_amdgcn_readfirstlane(row_start[node]);
    int p1 = __builtin_amdgcn_readfirstlane(row_start[node + 1]);
    int p = p0;

    int s0 = 0, s1 = 0, s2 = 0, s3 = 0, s4 = 0, s5 = 0, s6 = 0, s7 = 0;
    unsigned hu0 = 0, hu1 = 0, hu2 = 0, hu3 = 0, hu4 = 0, hu5 = 0, hu6 = 0, hu7 = 0;
    if (p + 8 <= p1) {
        s0 = src_perm[p];     s1 = src_perm[p + 1]; s2 = src_perm[p + 2]; s3 = src_perm[p + 3];
        s4 = src_perm[p + 4]; s5 = src_perm[p + 5]; s6 = src_perm[p + 6]; s7 = src_perm[p + 7];
        hu0 = hw[(unsigned)s0 << 6]; hu1 = hw[(unsigned)s1 << 6];
        hu2 = hw[(unsigned)s2 << 6]; hu3 = hw[(unsigned)s3 << 6];
        hu4 = hw[(unsigned)s4 << 6]; hu5 = hw[(unsigned)s5 << 6];
        hu6 = hw[(unsigned)s6 << 6]; hu7 = hw[(unsigned)s7 << 6];
    }
    while (p + 8 <= p1) {
        int np = p + 8;
        // current group's ea rows (SMEM, 8 x dwordx8)
        u8x e0 = *(const u8x*)(eaH + (size_t)(unsigned)(p    ) * 8);
        u8x e1 = *(const u8x*)(eaH + (size_t)(unsigned)(p + 1) * 8);
        u8x e2 = *(const u8x*)(eaH + (size_t)(unsigned)(p + 2) * 8);
        u8x e3 = *(const u8x*)(eaH + (size_t)(unsigned)(p + 3) * 8);
        u8x e4 = *(const u8x*)(eaH + (size_t)(unsigned)(p + 4) * 8);
        u8x e5 = *(const u8x*)(eaH + (size_t)(unsigned)(p + 5) * 8);
        u8x e6 = *(const u8x*)(eaH + (size_t)(unsigned)(p + 6) * 8);
        u8x e7 = *(const u8x*)(eaH + (size_t)(unsigned)(p + 7) * 8);
        // next group's src ids + h rows (prefetch)
        int t0 = 0, t1 = 0, t2 = 0, t3 = 0, t4 = 0, t5 = 0, t6 = 0, t7 = 0;
        unsigned hn0 = 0, hn1 = 0, hn2 = 0, hn3 = 0, hn4 = 0, hn5 = 0, hn6 = 0, hn7 = 0;
        if (np + 8 <= p1) {
            t0 = src_perm[np];     t1 = src_perm[np + 1]; t2 = src_perm[np + 2]; t3 = src_perm[np + 3];
            t4 = src_perm[np + 4]; t5 = src_perm[np + 5]; t6 = src_perm[np + 6]; t7 = src_perm[np + 7];
            hn0 = hw[(unsigned)t0 << 6]; hn1 = hw[(unsigned)t1 << 6];
            hn2 = hw[(unsigned)t2 << 6]; hn3 = hw[(unsigned)t3 << 6];
            hn4 = hw[(unsigned)t4 << 6]; hn5 = hw[(unsigned)t5 << 6];
            hn6 = hw[(unsigned)t6 << 6]; hn7 = hw[(unsigned)t7 << 6];
        }
        edge_f16(acc, bj, hu0, e0, wpk0, wpk1);
        edge_f16(acc, bj, hu1, e1, wpk0, wpk1);
        edge_f16(acc, bj, hu2, e2, wpk0, wpk1);
        edge_f16(acc, bj, hu3, e3, wpk0, wpk1);
        edge_f16(acc, bj, hu4, e4, wpk0, wpk1);
        edge_f16(acc, bj, hu5, e5, wpk0, wpk1);
        edge_f16(acc, bj, hu6, e6, wpk0, wpk1);
        edge_f16(acc, bj, hu7, e7, wpk0, wpk1);
        p = np;
        s0 = t0; s1 = t1; s2 = t2; s3 = t3; s4 = t4; s5 = t5; s6 = t6; s7 = t7;
        hu0 = hn0; hu1 = hn1; hu2 = hn2; hu3 = hn3;
        hu4 = hn4; hu5 = hn5; hu6 = hn6; hu7 = hn7;
    }
    for (; p < p1; ++p) {
        int s = src_perm[p];
        unsigned hu = hw[(unsigned)s << 6];
        u8x e = *(const u8x*)(eaH + (size_t)(unsigned)p * 8);
        edge_f16(acc, bj, hu, e, wpk0, wpk1);
    }
    if (PACK) {
        unsigned short h0, l0, h1, l1;
        split_bf16(acc.x, h0, l0);
        split_bf16(acc.y, h1, l1);
        uint2 pk;
        pk.x = (unsigned)h0 | ((unsigned)l0 << 16);
        pk.y = (unsigned)h1 | ((unsigned)l1 << 16);
        *(uint2*)((unsigned*)t + ((unsigned)node << 7) + c) = pk;
    } else {
        *(v2f*)(t + ((unsigned)node << 7) + c) = acc;
    }
}

// ====== fallback (no workspace for eaH): round-0 fp32 path via perm indirection ======
__device__ __forceinline__ void matvp(const v4f& a0, const v4f& a1,
                                      const v4f& a2, const v4f& a3,
                                      const v2f* __restrict__ w, v2f& m)
{
    m += w[0] * a0.x;  m += w[1] * a0.y;  m += w[2] * a0.z;  m += w[3] * a0.w;
    m += w[4] * a1.x;  m += w[5] * a1.y;  m += w[6] * a1.z;  m += w[7] * a1.w;
    m += w[8] * a2.x;  m += w[9] * a2.y;  m += w[10] * a2.z; m += w[11] * a2.w;
    m += w[12] * a3.x; m += w[13] * a3.y; m += w[14] * a3.z; m += w[15] * a3.w;
}

__global__ __launch_bounds__(256, 8) void aggregate_fp32(
    const unsigned short* __restrict__ h16, const float* __restrict__ eaG,
    const int* __restrict__ perm, const int* __restrict__ src_perm,
    const int* __restrict__ row_start,
    const float* __restrict__ We, const float* __restrict__ be,
    float* __restrict__ t, int Nn)
{
    int tid = threadIdx.x;
    int lane = tid & 63;
    int c = lane * 2;
    v2f w[16];
#pragma unroll
    for (int k = 0; k < 16; ++k) w[k] = *(const v2f*)&We[k * HID + c];
    v2f bj = *(const v2f*)&be[c];
    int node = blockIdx.x * 4 + (tid >> 6);
    if (node >= Nn) return;
    const unsigned* __restrict__ hw = (const unsigned*)h16 + lane;
    v2f acc = unpack2(hw[(unsigned)node << 6]);
    int p0 = __builtin_amdgcn_readfirstlane(row_start[node]);
    int p1 = __builtin_amdgcn_readfirstlane(row_start[node + 1]);
    int p = p0;
    int s0 = 0, s1 = 0, s2 = 0, s3 = 0;
    if (p + 4 <= p1) { s0 = src_perm[p]; s1 = src_perm[p + 1]; s2 = src_perm[p + 2]; s3 = src_perm[p + 3]; }
    while (p + 4 <= p1) {
        int np = p + 4;
        int t0 = 0, t1 = 0, t2 = 0, t3 = 0;
        if (np + 4 <= p1) { t0 = src_perm[np]; t1 = src_perm[np + 1]; t2 = src_perm[np + 2]; t3 = src_perm[np + 3]; }
        unsigned hu0 = hw[(unsigned)s0 << 6];
        unsigned hu1 = hw[(unsigned)s1 << 6];
        unsigned hu2 = hw[(unsigned)s2 << 6];
        unsigned hu3 = hw[(unsigned)s3 << 6];
        int q0 = perm[p], q1 = perm[p + 1], q2 = perm[p + 2], q3 = perm[p + 3];
        const v4f* e0 = (const v4f*)(eaG + (size_t)(unsigned)q0 * EDIM);
        const v4f* e1 = (const v4f*)(eaG + (size_t)(unsigned)q1 * EDIM);
        const v4f* e2 = (const v4f*)(eaG + (size_t)(unsigned)q2 * EDIM);
        const v4f* e3 = (const v4f*)(eaG + (size_t)(unsigned)q3 * EDIM);
        v4f a00 = e0[0], a01 = e0[1], a02 = e0[2], a03 = e0[3];
        v4f a10 = e1[0], a11 = e1[1], a12 = e1[2], a13 = e1[3];
        v4f a20 = e2[0], a21 = e2[1], a22 = e2[2], a23 = e2[3];
        v4f a30 = e3[0], a31 = e3[1], a32 = e3[2], a33 = e3[3];
        v2f m0 = bj + unpack2(hu0), m1 = bj + unpack2(hu1);
        v2f m2 = bj + unpack2(hu2), m3 = bj + unpack2(hu3);
        matvp(a00, a01, a02, a03, w, m0);
        matvp(a10, a11, a12, a13, w, m1);
        matvp(a20, a21, a22, a23, w, m2);
        matvp(a30, a31, a32, a33, w, m3);
        acc += (vmax0(m0) + vmax0(m1)) + (vmax0(m2) + vmax0(m3));
        p = np;
        s0 = t0; s1 = t1; s2 = t2; s3 = t3;
    }
    for (; p < p1; ++p) {
        int s = src_perm[p];
        int q = perm[p];
        const v4f* e0 = (const v4f*)(eaG + (size_t)(unsigned)q * EDIM);
        v4f a0 = e0[0], a1 = e0[1], a2 = e0[2], a3 = e0[3];
        v2f m0 = bj + unpack2(hw[(unsigned)s << 6]);
        matvp(a0, a1, a2, a3, w, m0);
        acc += vmax0(m0);
    }
    *(v2f*)(t + ((unsigned)node << 7) + c) = acc;
}

// ================= split-bf16 MFMA GEMM =================
// Stats are NSTAT-way slot-striped (r11, −44 µs): producer block b adds into
// slot (b & 15); consumers sum the 16 slots.
// A_PACK: A rows are packed-split u32 (hi | lo<<16) — staging is bit-ops only.
#define LPAD 40

template<int K, bool PRE_BN, bool POST_STATS, bool OUT_BF16, bool A_PACK>
__global__ __launch_bounds__(256) void gemm_mfma(
    const float* __restrict__ A, const unsigned short* __restrict__ Wh,
    const unsigned short* __restrict__ Wl, const float* __restrict__ bias,
    const float* __restrict__ preStats, const float* __restrict__ preG, const float* __restrict__ preB,
    void* __restrict__ Cout, float* __restrict__ postStats, int Nrows, float invN)
{
    __shared__ __align__(16) unsigned short Ah[128 * LPAD], Al[128 * LPAD];
    __shared__ __align__(16) unsigned short Bh[128 * LPAD], Bl[128 * LPAD];
    __shared__ float sc[PRE_BN ? K : 1], sb[PRE_BN ? K : 1];
    int tid = threadIdx.x;
    int rbase = blockIdx.x * 128;
    if (PRE_BN) {
        if (tid < K) {
            float Sm = 0.f, Qm = 0.f;
#pragma unroll
            for (int cpy = 0; cpy < NSTAT; ++cpy) {
                Sm += preStats[(cpy << 8) + tid];
                Qm += preStats[(cpy << 8) + 128 + tid];
            }
            float mean = Sm * invN;
            float var = Qm * invN - mean * mean;
            float rstd = rsqrtf(var + 1e-5f);
            float g = preG[tid];
            sc[tid] = rstd * g;
            sb[tid] = preB[tid] - mean * rstd * g;
        }
        __syncthreads();
    }
    int w = tid >> 6, nl = tid & 15, q = (tid >> 4) & 3;
    f4v acc[2][8];
#pragma unroll
    for (int mt = 0; mt < 2; ++mt)
#pragma unroll
        for (int nt = 0; nt < 8; ++nt)
#pragma unroll
            for (int r = 0; r < 4; ++r) acc[mt][nt][r] = 0.f;

    for (int ks = 0; ks < K / 32; ++ks) {
        int k0 = ks * 32;
        if (ks) __syncthreads();
#pragma unroll
        for (int i = 0; i < 4; ++i) {
            int cidx = tid + i * 256;
            int m = cidx >> 3, k4 = (cidx & 7) * 4;
            int gr = rbase + m;
            uint2 hp, lp;
            if (A_PACK) {
                uint4 v = make_uint4(0u, 0u, 0u, 0u);
                if (gr < Nrows) v = *(const uint4*)((const unsigned*)A + (size_t)gr * K + k0 + k4);
                hp.x = (v.x & 0xffffu) | (v.y << 16);
                hp.y = (v.z & 0xffffu) | (v.w << 16);
                lp.x = (v.x >> 16) | (v.y & 0xffff0000u);
                lp.y = (v.z >> 16) | (v.w & 0xffff0000u);
            } else {
                float4 v = make_float4(0.f, 0.f, 0.f, 0.f);
                if (gr < Nrows) v = *(const float4*)&A[(size_t)gr * K + k0 + k4];
                if (PRE_BN) {
                    v.x = fmaxf(v.x * sc[k0 + k4]     + sb[k0 + k4],     0.f);
                    v.y = fmaxf(v.y * sc[k0 + k4 + 1] + sb[k0 + k4 + 1], 0.f);
                    v.z = fmaxf(v.z * sc[k0 + k4 + 2] + sb[k0 + k4 + 2], 0.f);
                    v.w = fmaxf(v.w * sc[k0 + k4 + 3] + sb[k0 + k4 + 3], 0.f);
                }
                unsigned short h0, l0, h1, l1, h2, l2, h3, l3;
                split_bf16(v.x, h0, l0); split_bf16(v.y, h1, l1);
                split_bf16(v.z, h2, l2); split_bf16(v.w, h3, l3);
                hp.x = (unsigned)h0 | ((unsigned)h1 << 16); hp.y = (unsigned)h2 | ((unsigned)h3 << 16);
                lp.x = (unsigned)l0 | ((unsigned)l1 << 16); lp.y = (unsigned)l2 | ((unsigned)l3 << 16);
            }
            *(uint2*)&Ah[m * LPAD + k4] = hp;
            *(uint2*)&Al[m * LPAD + k4] = lp;
        }
#pragma unroll
        for (int i = 0; i < 2; ++i) {
            int g = tid + i * 256;
            int n = g >> 2, kq = (g & 3) * 8;
            uint4 hv = *(const uint4*)&Wh[(size_t)n * K + k0 + kq];
            uint4 lv = *(const uint4*)&Wl[(size_t)n * K + k0 + kq];
            *(uint4*)&Bh[n * LPAD + kq] = hv;
            *(uint4*)&Bl[n * LPAD + kq] = lv;
        }
        __syncthreads();
        s8v ah0 = *(const s8v*)&Ah[(w * 32 + nl) * LPAD + q * 8];
        s8v ah1 = *(const s8v*)&Ah[(w * 32 + 16 + nl) * LPAD + q * 8];
        s8v al0 = *(const s8v*)&Al[(w * 32 + nl) * LPAD + q * 8];
        s8v al1 = *(const s8v*)&Al[(w * 32 + 16 + nl) * LPAD + q * 8];
#pragma unroll
        for (int nt = 0; nt < 8; ++nt) {
            s8v bh = *(const s8v*)&Bh[(nt * 16 + nl) * LPAD + q * 8];
            s8v bl = *(const s8v*)&Bl[(nt * 16 + nl) * LPAD + q * 8];
            acc[0][nt] = MFMA_BF16(ah0, bh, acc[0][nt]);
            acc[0][nt] = MFMA_BF16(ah0, bl, acc[0][nt]);
            acc[0][nt] = MFMA_BF16(al0, bh, acc[0][nt]);
            acc[1][nt] = MFMA_BF16(ah1, bh, acc[1][nt]);
            acc[1][nt] = MFMA_BF16(ah1, bl, acc[1][nt]);
            acc[1][nt] = MFMA_BF16(al1, bh, acc[1][nt]);
        }
    }
    __syncthreads();

    float* Cf = (float*)Cout;
    unsigned short* Ch = (unsigned short*)Cout;
    float* redS = (float*)Ah;
    float* redQ = (float*)Al;
#pragma unroll
    for (int nt = 0; nt < 8; ++nt) {
        int col = nt * 16 + nl;
        float bcol = bias[col];
        float sv = 0.f, qv = 0.f;
#pragma unroll
        for (int mt = 0; mt < 2; ++mt) {
#pragma unroll
            for (int r = 0; r < 4; ++r) {
                int grow = rbase + w * 32 + mt * 16 + q * 4 + r;
                if (grow < Nrows) {
                    float o = acc[mt][nt][r] + bcol;
                    if (OUT_BF16) Ch[(size_t)grow * HID + col] = bf16_rne(o);
                    else          Cf[(size_t)grow * HID + col] = o;
                    if (POST_STATS) { sv += o; qv += o * o; }
                }
            }
        }
        if (POST_STATS) {
            sv += __shfl_down(sv, 32, 64); sv += __shfl_down(sv, 16, 64);
            qv += __shfl_down(qv, 32, 64); qv += __shfl_down(qv, 16, 64);
            if ((tid & 63) < 16) { redS[w * 128 + col] = sv; redQ[w * 128 + col] = qv; }
        }
    }
    if (POST_STATS) {
        __syncthreads();
        if (tid < 128) {
            float S = redS[tid] + redS[128 + tid] + redS[256 + tid] + redS[384 + tid];
            float Q = redQ[tid] + redQ[128 + tid] + redQ[256 + tid] + redQ[384 + tid];
            int cp = (blockIdx.x & (NSTAT - 1)) << 8;   // slot-striped: ~25 contenders/addr
            atomicAdd(&postStats[cp + tid], S);
            atomicAdd(&postStats[cp + 128 + tid], Q);
        }
    }
}

// ======== fused BN apply + ReLU + pool; h stored as packed bf16 (pool uses exact fp32) ========
__global__ void bn_apply_pool(const float* __restrict__ X, unsigned short* __restrict__ h16,
                              const float* __restrict__ stats, const float* __restrict__ g,
                              const float* __restrict__ b, const int* __restrict__ starts,
                              float* __restrict__ z, int l, float invN)
{
    int gph = blockIdx.x;
    int tid = threadIdx.x;
    int ch4 = (tid & 31) * 4, wk = tid >> 5;   // 16 walkers x 32 lanes(float4)
    float sc[4], sh[4];
#pragma unroll
    for (int u = 0; u < 4; ++u) {
        int j = ch4 + u;
        float Sm = 0.f, Qm = 0.f;
#pragma unroll
        for (int cpy = 0; cpy < NSTAT; ++cpy) {
            Sm += stats[(cpy << 8) + j];
            Qm += stats[(cpy << 8) + 128 + j];
        }
        float mean = Sm * invN;
        float var = Qm * invN - mean * mean;
        float rstd = rsqrtf(var + 1e-5f);
        float gg = g[j];
        sc[u] = rstd * gg;
        sh[u] = b[j] - mean * rstd * gg;
    }
    int s = starts[gph], e = starts[gph + 1];
    float4 sum = make_float4(0.f, 0.f, 0.f, 0.f);
    float4 mx = make_float4(0.f, 0.f, 0.f, 0.f);
    unsigned* hv32 = (unsigned*)h16;
    for (int n = s + wk; n < e; n += 16) {
        float4 v = *(const float4*)&X[(size_t)n * HID + ch4];
        v.x = fmaxf(v.x * sc[0] + sh[0], 0.f);
        v.y = fmaxf(v.y * sc[1] + sh[1], 0.f);
        v.z = fmaxf(v.z * sc[2] + sh[2], 0.f);
        v.w = fmaxf(v.w * sc[3] + sh[3], 0.f);
        uint2 pk;
        pk.x = pack2(v.x, v.y);
        pk.y = pack2(v.z, v.w);
        *(uint2*)&hv32[(size_t)n * 64 + (ch4 >> 1)] = pk;
        sum.x += v.x; sum.y += v.y; sum.z += v.z; sum.w += v.w;
        mx.x = fmaxf(mx.x, v.x); mx.y = fmaxf(mx.y, v.y);
        mx.z = fmaxf(mx.z, v.z); mx.w = fmaxf(mx.w, v.w);
    }
    __shared__ float ls[16 * 128], lm[16 * 128];
    *(float4*)&ls[wk * 128 + ch4] = sum;
    *(float4*)&lm[wk * 128 + ch4] = mx;
    __syncthreads();
    if (tid < 128) {
        float S = 0.f, M = 0.f;
#pragma unroll
        for (int k = 0; k < 16; ++k) {
            S += ls[k * 128 + tid];
            M = fmaxf(M, lm[k * 128 + tid]);
        }
        float cnt = (float)(e - s);
        z[(size_t)gph * 768 + l * 128 + tid] = S / fmaxf(cnt, 1.f);
        z[(size_t)gph * 768 + 384 + l * 128 + tid] = M;
    }
}

// ================= head =================
// 512 threads: 4-way K-split (192/thread vs 768) + LDS reduce — 4x the waves,
// 4x shorter serial FMA chain (old version ran at 0.5 waves/SIMD).
__global__ void head_gemm1(const float* __restrict__ z, const float* __restrict__ W,
                           const float* __restrict__ bias, float* __restrict__ zr,
                           float* __restrict__ msums)
{
    __shared__ __align__(16) float zl[768];
    __shared__ float part[512];
    int g = blockIdx.x, j = threadIdx.x;
    for (int i = j; i < 768; i += 512) zl[i] = z[(size_t)g * 768 + i];
    __syncthreads();
    int ch = j & 127, kq = j >> 7;       // 4 k-quarters x 128 channels
    int kbase = kq * 192;
    float acc = 0.f;
    for (int k = 0; k < 192; k += 4) {
        float4 a4 = *(const float4*)&zl[kbase + k];
        acc += a4.x * W[(kbase + k) * 128 + ch] + a4.y * W[(kbase + k + 1) * 128 + ch]
             + a4.z * W[(kbase + k + 2) * 128 + ch] + a4.w * W[(kbase + k + 3) * 128 + ch];
    }
    part[j] = acc;
    __syncthreads();
    if (j < 128) {
        float v = part[j] + part[128 + j] + part[256 + j] + part[384 + j] + bias[j];
        zr[(size_t)g * 128 + j] = v;
        int cp = (g & (NSTAT - 1)) << 8;   // slot-striped msums
        atomicAdd(&msums[cp + j], v);
        atomicAdd(&msums[cp + 128 + j], v * v);
    }
}

__global__ void head_final(const float* __restrict__ zr, const float* __restrict__ msums,
                           const float* __restrict__ hg, const float* __restrict__ hb,
                           const float* __restrict__ W2, const float* __restrict__ b2,
                           float* __restrict__ out, float invG)
{
    int g = blockIdx.x, j = threadIdx.x;
    float Sm = 0.f, Qm = 0.f;
#pragma unroll
    for (int cpy = 0; cpy < NSTAT; ++cpy) {
        Sm += msums[(cpy << 8) + j];
        Qm += msums[(cpy << 8) + 128 + j];
    }
    float mean = Sm * invG;
    float var = Qm * invG - mean * mean;
    float rstd = rsqrtf(var + 1e-5f);
    float v = zr[(size_t)g * 128 + j];
    v = (v - mean) * rstd * hg[j] + hb[j];
    v = fmaxf(v, 0.f);
    float p = v * W2[j];
#pragma unroll
    for (int off = 32; off > 0; off >>= 1) p += __shfl_down(p, off, 64);
    __shared__ float partial[2];
    if ((j & 63) == 0) partial[j >> 6] = p;
    __syncthreads();
    if (j == 0) out[g] = partial[0] + partial[1] + b2[0];
}

extern "C" void kernel_launch(void* const* d_in, const int* in_sizes, int n_in,
                              void* d_out, int out_size, void* d_ws, size_t ws_size,
                              hipStream_t stream)
{
    const float* x         = (const float*)d_in[0];
    const float* edge_attr = (const float*)d_in[1];
    const int*   src       = (const int*)d_in[2];
    const int*   dst       = (const int*)d_in[3];
    const int*   batch     = (const int*)d_in[4];
    const float* Wp        = (const float*)d_in[5];
    const float* bp        = (const float*)d_in[6];
    const float* conv_We   = (const float*)d_in[7];
    const float* conv_be   = (const float*)d_in[8];
    const float* conv_W1   = (const float*)d_in[9];
    const float* conv_b1   = (const float*)d_in[10];
    const float* conv_g1   = (const float*)d_in[11];
    const float* conv_bt1  = (const float*)d_in[12];
    const float* conv_W2   = (const float*)d_in[13];
    const float* conv_b2   = (const float*)d_in[14];
    const float* bn_g      = (const float*)d_in[15];
    const float* bn_b      = (const float*)d_in[16];
    const float* head_W1   = (const float*)d_in[17];
    const float* head_b1   = (const float*)d_in[18];
    const float* head_g    = (const float*)d_in[19];
    const float* head_bt   = (const float*)d_in[20];
    const float* head_W2   = (const float*)d_in[21];
    const float* head_b2   = (const float*)d_in[22];

    const int N = in_sizes[4];            // 50000
    const int E = in_sizes[2];            // 800000
    const int G = out_size;               // 256
    const int L = 3;

    // ---- workspace layout ----
    const int SLOT = NSTAT * 256;                    // 4096 floats per stat set
    float* t        = (float*)d_ws;                  // N*128 fp32
    unsigned short* h16 = (unsigned short*)(t + (size_t)N * HID);  // N*128 bf16
    float* z        = (float*)(h16 + (size_t)N * HID);             // G*768
    float* zr       = z + (size_t)G * 768;           // G*128
    float* statsAll = zr + (size_t)G * HID;          // 7 sets x SLOT
    int*   deg      = (int*)(statsAll + 7 * SLOT);   // N
    int*   starts   = deg + N;                       // G+1
    int*   row_start= starts + (G + 1);              // N+1
    int*   cursor   = row_start + (N + 1);           // N
    int*   bsum     = cursor + N;                    // 256
    int*   src_perm = bsum + 256;                    // E
    int*   perm     = src_perm + E;                  // E
    unsigned short* wt = (unsigned short*)(perm + E);  // 212992 ushorts gemm weights
    size_t base_end = (size_t)((char*)(wt + 212992) - (char*)d_ws);
    size_t ea_off = (base_end + 63) & ~(size_t)63;   // 64B-align ea rows
    bool gath = (ea_off + (size_t)E * 8 * sizeof(unsigned)) <= ws_size;  // f16 rows: 32B/edge
    unsigned* eaH = (unsigned*)((char*)d_ws + ea_off);
    float* msums = statsAll + 6 * SLOT;

    (void)n_in;

    const float invN = 1.0f / (float)N;
    const float invG = 1.0f / (float)G;
    const int nb = (N + 255) / 256;
    const int gemmBlocks = (N + 127) / 128;

    // ---- CSR build + weight prep ----
    (void)hipMemsetAsync(statsAll, 0, 7 * SLOT * sizeof(float) + (size_t)N * sizeof(int), stream);
    hist_kernel<<<(E + 255) / 256, 256, 0, stream>>>(dst, deg, E);
    block_sum_kernel<<<nb, 256, 0, stream>>>(deg, bsum, N);
    bsum_scan_kernel<<<1, 256, 0, stream>>>(bsum, nb, &row_start[N]);
    block_scan_kernel<<<nb, 256, 0, stream>>>(deg, bsum, row_start, cursor, batch, starts, N, G);
    scatter_kernel<<<(E + 255) / 256, 256, 0, stream>>>(src, dst, cursor, perm, src_perm, E);
    if (gath)
        gather_ea_f16<<<(E * 2 + 255) / 256, 256, 0, stream>>>(edge_attr, perm, eaH, E);
    prep_weights<<<(8192 + 6 * 16384 + 255) / 256, 256, 0, stream>>>(Wp, conv_W1, conv_W2, wt);

    const unsigned short* Wp_hi = wt;
    const unsigned short* Wp_lo = wt + 8192;

    // h16 = bf16(x @ Wp + bp)
    gemm_mfma<64, false, false, true, false><<<gemmBlocks, 256, 0, stream>>>(
        x, Wp_hi, Wp_lo, bp, nullptr, nullptr, nullptr, h16, nullptr, N, invN);

    for (int l = 0; l < L; ++l) {
        float* sI = statsAll + (size_t)(2 * l) * SLOT;
        float* sO = sI + SLOT;
        const unsigned short* W1hi = wt + 16384 + (size_t)(2 * l) * 32768;
        const unsigned short* W1lo = W1hi + 16384;
        const unsigned short* W2hi = wt + 16384 + (size_t)(2 * l + 1) * 32768;
        const unsigned short* W2lo = W2hi + 16384;
        if (gath) {
            // aggregate stores packed-split u32 in t; W1 gemm stages with bit-ops only
            aggregate_f16<true><<<(N + 3) / 4, 256, 0, stream>>>(
                h16, eaH, src_perm, row_start,
                conv_We + (size_t)l * EDIM * HID, conv_be + l * HID, t, N);
            gemm_mfma<128, false, true, false, true><<<gemmBlocks, 256, 0, stream>>>(
                t, W1hi, W1lo, conv_b1 + l * HID,
                nullptr, nullptr, nullptr, t, sI, N, invN);
        } else {
            aggregate_fp32<<<(N + 3) / 4, 256, 0, stream>>>(
                h16, edge_attr, perm, src_perm, row_start,
                conv_We + (size_t)l * EDIM * HID, conv_be + l * HID, t, N);
            gemm_mfma<128, false, true, false, false><<<gemmBlocks, 256, 0, stream>>>(
                t, W1hi, W1lo, conv_b1 + l * HID,
                nullptr, nullptr, nullptr, t, sI, N, invN);
        }
        gemm_mfma<128, true, true, false, false><<<gemmBlocks, 256, 0, stream>>>(
            t, W2hi, W2lo, conv_b2 + l * HID,
            sI, conv_g1 + l * HID, conv_bt1 + l * HID, t, sO, N, invN);
        bn_apply_pool<<<G, 512, 0, stream>>>(
            t, h16, sO, bn_g + l * HID, bn_b + l * HID, starts, z, l, invN);
    }

    head_gemm1<<<G, 512, 0, stream>>>(z, head_W1, head_b1, zr, msums);
    head_final<<<G, 128, 0, stream>>>(zr, msums, head_g, head_bt, head_W2, head_b2,
                                      (float*)d_out, invG);
}

// Round 15
// 615.606 us; speedup vs baseline: 1.2184x; 1.0004x over previous
//
#include <hip/hip_runtime.h>
#include <hip/hip_bf16.h>
#include <hip/hip_fp16.h>

#define HID 128
#define EDIM 16
#define NSTAT 16   // stat-slot copies to break atomic serialization

typedef float v4f __attribute__((ext_vector_type(4)));
typedef float v2f __attribute__((ext_vector_type(2)));
typedef short s8v __attribute__((ext_vector_type(8)));   // 8 bf16 (4 VGPRs) MFMA frag
typedef float f4v __attribute__((ext_vector_type(4)));   // MFMA acc
typedef unsigned int u8x __attribute__((ext_vector_type(8)));  // 8 dwords = 16 f16
typedef _Float16 h2v __attribute__((ext_vector_type(2)));      // f16 pair for fdot2

#define MFMA_BF16(a, b, c) __builtin_amdgcn_mfma_f32_16x16x32_bf16((a), (b), (c), 0, 0, 0)

__device__ __forceinline__ unsigned short bf16_rne(float v)
{
    unsigned u = __builtin_bit_cast(unsigned, v);
    return (unsigned short)((u + 0x7fffu + ((u >> 16) & 1u)) >> 16);
}

__device__ __forceinline__ unsigned pack2(float lo, float hi)
{
    return (unsigned)bf16_rne(lo) | ((unsigned)bf16_rne(hi) << 16);
}

__device__ __forceinline__ float bflo(unsigned u) { return __builtin_bit_cast(float, u << 16); }
__device__ __forceinline__ float bfhi(unsigned u) { return __builtin_bit_cast(float, u & 0xffff0000u); }

__device__ __forceinline__ v2f unpack2(unsigned u)
{
    v2f r; r.x = bflo(u); r.y = bfhi(u); return r;
}

__device__ __forceinline__ void split_bf16(float v, unsigned short& h, unsigned short& l)
{
    unsigned u = __builtin_bit_cast(unsigned, v);
    unsigned hu = (u + 0x7fffu + ((u >> 16) & 1u)) >> 16;
    h = (unsigned short)hu;
    float hf = __builtin_bit_cast(float, hu << 16);
    l = bf16_rne(v - hf);
}

__device__ __forceinline__ v2f vmax0(v2f a)
{
    v2f r; r.x = fmaxf(a.x, 0.f); r.y = fmaxf(a.y, 0.f); return r;
}

// pack two floats to f16x2 (RNE)
__device__ __forceinline__ unsigned pkh2(float lo, float hi)
{
    return (unsigned)__half_as_ushort(__float2half(lo)) |
           ((unsigned)__half_as_ushort(__float2half(hi)) << 16);
}

// d += ea.lo*w.lo + ea.hi*w.hi (fp32 accumulate). Builtin (NOT bare asm): bare
// VOP3P asm assembles wrong default modifiers (round-6 absmax 0.54).
__device__ __forceinline__ void dot2(float& d, unsigned ea, unsigned w)
{
    d = __builtin_amdgcn_fdot2(__builtin_bit_cast(h2v, ea),
                               __builtin_bit_cast(h2v, w), d, false);
}

// ================= CSR build =================
__global__ void hist_kernel(const int* __restrict__ dst, int* __restrict__ deg, int E)
{
    int e = blockIdx.x * 256 + threadIdx.x;
    if (e < E) atomicAdd(&deg[dst[e]], 1);
}

__global__ void block_sum_kernel(const int* __restrict__ deg, int* __restrict__ bsum, int Nn)
{
    int i = blockIdx.x * 256 + threadIdx.x;
    int v = (i < Nn) ? deg[i] : 0;
#pragma unroll
    for (int off = 32; off > 0; off >>= 1) v += __shfl_down(v, off, 64);
    __shared__ int ws[4];
    if ((threadIdx.x & 63) == 0) ws[threadIdx.x >> 6] = v;
    __syncthreads();
    if (threadIdx.x == 0) bsum[blockIdx.x] = ws[0] + ws[1] + ws[2] + ws[3];
}

__global__ void bsum_scan_kernel(int* bsum, int nb, int* total_out)
{
    __shared__ int sh[256];
    int tid = threadIdx.x;
    int v = (tid < nb) ? bsum[tid] : 0;
    sh[tid] = v;
    __syncthreads();
    for (int off = 1; off < 256; off <<= 1) {
        int tv = (tid >= off) ? sh[tid - off] : 0;
        __syncthreads();
        sh[tid] += tv;
        __syncthreads();
    }
    if (tid < nb) bsum[tid] = sh[tid] - v;
    if (tid == 255) *total_out = sh[255];
}

// block-level CSR scan + (last block) graph segment starts — one fused dispatch
__global__ void block_scan_kernel(const int* __restrict__ deg, const int* __restrict__ bsum,
                                  int* __restrict__ row_start, int* __restrict__ cursor,
                                  const int* __restrict__ batch, int* __restrict__ starts,
                                  int Nn, int Gn)
{
    __shared__ int sh[256];
    int tid = threadIdx.x;
    int i = blockIdx.x * 256 + tid;
    int v = (i < Nn) ? deg[i] : 0;
    sh[tid] = v;
    __syncthreads();
    for (int off = 1; off < 256; off <<= 1) {
        int tv = (tid >= off) ? sh[tid - off] : 0;
        __syncthreads();
        sh[tid] += tv;
        __syncthreads();
    }
    if (i < Nn) {
        int excl = sh[tid] - v + bsum[blockIdx.x];
        row_start[i] = excl;
        cursor[i] = excl;
    }
    if (blockIdx.x == gridDim.x - 1) {
        for (int g = tid; g <= Gn; g += 256) {
            int lo = 0, hi = Nn;
            while (lo < hi) { int mid = (lo + hi) >> 1; if (batch[mid] < g) lo = mid + 1; else hi = mid; }
            starts[g] = lo;
        }
    }
}

// phase 1: permutation only (12B/edge traffic; scattered 4B writes live in L2)
__global__ void scatter_kernel(const int* __restrict__ src, const int* __restrict__ dst,
                               int* cursor, int* __restrict__ perm,
                               int* __restrict__ src_perm, int E)
{
    int e = blockIdx.x * 256 + threadIdx.x;
    if (e >= E) return;
    int pos = atomicAdd(&cursor[dst[e]], 1);
    perm[pos] = e;
    src_perm[pos] = src[e];
}

// phase 2: ea permute-copy + f16 convert — scattered READS (no RFO),
// fully COALESCED 16B writes (r13's fused scatter-write form caused 3x write
// amplification: 103 MB WRITE_SIZE, 81 µs). 2 threads per edge row.
__global__ void gather_ea_f16(const float* __restrict__ ea, const int* __restrict__ perm,
                              unsigned* __restrict__ eaH, int E)
{
    int idx = blockIdx.x * 256 + threadIdx.x;
    int p = idx >> 1, hf = idx & 1;
    if (p >= E) return;
    int e = perm[p];
    const float* ap = &ea[(size_t)e * EDIM + hf * 8];
    float4 f0 = *(const float4*)ap;
    float4 f1 = *(const float4*)(ap + 4);
    uint4 o;
    o.x = pkh2(f0.x, f0.y);
    o.y = pkh2(f0.z, f0.w);
    o.z = pkh2(f1.x, f1.y);
    o.w = pkh2(f1.z, f1.w);
    *(uint4*)&eaH[(size_t)p * 8 + hf * 4] = o;
}

// ================= weight prep: fp32 [K,128] -> transposed split-bf16 [128,K] hi/lo =================
__global__ void prep_weights(const float* __restrict__ Wp, const float* __restrict__ W1,
                             const float* __restrict__ W2, unsigned short* __restrict__ out)
{
    int idx = blockIdx.x * 256 + threadIdx.x;
    if (idx < 8192) {
        int n = idx >> 6, k = idx & 63;
        unsigned short h, l;
        split_bf16(Wp[k * 128 + n], h, l);
        out[idx] = h;
        out[8192 + idx] = l;
    } else {
        int j = idx - 8192;
        if (j >= 6 * 16384) return;
        int m2 = j >> 14;
        int r = j & 16383;
        int n = r >> 7, k = r & 127;
        int l = m2 >> 1;
        const float* Wsrc = (m2 & 1) ? (W2 + l * 16384) : (W1 + l * 16384);
        unsigned short h, lo;
        split_bf16(Wsrc[k * 128 + n], h, lo);
        int base = 16384 + m2 * 32768;
        out[base + r] = h;
        out[base + 16384 + r] = lo;
    }
}

// ====== Node-centric aggregation (r7 structure, ~62 µs): f16 ea + fdot2 ======
// 1 wave/node, 2 ch/lane. ea rows wave-uniform -> SGPR (8 dwords/row);
// 16 dot2/edge. 8-edge groups: one lgkmcnt drain per 8 edges.
// h gathers rotated one group ahead (VMEM, counted).
// PACK: store each output channel as u32 = bf16_hi | (bf16_lo<<16) IN t (same
// 4B/elem) so the W1 GEMM stages with bit-ops only — bit-identical to
// fp32-store-then-split (split-at-producer == split-at-consumer).
__device__ __forceinline__ void edge_f16(v2f& acc, v2f bj, unsigned hu, const u8x& e,
                                         const unsigned* __restrict__ wpk0,
                                         const unsigned* __restrict__ wpk1)
{
    float m0 = bj.x + bflo(hu);
    float m1 = bj.y + bfhi(hu);
#pragma unroll
    for (int kp = 0; kp < 8; ++kp) {
        dot2(m0, e[kp], wpk0[kp]);
        dot2(m1, e[kp], wpk1[kp]);
    }
    acc.x += fmaxf(m0, 0.f);
    acc.y += fmaxf(m1, 0.f);
}

template<bool PACK>
__global__ __launch_bounds__(256, 8) void aggregate_f16(
    const unsigned short* __restrict__ h16, const unsigned* __restrict__ eaH,
    const int* __restrict__ src_perm, const int* __restrict__ row_start,
    const float* __restrict__ We, const float* __restrict__ be,
    float* __restrict__ t, int Nn)
{
    int tid = threadIdx.x;
    int lane = tid & 63;
    int c = lane * 2;
    // f16 weight k-pairs per output channel (16 VGPRs)
    unsigned wpk0[8], wpk1[8];
#pragma unroll
    for (int kp = 0; kp < 8; ++kp) {
        wpk0[kp] = pkh2(We[(2 * kp) * HID + c],     We[(2 * kp + 1) * HID + c]);
        wpk1[kp] = pkh2(We[(2 * kp) * HID + c + 1], We[(2 * kp + 1) * HID + c + 1]);
    }
    v2f bj = *(const v2f*)&be[c];
    int node = blockIdx.x * 4 + (tid >> 6);
    if (node >= Nn) return;
    const unsigned* __restrict__ hw = (const unsigned*)h16 + lane;  // bf16 ch-pair per lane
    v2f acc = unpack2(hw[(unsigned)node << 6]);
    int p0 = __builtin_amdgcn_readfirstlane(row_start[node]);
    int p1 = __builtin_amdgcn_readfirstlane(row_start[node + 1]);
    int p = p0;

    int s0 = 0, s1 = 0, s2 = 0, s3 = 0, s4 = 0, s5 = 0, s6 = 0, s7 = 0;
    unsigned hu0 = 0, hu1 = 0, hu2 = 0, hu3 = 0, hu4 = 0, hu5 = 0, hu6 = 0, hu7 = 0;
    if (p + 8 <= p1) {
        s0 = src_perm[p];     s1 = src_perm[p + 1]; s2 = src_perm[p + 2]; s3 = src_perm[p + 3];
        s4 = src_perm[p + 4]; s5 = src_perm[p + 5]; s6 = src_perm[p + 6]; s7 = src_perm[p + 7];
        hu0 = hw[(unsigned)s0 << 6]; hu1 = hw[(unsigned)s1 << 6];
        hu2 = hw[(unsigned)s2 << 6]; hu3 = hw[(unsigned)s3 << 6];
        hu4 = hw[(unsigned)s4 << 6]; hu5 = hw[(unsigned)s5 << 6];
        hu6 = hw[(unsigned)s6 << 6]; hu7 = hw[(unsigned)s7 << 6];
    }
    while (p + 8 <= p1) {
        int np = p + 8;
        // current group's ea rows (SMEM, 8 x dwordx8)
        u8x e0 = *(const u8x*)(eaH + (size_t)(unsigned)(p    ) * 8);
        u8x e1 = *(const u8x*)(eaH + (size_t)(unsigned)(p + 1) * 8);
        u8x e2 = *(const u8x*)(eaH + (size_t)(unsigned)(p + 2) * 8);
        u8x e3 = *(const u8x*)(eaH + (size_t)(unsigned)(p + 3) * 8);
        u8x e4 = *(const u8x*)(eaH + (size_t)(unsigned)(p + 4) * 8);
        u8x e5 = *(const u8x*)(eaH + (size_t)(unsigned)(p + 5) * 8);
        u8x e6 = *(const u8x*)(eaH + (size_t)(unsigned)(p + 6) * 8);
        u8x e7 = *(const u8x*)(eaH + (size_t)(unsigned)(p + 7) * 8);
        // next group's src ids + h rows (prefetch)
        int t0 = 0, t1 = 0, t2 = 0, t3 = 0, t4 = 0, t5 = 0, t6 = 0, t7 = 0;
        unsigned hn0 = 0, hn1 = 0, hn2 = 0, hn3 = 0, hn4 = 0, hn5 = 0, hn6 = 0, hn7 = 0;
        if (np + 8 <= p1) {
            t0 = src_perm[np];     t1 = src_perm[np + 1]; t2 = src_perm[np + 2]; t3 = src_perm[np + 3];
            t4 = src_perm[np + 4]; t5 = src_perm[np + 5]; t6 = src_perm[np + 6]; t7 = src_perm[np + 7];
            hn0 = hw[(unsigned)t0 << 6]; hn1 = hw[(unsigned)t1 << 6];
            hn2 = hw[(unsigned)t2 << 6]; hn3 = hw[(unsigned)t3 << 6];
            hn4 = hw[(unsigned)t4 << 6]; hn5 = hw[(unsigned)t5 << 6];
            hn6 = hw[(unsigned)t6 << 6]; hn7 = hw[(unsigned)t7 << 6];
        }
        edge_f16(acc, bj, hu0, e0, wpk0, wpk1);
        edge_f16(acc, bj, hu1, e1, wpk0, wpk1);
        edge_f16(acc, bj, hu2, e2, wpk0, wpk1);
        edge_f16(acc, bj, hu3, e3, wpk0, wpk1);
        edge_f16(acc, bj, hu4, e4, wpk0, wpk1);
        edge_f16(acc, bj, hu5, e5, wpk0, wpk1);
        edge_f16(acc, bj, hu6, e6, wpk0, wpk1);
        edge_f16(acc, bj, hu7, e7, wpk0, wpk1);
        p = np;
        s0 = t0; s1 = t1; s2 = t2; s3 = t3; s4 = t4; s5 = t5; s6 = t6; s7 = t7;
        hu0 = hn0; hu1 = hn1; hu2 = hn2; hu3 = hn3;
        hu4 = hn4; hu5 = hn5; hu6 = hn6; hu7 = hn7;
    }
    for (; p < p1; ++p) {
        int s = src_perm[p];
        unsigned hu = hw[(unsigned)s << 6];
        u8x e = *(const u8x*)(eaH + (size_t)(unsigned)p * 8);
        edge_f16(acc, bj, hu, e, wpk0, wpk1);
    }
    if (PACK) {
        unsigned short h0, l0, h1, l1;
        split_bf16(acc.x, h0, l0);
        split_bf16(acc.y, h1, l1);
        uint2 pk;
        pk.x = (unsigned)h0 | ((unsigned)l0 << 16);
        pk.y = (unsigned)h1 | ((unsigned)l1 << 16);
        *(uint2*)((unsigned*)t + ((unsigned)node << 7) + c) = pk;
    } else {
        *(v2f*)(t + ((unsigned)node << 7) + c) = acc;
    }
}

// ====== fallback (no workspace for eaH): round-0 fp32 path via perm indirection ======
__device__ __forceinline__ void matvp(const v4f& a0, const v4f& a1,
                                      const v4f& a2, const v4f& a3,
                                      const v2f* __restrict__ w, v2f& m)
{
    m += w[0] * a0.x;  m += w[1] * a0.y;  m += w[2] * a0.z;  m += w[3] * a0.w;
    m += w[4] * a1.x;  m += w[5] * a1.y;  m += w[6] * a1.z;  m += w[7] * a1.w;
    m += w[8] * a2.x;  m += w[9] * a2.y;  m += w[10] * a2.z; m += w[11] * a2.w;
    m += w[12] * a3.x; m += w[13] * a3.y; m += w[14] * a3.z; m += w[15] * a3.w;
}

__global__ __launch_bounds__(256, 8) void aggregate_fp32(
    const unsigned short* __restrict__ h16, const float* __restrict__ eaG,
    const int* __restrict__ perm, const int* __restrict__ src_perm,
    const int* __restrict__ row_start,
    const float* __restrict__ We, const float* __restrict__ be,
    float* __restrict__ t, int Nn)
{
    int tid = threadIdx.x;
    int lane = tid & 63;
    int c = lane * 2;
    v2f w[16];
#pragma unroll
    for (int k = 0; k < 16; ++k) w[k] = *(const v2f*)&We[k * HID + c];
    v2f bj = *(const v2f*)&be[c];
    int node = blockIdx.x * 4 + (tid >> 6);
    if (node >= Nn) return;
    const unsigned* __restrict__ hw = (const unsigned*)h16 + lane;
    v2f acc = unpack2(hw[(unsigned)node << 6]);
    int p0 = __builtin_amdgcn_readfirstlane(row_start[node]);
    int p1 = __builtin_amdgcn_readfirstlane(row_start[node + 1]);
    int p = p0;
    int s0 = 0, s1 = 0, s2 = 0, s3 = 0;
    if (p + 4 <= p1) { s0 = src_perm[p]; s1 = src_perm[p + 1]; s2 = src_perm[p + 2]; s3 = src_perm[p + 3]; }
    while (p + 4 <= p1) {
        int np = p + 4;
        int t0 = 0, t1 = 0, t2 = 0, t3 = 0;
        if (np + 4 <= p1) { t0 = src_perm[np]; t1 = src_perm[np + 1]; t2 = src_perm[np + 2]; t3 = src_perm[np + 3]; }
        unsigned hu0 = hw[(unsigned)s0 << 6];
        unsigned hu1 = hw[(unsigned)s1 << 6];
        unsigned hu2 = hw[(unsigned)s2 << 6];
        unsigned hu3 = hw[(unsigned)s3 << 6];
        int q0 = perm[p], q1 = perm[p + 1], q2 = perm[p + 2], q3 = perm[p + 3];
        const v4f* e0 = (const v4f*)(eaG + (size_t)(unsigned)q0 * EDIM);
        const v4f* e1 = (const v4f*)(eaG + (size_t)(unsigned)q1 * EDIM);
        const v4f* e2 = (const v4f*)(eaG + (size_t)(unsigned)q2 * EDIM);
        const v4f* e3 = (const v4f*)(eaG + (size_t)(unsigned)q3 * EDIM);
        v4f a00 = e0[0], a01 = e0[1], a02 = e0[2], a03 = e0[3];
        v4f a10 = e1[0], a11 = e1[1], a12 = e1[2], a13 = e1[3];
        v4f a20 = e2[0], a21 = e2[1], a22 = e2[2], a23 = e2[3];
        v4f a30 = e3[0], a31 = e3[1], a32 = e3[2], a33 = e3[3];
        v2f m0 = bj + unpack2(hu0), m1 = bj + unpack2(hu1);
        v2f m2 = bj + unpack2(hu2), m3 = bj + unpack2(hu3);
        matvp(a00, a01, a02, a03, w, m0);
        matvp(a10, a11, a12, a13, w, m1);
        matvp(a20, a21, a22, a23, w, m2);
        matvp(a30, a31, a32, a33, w, m3);
        acc += (vmax0(m0) + vmax0(m1)) + (vmax0(m2) + vmax0(m3));
        p = np;
        s0 = t0; s1 = t1; s2 = t2; s3 = t3;
    }
    for (; p < p1; ++p) {
        int s = src_perm[p];
        int q = perm[p];
        const v4f* e0 = (const v4f*)(eaG + (size_t)(unsigned)q * EDIM);
        v4f a0 = e0[0], a1 = e0[1], a2 = e0[2], a3 = e0[3];
        v2f m0 = bj + unpack2(hw[(unsigned)s << 6]);
        matvp(a0, a1, a2, a3, w, m0);
        acc += vmax0(m0);
    }
    *(v2f*)(t + ((unsigned)node << 7) + c) = acc;
}

// ================= split-bf16 MFMA GEMM =================
// Stats are NSTAT-way slot-striped (r11, −44 µs). A_PACK: packed-split u32 A.
// MT: M-tile rows per block. MT=64 doubles the grid (391 -> 782 blocks,
// 1.5 -> 3.05 blocks/CU): r14 accounting showed the GEMMs far above their
// ~8 µs roofline — load-imbalance/latency-bound at 391 blocks.
#define LPAD 40

template<int K, int MT, bool PRE_BN, bool POST_STATS, bool OUT_BF16, bool A_PACK>
__global__ __launch_bounds__(256) void gemm_mfma(
    const float* __restrict__ A, const unsigned short* __restrict__ Wh,
    const unsigned short* __restrict__ Wl, const float* __restrict__ bias,
    const float* __restrict__ preStats, const float* __restrict__ preG, const float* __restrict__ preB,
    void* __restrict__ Cout, float* __restrict__ postStats, int Nrows, float invN)
{
    constexpr int RPW = MT / 4;        // rows per wave
    constexpr int MTS = RPW / 16;      // 16-row MFMA tiles per wave
    __shared__ __align__(16) unsigned short Ah[MT * LPAD], Al[MT * LPAD];
    __shared__ __align__(16) unsigned short Bh[128 * LPAD], Bl[128 * LPAD];
    __shared__ float sc[PRE_BN ? K : 1], sb[PRE_BN ? K : 1];
    int tid = threadIdx.x;
    int rbase = blockIdx.x * MT;
    if (PRE_BN) {
        if (tid < K) {
            float Sm = 0.f, Qm = 0.f;
#pragma unroll
            for (int cpy = 0; cpy < NSTAT; ++cpy) {
                Sm += preStats[(cpy << 8) + tid];
                Qm += preStats[(cpy << 8) + 128 + tid];
            }
            float mean = Sm * invN;
            float var = Qm * invN - mean * mean;
            float rstd = rsqrtf(var + 1e-5f);
            float g = preG[tid];
            sc[tid] = rstd * g;
            sb[tid] = preB[tid] - mean * rstd * g;
        }
        __syncthreads();
    }
    int w = tid >> 6, nl = tid & 15, q = (tid >> 4) & 3;
    f4v acc[MTS][8];
#pragma unroll
    for (int mt = 0; mt < MTS; ++mt)
#pragma unroll
        for (int nt = 0; nt < 8; ++nt)
#pragma unroll
            for (int r = 0; r < 4; ++r) acc[mt][nt][r] = 0.f;

    for (int ks = 0; ks < K / 32; ++ks) {
        int k0 = ks * 32;
        if (ks) __syncthreads();
#pragma unroll
        for (int i = 0; i < MT / 32; ++i) {
            int cidx = tid + i * 256;
            int m = cidx >> 3, k4 = (cidx & 7) * 4;
            int gr = rbase + m;
            uint2 hp, lp;
            if (A_PACK) {
                uint4 v = make_uint4(0u, 0u, 0u, 0u);
                if (gr < Nrows) v = *(const uint4*)((const unsigned*)A + (size_t)gr * K + k0 + k4);
                hp.x = (v.x & 0xffffu) | (v.y << 16);
                hp.y = (v.z & 0xffffu) | (v.w << 16);
                lp.x = (v.x >> 16) | (v.y & 0xffff0000u);
                lp.y = (v.z >> 16) | (v.w & 0xffff0000u);
            } else {
                float4 v = make_float4(0.f, 0.f, 0.f, 0.f);
                if (gr < Nrows) v = *(const float4*)&A[(size_t)gr * K + k0 + k4];
                if (PRE_BN) {
                    v.x = fmaxf(v.x * sc[k0 + k4]     + sb[k0 + k4],     0.f);
                    v.y = fmaxf(v.y * sc[k0 + k4 + 1] + sb[k0 + k4 + 1], 0.f);
                    v.z = fmaxf(v.z * sc[k0 + k4 + 2] + sb[k0 + k4 + 2], 0.f);
                    v.w = fmaxf(v.w * sc[k0 + k4 + 3] + sb[k0 + k4 + 3], 0.f);
                }
                unsigned short h0, l0, h1, l1, h2, l2, h3, l3;
                split_bf16(v.x, h0, l0); split_bf16(v.y, h1, l1);
                split_bf16(v.z, h2, l2); split_bf16(v.w, h3, l3);
                hp.x = (unsigned)h0 | ((unsigned)h1 << 16); hp.y = (unsigned)h2 | ((unsigned)h3 << 16);
                lp.x = (unsigned)l0 | ((unsigned)l1 << 16); lp.y = (unsigned)l2 | ((unsigned)l3 << 16);
            }
            *(uint2*)&Ah[m * LPAD + k4] = hp;
            *(uint2*)&Al[m * LPAD + k4] = lp;
        }
#pragma unroll
        for (int i = 0; i < 2; ++i) {
            int g = tid + i * 256;
            int n = g >> 2, kq = (g & 3) * 8;
            uint4 hv = *(const uint4*)&Wh[(size_t)n * K + k0 + kq];
            uint4 lv = *(const uint4*)&Wl[(size_t)n * K + k0 + kq];
            *(uint4*)&Bh[n * LPAD + kq] = hv;
            *(uint4*)&Bl[n * LPAD + kq] = lv;
        }
        __syncthreads();
        s8v ah[MTS], al[MTS];
#pragma unroll
        for (int mt = 0; mt < MTS; ++mt) {
            ah[mt] = *(const s8v*)&Ah[(w * RPW + mt * 16 + nl) * LPAD + q * 8];
            al[mt] = *(const s8v*)&Al[(w * RPW + mt * 16 + nl) * LPAD + q * 8];
        }
#pragma unroll
        for (int nt = 0; nt < 8; ++nt) {
            s8v bh = *(const s8v*)&Bh[(nt * 16 + nl) * LPAD + q * 8];
            s8v bl = *(const s8v*)&Bl[(nt * 16 + nl) * LPAD + q * 8];
#pragma unroll
            for (int mt = 0; mt < MTS; ++mt) {
                acc[mt][nt] = MFMA_BF16(ah[mt], bh, acc[mt][nt]);
                acc[mt][nt] = MFMA_BF16(ah[mt], bl, acc[mt][nt]);
                acc[mt][nt] = MFMA_BF16(al[mt], bh, acc[mt][nt]);
            }
        }
    }
    __syncthreads();

    float* Cf = (float*)Cout;
    unsigned short* Ch = (unsigned short*)Cout;
    float* redS = (float*)Ah;
    float* redQ = (float*)Al;
#pragma unroll
    for (int nt = 0; nt < 8; ++nt) {
        int col = nt * 16 + nl;
        float bcol = bias[col];
        float sv = 0.f, qv = 0.f;
#pragma unroll
        for (int mt = 0; mt < MTS; ++mt) {
#pragma unroll
            for (int r = 0; r < 4; ++r) {
                int grow = rbase + w * RPW + mt * 16 + q * 4 + r;
                if (grow < Nrows) {
                    float o = acc[mt][nt][r] + bcol;
                    if (OUT_BF16) Ch[(size_t)grow * HID + col] = bf16_rne(o);
                    else          Cf[(size_t)grow * HID + col] = o;
                    if (POST_STATS) { sv += o; qv += o * o; }
                }
            }
        }
        if (POST_STATS) {
            sv += __shfl_down(sv, 32, 64); sv += __shfl_down(sv, 16, 64);
            qv += __shfl_down(qv, 32, 64); qv += __shfl_down(qv, 16, 64);
            if ((tid & 63) < 16) { redS[w * 128 + col] = sv; redQ[w * 128 + col] = qv; }
        }
    }
    if (POST_STATS) {
        __syncthreads();
        if (tid < 128) {
            float S = redS[tid] + redS[128 + tid] + redS[256 + tid] + redS[384 + tid];
            float Q = redQ[tid] + redQ[128 + tid] + redQ[256 + tid] + redQ[384 + tid];
            int cp = (blockIdx.x & (NSTAT - 1)) << 8;   // slot-striped: ~49-contender max
            atomicAdd(&postStats[cp + tid], S);
            atomicAdd(&postStats[cp + 128 + tid], Q);
        }
    }
}

// ======== fused BN apply + ReLU + pool; h stored as packed bf16 (pool uses exact fp32) ========
__global__ void bn_apply_pool(const float* __restrict__ X, unsigned short* __restrict__ h16,
                              const float* __restrict__ stats, const float* __restrict__ g,
                              const float* __restrict__ b, const int* __restrict__ starts,
                              float* __restrict__ z, int l, float invN)
{
    int gph = blockIdx.x;
    int tid = threadIdx.x;
    int ch4 = (tid & 31) * 4, wk = tid >> 5;   // 16 walkers x 32 lanes(float4)
    float sc[4], sh[4];
#pragma unroll
    for (int u = 0; u < 4; ++u) {
        int j = ch4 + u;
        float Sm = 0.f, Qm = 0.f;
#pragma unroll
        for (int cpy = 0; cpy < NSTAT; ++cpy) {
            Sm += stats[(cpy << 8) + j];
            Qm += stats[(cpy << 8) + 128 + j];
        }
        float mean = Sm * invN;
        float var = Qm * invN - mean * mean;
        float rstd = rsqrtf(var + 1e-5f);
        float gg = g[j];
        sc[u] = rstd * gg;
        sh[u] = b[j] - mean * rstd * gg;
    }
    int s = starts[gph], e = starts[gph + 1];
    float4 sum = make_float4(0.f, 0.f, 0.f, 0.f);
    float4 mx = make_float4(0.f, 0.f, 0.f, 0.f);
    unsigned* hv32 = (unsigned*)h16;
    for (int n = s + wk; n < e; n += 16) {
        float4 v = *(const float4*)&X[(size_t)n * HID + ch4];
        v.x = fmaxf(v.x * sc[0] + sh[0], 0.f);
        v.y = fmaxf(v.y * sc[1] + sh[1], 0.f);
        v.z = fmaxf(v.z * sc[2] + sh[2], 0.f);
        v.w = fmaxf(v.w * sc[3] + sh[3], 0.f);
        uint2 pk;
        pk.x = pack2(v.x, v.y);
        pk.y = pack2(v.z, v.w);
        *(uint2*)&hv32[(size_t)n * 64 + (ch4 >> 1)] = pk;
        sum.x += v.x; sum.y += v.y; sum.z += v.z; sum.w += v.w;
        mx.x = fmaxf(mx.x, v.x); mx.y = fmaxf(mx.y, v.y);
        mx.z = fmaxf(mx.z, v.z); mx.w = fmaxf(mx.w, v.w);
    }
    __shared__ float ls[16 * 128], lm[16 * 128];
    *(float4*)&ls[wk * 128 + ch4] = sum;
    *(float4*)&lm[wk * 128 + ch4] = mx;
    __syncthreads();
    if (tid < 128) {
        float S = 0.f, M = 0.f;
#pragma unroll
        for (int k = 0; k < 16; ++k) {
            S += ls[k * 128 + tid];
            M = fmaxf(M, lm[k * 128 + tid]);
        }
        float cnt = (float)(e - s);
        z[(size_t)gph * 768 + l * 128 + tid] = S / fmaxf(cnt, 1.f);
        z[(size_t)gph * 768 + 384 + l * 128 + tid] = M;
    }
}

// ================= head =================
// 512 threads: 4-way K-split (192/thread vs 768) + LDS reduce — 4x the waves,
// 4x shorter serial FMA chain (old version ran at 0.5 waves/SIMD).
__global__ void head_gemm1(const float* __restrict__ z, const float* __restrict__ W,
                           const float* __restrict__ bias, float* __restrict__ zr,
                           float* __restrict__ msums)
{
    __shared__ __align__(16) float zl[768];
    __shared__ float part[512];
    int g = blockIdx.x, j = threadIdx.x;
    for (int i = j; i < 768; i += 512) zl[i] = z[(size_t)g * 768 + i];
    __syncthreads();
    int ch = j & 127, kq = j >> 7;       // 4 k-quarters x 128 channels
    int kbase = kq * 192;
    float acc = 0.f;
    for (int k = 0; k < 192; k += 4) {
        float4 a4 = *(const float4*)&zl[kbase + k];
        acc += a4.x * W[(kbase + k) * 128 + ch] + a4.y * W[(kbase + k + 1) * 128 + ch]
             + a4.z * W[(kbase + k + 2) * 128 + ch] + a4.w * W[(kbase + k + 3) * 128 + ch];
    }
    part[j] = acc;
    __syncthreads();
    if (j < 128) {
        float v = part[j] + part[128 + j] + part[256 + j] + part[384 + j] + bias[j];
        zr[(size_t)g * 128 + j] = v;
        int cp = (g & (NSTAT - 1)) << 8;   // slot-striped msums
        atomicAdd(&msums[cp + j], v);
        atomicAdd(&msums[cp + 128 + j], v * v);
    }
}

__global__ void head_final(const float* __restrict__ zr, const float* __restrict__ msums,
                           const float* __restrict__ hg, const float* __restrict__ hb,
                           const float* __restrict__ W2, const float* __restrict__ b2,
                           float* __restrict__ out, float invG)
{
    int g = blockIdx.x, j = threadIdx.x;
    float Sm = 0.f, Qm = 0.f;
#pragma unroll
    for (int cpy = 0; cpy < NSTAT; ++cpy) {
        Sm += msums[(cpy << 8) + j];
        Qm += msums[(cpy << 8) + 128 + j];
    }
    float mean = Sm * invG;
    float var = Qm * invG - mean * mean;
    float rstd = rsqrtf(var + 1e-5f);
    float v = zr[(size_t)g * 128 + j];
    v = (v - mean) * rstd * hg[j] + hb[j];
    v = fmaxf(v, 0.f);
    float p = v * W2[j];
#pragma unroll
    for (int off = 32; off > 0; off >>= 1) p += __shfl_down(p, off, 64);
    __shared__ float partial[2];
    if ((j & 63) == 0) partial[j >> 6] = p;
    __syncthreads();
    if (j == 0) out[g] = partial[0] + partial[1] + b2[0];
}

extern "C" void kernel_launch(void* const* d_in, const int* in_sizes, int n_in,
                              void* d_out, int out_size, void* d_ws, size_t ws_size,
                              hipStream_t stream)
{
    const float* x         = (const float*)d_in[0];
    const float* edge_attr = (const float*)d_in[1];
    const int*   src       = (const int*)d_in[2];
    const int*   dst       = (const int*)d_in[3];
    const int*   batch     = (const int*)d_in[4];
    const float* Wp        = (const float*)d_in[5];
    const float* bp        = (const float*)d_in[6];
    const float* conv_We   = (const float*)d_in[7];
    const float* conv_be   = (const float*)d_in[8];
    const float* conv_W1   = (const float*)d_in[9];
    const float* conv_b1   = (const float*)d_in[10];
    const float* conv_g1   = (const float*)d_in[11];
    const float* conv_bt1  = (const float*)d_in[12];
    const float* conv_W2   = (const float*)d_in[13];
    const float* conv_b2   = (const float*)d_in[14];
    const float* bn_g      = (const float*)d_in[15];
    const float* bn_b      = (const float*)d_in[16];
    const float* head_W1   = (const float*)d_in[17];
    const float* head_b1   = (const float*)d_in[18];
    const float* head_g    = (const float*)d_in[19];
    const float* head_bt   = (const float*)d_in[20];
    const float* head_W2   = (const float*)d_in[21];
    const float* head_b2   = (const float*)d_in[22];

    const int N = in_sizes[4];            // 50000
    const int E = in_sizes[2];            // 800000
    const int G = out_size;               // 256
    const int L = 3;

    // ---- workspace layout ----
    const int SLOT = NSTAT * 256;                    // 4096 floats per stat set
    float* t        = (float*)d_ws;                  // N*128 fp32
    unsigned short* h16 = (unsigned short*)(t + (size_t)N * HID);  // N*128 bf16
    float* z        = (float*)(h16 + (size_t)N * HID);             // G*768
    float* zr       = z + (size_t)G * 768;           // G*128
    float* statsAll = zr + (size_t)G * HID;          // 7 sets x SLOT
    int*   deg      = (int*)(statsAll + 7 * SLOT);   // N
    int*   starts   = deg + N;                       // G+1
    int*   row_start= starts + (G + 1);              // N+1
    int*   cursor   = row_start + (N + 1);           // N
    int*   bsum     = cursor + N;                    // 256
    int*   src_perm = bsum + 256;                    // E
    int*   perm     = src_perm + E;                  // E
    unsigned short* wt = (unsigned short*)(perm + E);  // 212992 ushorts gemm weights
    size_t base_end = (size_t)((char*)(wt + 212992) - (char*)d_ws);
    size_t ea_off = (base_end + 63) & ~(size_t)63;   // 64B-align ea rows
    bool gath = (ea_off + (size_t)E * 8 * sizeof(unsigned)) <= ws_size;  // f16 rows: 32B/edge
    unsigned* eaH = (unsigned*)((char*)d_ws + ea_off);
    float* msums = statsAll + 6 * SLOT;

    (void)n_in;

    const float invN = 1.0f / (float)N;
    const float invG = 1.0f / (float)G;
    const int nb = (N + 255) / 256;
    const int gemmBlocks = (N + 63) / 64;   // MT=64: 782 blocks, 3.05/CU

    // ---- CSR build + weight prep ----
    (void)hipMemsetAsync(statsAll, 0, 7 * SLOT * sizeof(float) + (size_t)N * sizeof(int), stream);
    hist_kernel<<<(E + 255) / 256, 256, 0, stream>>>(dst, deg, E);
    block_sum_kernel<<<nb, 256, 0, stream>>>(deg, bsum, N);
    bsum_scan_kernel<<<1, 256, 0, stream>>>(bsum, nb, &row_start[N]);
    block_scan_kernel<<<nb, 256, 0, stream>>>(deg, bsum, row_start, cursor, batch, starts, N, G);
    scatter_kernel<<<(E + 255) / 256, 256, 0, stream>>>(src, dst, cursor, perm, src_perm, E);
    if (gath)
        gather_ea_f16<<<(E * 2 + 255) / 256, 256, 0, stream>>>(edge_attr, perm, eaH, E);
    prep_weights<<<(8192 + 6 * 16384 + 255) / 256, 256, 0, stream>>>(Wp, conv_W1, conv_W2, wt);

    const unsigned short* Wp_hi = wt;
    const unsigned short* Wp_lo = wt + 8192;

    // h16 = bf16(x @ Wp + bp)
    gemm_mfma<64, 64, false, false, true, false><<<gemmBlocks, 256, 0, stream>>>(
        x, Wp_hi, Wp_lo, bp, nullptr, nullptr, nullptr, h16, nullptr, N, invN);

    for (int l = 0; l < L; ++l) {
        float* sI = statsAll + (size_t)(2 * l) * SLOT;
        float* sO = sI + SLOT;
        const unsigned short* W1hi = wt + 16384 + (size_t)(2 * l) * 32768;
        const unsigned short* W1lo = W1hi + 16384;
        const unsigned short* W2hi = wt + 16384 + (size_t)(2 * l + 1) * 32768;
        const unsigned short* W2lo = W2hi + 16384;
        if (gath) {
            // aggregate stores packed-split u32 in t; W1 gemm stages with bit-ops only
            aggregate_f16<true><<<(N + 3) / 4, 256, 0, stream>>>(
                h16, eaH, src_perm, row_start,
                conv_We + (size_t)l * EDIM * HID, conv_be + l * HID, t, N);
            gemm_mfma<128, 64, false, true, false, true><<<gemmBlocks, 256, 0, stream>>>(
                t, W1hi, W1lo, conv_b1 + l * HID,
                nullptr, nullptr, nullptr, t, sI, N, invN);
        } else {
            aggregate_fp32<<<(N + 3) / 4, 256, 0, stream>>>(
                h16, edge_attr, perm, src_perm, row_start,
                conv_We + (size_t)l * EDIM * HID, conv_be + l * HID, t, N);
            gemm_mfma<128, 64, false, true, false, false><<<gemmBlocks, 256, 0, stream>>>(
                t, W1hi, W1lo, conv_b1 + l * HID,
                nullptr, nullptr, nullptr, t, sI, N, invN);
        }
        gemm_mfma<128, 64, true, true, false, false><<<gemmBlocks, 256, 0, stream>>>(
            t, W2hi, W2lo, conv_b2 + l * HID,
            sI, conv_g1 + l * HID, conv_bt1 + l * HID, t, sO, N, invN);
        bn_apply_pool<<<G, 512, 0, stream>>>(
            t, h16, sO, bn_g + l * HID, bn_b + l * HID, starts, z, l, invN);
    }

    head_gemm1<<<G, 512, 0, stream>>>(z, head_W1, head_b1, zr, msums);
    head_final<<<G, 128, 0, stream>>>(zr, msums, head_g, head_bt, head_W2, head_b2,
                                      (float*)d_out, invG);
}